// Round 4
// baseline (536.659 us; speedup 1.0000x reference)
//
#include <hip/hip_runtime.h>
#include <hip/hip_bf16.h>
#include <math.h>

// Problem constants (fixed by the reference)
#define N_NODES 10000
#define N_EDGES 160000
#define BATCH   4096
#define DIM     512
#define HID     256
#define KEXT    1536   // 3 x 512: split-bf16 product expansion

typedef short short8 __attribute__((ext_vector_type(8)));
typedef float f32x4  __attribute__((ext_vector_type(4)));

// ---------------------------------------------------------------------------
// graph build utilities
// ---------------------------------------------------------------------------
__global__ void zero_init_kernel(int* cnt, int* cursor, int* flag, int* pcnt) {
    int i = blockIdx.x * blockDim.x + threadIdx.x;
    if (i < N_NODES) { cnt[i] = 0; cursor[i] = 0; flag[i] = 0; }
    if (i == 0) pcnt[0] = 0;
}

__global__ void count_deg_kernel(const int* __restrict__ dst, int* __restrict__ cnt) {
    int e = blockIdx.x * blockDim.x + threadIdx.x;
    if (e < N_EDGES) atomicAdd(&cnt[dst[e]], 1);
}

__global__ void mark_labels_kernel(const int* __restrict__ label, int* __restrict__ flag) {
    int b = blockIdx.x * blockDim.x + threadIdx.x;
    if (b < BATCH) flag[label[b]] = 1;          // idempotent, races benign
}

// block-local scan (256/block) + per-block sums; also computes dinv
__global__ __launch_bounds__(256) void scanA_kernel(const int* __restrict__ cnt,
        int* __restrict__ offs, int* __restrict__ bsum, float* __restrict__ dinv) {
    __shared__ int sh[256];
    int i = blockIdx.x * 256 + threadIdx.x;
    int v = (i < N_NODES) ? cnt[i] : 0;
    if (i < N_NODES) dinv[i] = rsqrtf((float)(1 + v));
    sh[threadIdx.x] = v;
    __syncthreads();
    for (int off = 1; off < 256; off <<= 1) {
        int t = (threadIdx.x >= (unsigned)off) ? sh[threadIdx.x - off] : 0;
        __syncthreads();
        sh[threadIdx.x] += t;
        __syncthreads();
    }
    if (i < N_NODES) offs[i] = sh[threadIdx.x] - v;   // exclusive within block
    if (threadIdx.x == 255) bsum[blockIdx.x] = sh[255];
}

__global__ void scanB_kernel(int* bsum, int nblocks) {
    if (threadIdx.x == 0 && blockIdx.x == 0) {
        int a = 0;
        for (int b = 0; b < nblocks; ++b) { int t = bsum[b]; bsum[b] = a; a += t; }
    }
}

__global__ __launch_bounds__(256) void scanC_kernel(int* __restrict__ offs,
                                                    const int* __restrict__ bsum) {
    int i = blockIdx.x * 256 + threadIdx.x;
    if (i < N_NODES) offs[i] += bsum[blockIdx.x];
    if (i == 0) offs[N_NODES] = N_EDGES;
}

__global__ void fill_csr_kernel(const int* __restrict__ dst, const int* __restrict__ offs,
                                int* __restrict__ cursor, int* __restrict__ csr) {
    int e = blockIdx.x * blockDim.x + threadIdx.x;
    if (e < N_EDGES) {
        int d = dst[e];
        int p = offs[d] + atomicAdd(&cursor[d], 1);
        csr[p] = e;
    }
}

__global__ void compact_kernel(const int* __restrict__ flag, int* __restrict__ pcnt,
                               int* __restrict__ nodelist, int* __restrict__ pos) {
    int n = blockIdx.x * blockDim.x + threadIdx.x;
    if (n < N_NODES && flag[n]) {
        int p = atomicAdd(pcnt, 1);
        nodelist[p] = n;
        pos[n] = p;
    }
}

// ---------------------------------------------------------------------------
// GCN aggregation over 256 channels: wave-per-node, float4 per lane.
// ---------------------------------------------------------------------------
template <int BIAS, int RELU, int COMPACT>
__global__ __launch_bounds__(256) void agg256_kernel(const float* __restrict__ xw,
        const float* __restrict__ dinv, const int* __restrict__ src,
        const int* __restrict__ offs, const int* __restrict__ csr,
        const float* __restrict__ bias, float* __restrict__ out,
        const int* __restrict__ nodelist, const int* __restrict__ pcnt) {
    int wid  = blockIdx.x * 4 + (threadIdx.x >> 6);
    int lane = threadIdx.x & 63;
    int n;
    if (COMPACT) { if (wid >= pcnt[0]) return; n = nodelist[wid]; }
    else         { if (wid >= N_NODES) return; n = wid; }
    int c4 = lane * 4;
    float di = dinv[n];
    float d2 = di * di;
    float4 self = *(const float4*)&xw[(size_t)n * 256 + c4];
    float4 a = make_float4(d2 * self.x, d2 * self.y, d2 * self.z, d2 * self.w);
    int s0 = offs[n], s1 = offs[n + 1];
    for (int i = s0; i < s1; ++i) {
        int e  = csr[i];
        int sr = src[e];
        float wgt = di * dinv[sr];
        float4 v = *(const float4*)&xw[(size_t)sr * 256 + c4];
        a.x = fmaf(wgt, v.x, a.x); a.y = fmaf(wgt, v.y, a.y);
        a.z = fmaf(wgt, v.z, a.z); a.w = fmaf(wgt, v.w, a.w);
    }
    if (BIAS) {
        float4 b = *(const float4*)&bias[c4];
        a.x += b.x; a.y += b.y; a.z += b.z; a.w += b.w;
    }
    if (RELU) {
        a.x = fmaxf(a.x, 0.f); a.y = fmaxf(a.y, 0.f);
        a.z = fmaxf(a.z, 0.f); a.w = fmaxf(a.w, 0.f);
    }
    int orow = COMPACT ? wid : n;
    *(float4*)&out[(size_t)orow * 256 + c4] = a;
}

// ---------------------------------------------------------------------------
// Dense NN GEMM: C[M,N] = A[M,K] @ B[K,N] (+bias)(+relu)  (fp32 VALU)
// ---------------------------------------------------------------------------
#define BM 128
#define BN 64
#define BK 16

template <int BIAS, int RELU>
__global__ __launch_bounds__(256) void gemm_nn_kernel(const float* __restrict__ A,
        const float* __restrict__ Bm, const float* __restrict__ bias,
        float* __restrict__ C, int M, int N, int K) {
    __shared__ float As[BK][BM + 4];
    __shared__ float Bs[BK][BN + 4];
    int t   = threadIdx.x;
    int rt  = blockIdx.y, ct = blockIdx.x;
    int row0 = rt * BM, col0 = ct * BN;
    int a_row = t >> 2;              // 0..63
    int a_k4  = (t & 3) * 4;         // 0,4,8,12
    int b_k   = t >> 4;              // 0..15
    int b_n   = (t & 15) * 4;        // 0..60
    int tx = t & 15, ty = t >> 4;

    float acc[8][4];
#pragma unroll
    for (int i = 0; i < 8; ++i)
#pragma unroll
        for (int j = 0; j < 4; ++j) acc[i][j] = 0.0f;

    for (int k0 = 0; k0 < K; k0 += BK) {
        int r1 = row0 + a_row;       if (r1 > M - 1) r1 = M - 1;
        int r2 = row0 + a_row + 64;  if (r2 > M - 1) r2 = M - 1;
        float4 v1 = *(const float4*)&A[(size_t)r1 * K + k0 + a_k4];
        float4 v2 = *(const float4*)&A[(size_t)r2 * K + k0 + a_k4];
        As[a_k4 + 0][a_row] = v1.x;  As[a_k4 + 1][a_row] = v1.y;
        As[a_k4 + 2][a_row] = v1.z;  As[a_k4 + 3][a_row] = v1.w;
        As[a_k4 + 0][a_row + 64] = v2.x;  As[a_k4 + 1][a_row + 64] = v2.y;
        As[a_k4 + 2][a_row + 64] = v2.z;  As[a_k4 + 3][a_row + 64] = v2.w;
        float4 bv = *(const float4*)&Bm[(size_t)(k0 + b_k) * N + col0 + b_n];
        *(float4*)&Bs[b_k][b_n] = bv;
        __syncthreads();
#pragma unroll
        for (int k = 0; k < BK; ++k) {
            float4 a0 = *(const float4*)&As[k][ty * 8];
            float4 a1 = *(const float4*)&As[k][ty * 8 + 4];
            float4 b0 = *(const float4*)&Bs[k][tx * 4];
            float av[8] = {a0.x, a0.y, a0.z, a0.w, a1.x, a1.y, a1.z, a1.w};
            float bvv[4] = {b0.x, b0.y, b0.z, b0.w};
#pragma unroll
            for (int i = 0; i < 8; ++i)
#pragma unroll
                for (int j = 0; j < 4; ++j) acc[i][j] = fmaf(av[i], bvv[j], acc[i][j]);
        }
        __syncthreads();
    }

    float4 bb = make_float4(0.f, 0.f, 0.f, 0.f);
    if (BIAS) bb = *(const float4*)&bias[col0 + tx * 4];
#pragma unroll
    for (int i = 0; i < 8; ++i) {
        int r = row0 + ty * 8 + i;
        if (r < M) {
            float4 v = make_float4(acc[i][0] + bb.x, acc[i][1] + bb.y,
                                   acc[i][2] + bb.z, acc[i][3] + bb.w);
            if (RELU) {
                v.x = fmaxf(v.x, 0.f); v.y = fmaxf(v.y, 0.f);
                v.z = fmaxf(v.z, 0.f); v.w = fmaxf(v.w, 0.f);
            }
            *(float4*)&C[(size_t)r * N + col0 + tx * 4] = v;
        }
    }
}

// ---------------------------------------------------------------------------
// split-bf16 helpers
// ---------------------------------------------------------------------------
__device__ __forceinline__ unsigned short f2bf(float x) {
    unsigned u = __float_as_uint(x);
    return (unsigned short)((u + 0x7FFFu + ((u >> 16) & 1u)) >> 16);   // RNE
}
__device__ __forceinline__ float bf2f(unsigned short h) {
    return __uint_as_float(((unsigned)h) << 16);
}

// Build K-extended bf16 matrices (src row stride = DIM = 512).
// MODE 0 (A/text, gathered via pos[label[r]]): segments [hi | lo | hi]
// MODE 1 (B/image):                            segments [hi | hi | lo]
template <int MODE>
__global__ __launch_bounds__(256) void build_ext_kernel(const float* __restrict__ srcmat,
        const int* __restrict__ label, const int* __restrict__ pos,
        unsigned short* __restrict__ dstmat) {
    int id = blockIdx.x * 256 + threadIdx.x;     // BATCH*128 threads, 4 elems each
    int r  = id >> 7;
    int c4 = (id & 127) << 2;
    int srow = (MODE == 0) ? pos[label[r]] : r;
    float4 v = *(const float4*)&srcmat[(size_t)srow * DIM + c4];
    ushort4 h, l;
    h.x = f2bf(v.x); l.x = f2bf(v.x - bf2f(h.x));
    h.y = f2bf(v.y); l.y = f2bf(v.y - bf2f(h.y));
    h.z = f2bf(v.z); l.z = f2bf(v.z - bf2f(h.z));
    h.w = f2bf(v.w); l.w = f2bf(v.w - bf2f(h.w));
    unsigned short* base = dstmat + (size_t)r * KEXT;
    if (MODE == 0) {
        *(ushort4*)&base[c4]        = h;
        *(ushort4*)&base[512 + c4]  = l;
        *(ushort4*)&base[1024 + c4] = h;
    } else {
        *(ushort4*)&base[c4]        = h;
        *(ushort4*)&base[512 + c4]  = h;
        *(ushort4*)&base[1024 + c4] = l;
    }
}

// ---------------------------------------------------------------------------
// logits = Aext @ Bext^T  (bf16 MFMA, K=1536), fused online softmax partials.
// 128x128 tile, BK=32, 4 waves (2x2), wave = 64x64 via 4x4 16x16x32 MFMAs.
// BARRIER-FREE K-loop: each wave stages ONLY the chunks it consumes into
// wave-private LDS (A duplicated across wx pair, B across wy pair -> L1 absorbs).
// Double-buffered, drained with fine-grained `s_waitcnt vmcnt(8)` (AITER-style):
// the 8 staging loads of step k have a full step of MFMA (~600 cyc) in flight.
// No __syncthreads anywhere in the loop.
// ---------------------------------------------------------------------------
__device__ __forceinline__ void gld_lds16(const void* g, void* l) {
    __builtin_amdgcn_global_load_lds(
        (const __attribute__((address_space(1))) unsigned int*)g,
        (__attribute__((address_space(3))) unsigned int*)l, 16, 0, 0);
}

__global__ __launch_bounds__(256) void logits_mfma_kernel(
        const unsigned short* __restrict__ Aext, const unsigned short* __restrict__ Bext,
        float* __restrict__ pmax, float* __restrict__ psum, float* __restrict__ diagv) {
    // [buffer][wave][4 A-chunks | 4 B-chunks], chunk = 16 rows x 32 k = 512 ushorts
    __shared__ __align__(16) unsigned short sh[2][4][4096];   // 64 KB

    int t    = threadIdx.x;
    int lane = t & 63;
    int w    = t >> 6;            // wave 0..3
    int wy   = w >> 1, wx = w & 1;
    int rt   = blockIdx.y, ct = blockIdx.x;
    int m    = lane & 15;         // fragment row within 16
    int q    = lane >> 4;         // k-chunk quad

    // wave-private staging pointers: lane (m,q) loads 16B of row i*16+m, k-offset q*8
    const unsigned short* pa[4];
    const unsigned short* pb[4];
#pragma unroll
    for (int i = 0; i < 4; ++i) {
        pa[i] = Aext + (size_t)(rt * 128 + wy * 64 + i * 16 + m) * KEXT + q * 8;
        pb[i] = Bext + (size_t)(ct * 128 + wx * 64 + i * 16 + m) * KEXT + q * 8;
    }
    unsigned short* u0 = &sh[0][w][0];
    unsigned short* u1 = &sh[1][w][0];

    f32x4 acc[4][4];
#pragma unroll
    for (int i = 0; i < 4; ++i)
#pragma unroll
        for (int j = 0; j < 4; ++j) acc[i][j] = (f32x4){0.f, 0.f, 0.f, 0.f};

    // prologue: stage k-step 0 into buffer 0 (8 loads)
#pragma unroll
    for (int i = 0; i < 4; ++i) {
        gld_lds16(pa[i], u0 + i * 512);
        gld_lds16(pb[i], u0 + 2048 + i * 512);
    }

    const int NK = KEXT / 32;     // 48
    for (int k = 0; k < NK; ++k) {
        unsigned short* uc = (k & 1) ? u1 : u0;
        unsigned short* un = (k & 1) ? u0 : u1;
        if (k + 1 < NK) {
            int ko = (k + 1) * 32;
#pragma unroll
            for (int i = 0; i < 4; ++i) {
                gld_lds16(pa[i] + ko, un + i * 512);
                gld_lds16(pb[i] + ko, un + 2048 + i * 512);
            }
            // wait for the PREVIOUS step's 8 loads (oldest), keep newest 8 in flight
            asm volatile("s_waitcnt vmcnt(8)" ::: "memory");
        } else {
            asm volatile("s_waitcnt vmcnt(0)" ::: "memory");
        }
        short8 af[4], bf[4];
#pragma unroll
        for (int i = 0; i < 4; ++i) af[i] = *(const short8*)&uc[i * 512 + lane * 8];
#pragma unroll
        for (int i = 0; i < 4; ++i) bf[i] = *(const short8*)&uc[2048 + i * 512 + lane * 8];
#pragma unroll
        for (int i = 0; i < 4; ++i)
#pragma unroll
            for (int j = 0; j < 4; ++j)
                acc[i][j] = __builtin_amdgcn_mfma_f32_16x16x32_bf16(af[i], bf[j], acc[i][j], 0, 0, 0);
    }

    // C/D layout: col = lane&15, row = q*4 + reg (within each 16x16 tile)
    // diagonal values
    if (rt == ct && wy == wx) {
        int reg = m - q * 4;
        if (reg >= 0 && reg < 4) {
#pragma unroll
            for (int mt = 0; mt < 4; ++mt) {
                f32x4 dvv = acc[mt][mt];
                float dv = (reg == 0) ? dvv.x : (reg == 1) ? dvv.y : (reg == 2) ? dvv.z : dvv.w;
                diagv[rt * 128 + wy * 64 + mt * 16 + m] = dv;
            }
        }
    }

    // per-row (max, sumexp) over this wave's 64 cols: max pass, then sum pass
#pragma unroll
    for (int mt = 0; mt < 4; ++mt) {
#pragma unroll
        for (int reg = 0; reg < 4; ++reg) {
            float v0 = acc[mt][0][reg], v1 = acc[mt][1][reg];
            float v2 = acc[mt][2][reg], v3 = acc[mt][3][reg];
            float mx = fmaxf(fmaxf(v0, v1), fmaxf(v2, v3));
#pragma unroll
            for (int d = 1; d < 16; d <<= 1) mx = fmaxf(mx, __shfl_xor(mx, d, 64));
            float sm = __expf(v0 - mx) + __expf(v1 - mx) + __expf(v2 - mx) + __expf(v3 - mx);
#pragma unroll
            for (int d = 1; d < 16; d <<= 1) sm += __shfl_xor(sm, d, 64);
            if (m == 0) {
                int row = rt * 128 + wy * 64 + mt * 16 + q * 4 + reg;
                pmax[(size_t)row * 64 + ct * 2 + wx] = mx;
                psum[(size_t)row * 64 + ct * 2 + wx] = sm;
            }
        }
    }
}

// combine 64 col-tile partials per row -> per-row loss term
__global__ __launch_bounds__(256) void row_finalize_kernel(const float* __restrict__ pmax,
        const float* __restrict__ psum, const float* __restrict__ diagv,
        const int* __restrict__ label, float* __restrict__ terms) {
    int gid  = blockIdx.x * blockDim.x + threadIdx.x;
    int row  = gid >> 6;
    int lane = threadIdx.x & 63;
    if (row >= BATCH) return;
    float m = pmax[(size_t)row * 64 + lane];
    float s = psum[(size_t)row * 64 + lane];
    float M = m;
#pragma unroll
    for (int d = 1; d < 64; d <<= 1) M = fmaxf(M, __shfl_xor(M, d, 64));
    s *= __expf(m - M);
#pragma unroll
    for (int d = 1; d < 64; d <<= 1) s += __shfl_xor(s, d, 64);
    if (lane == 0) {
        float lse = M + __logf(s);
        terms[row] = -(float)label[row] * (diagv[row] - lse);
    }
}

__global__ __launch_bounds__(256) void final_sum_kernel(const float* __restrict__ terms,
                                                        float* __restrict__ out) {
    __shared__ float red[256];
    float s = 0.0f;
    for (int i = threadIdx.x; i < BATCH; i += 256) s += terms[i];
    red[threadIdx.x] = s;
    __syncthreads();
    for (int w = 128; w > 0; w >>= 1) {
        if (threadIdx.x < (unsigned)w) red[threadIdx.x] += red[threadIdx.x + w];
        __syncthreads();
    }
    // contrastive mean + triplet loss (identically 1.0: d_ap==d_an, relu(margin)=1)
    if (threadIdx.x == 0) out[0] = red[0] / (float)BATCH + 1.0f;
}

// ---------------------------------------------------------------------------
extern "C" void kernel_launch(void* const* d_in, const int* in_sizes, int n_in,
                              void* d_out, int out_size, void* d_ws, size_t ws_size,
                              hipStream_t stream) {
    const float* image   = (const float*)d_in[0];
    const float* x_nodes = (const float*)d_in[1];
    const int*   edge    = (const int*)d_in[2];
    const int*   label   = (const int*)d_in[3];
    const float* W_img1  = (const float*)d_in[4];
    const float* b_img1  = (const float*)d_in[5];
    const float* W_img2  = (const float*)d_in[6];
    const float* b_img2  = (const float*)d_in[7];
    const float* W_g1    = (const float*)d_in[8];
    const float* b_g1    = (const float*)d_in[9];
    const float* W_g2    = (const float*)d_in[10];
    const float* b_g2    = (const float*)d_in[11];
    const int* src = edge;              // edge_index[0]
    const int* dst = edge + N_EDGES;    // edge_index[1]

    // workspace carve-up (256B aligned regions)
    char* ws = (char*)d_ws;
    size_t off = 0;
    auto alloc = [&](size_t bytes) { size_t r = off; off = (off + bytes + 255) & ~(size_t)255; return r; };
    float* dinv     = (float*)(ws + alloc(N_NODES * 4));
    int*   cnt      = (int*)  (ws + alloc(N_NODES * 4));
    int*   offs     = (int*)  (ws + alloc((N_NODES + 1) * 4));
    int*   cursor   = (int*)  (ws + alloc(N_NODES * 4));
    int*   csr      = (int*)  (ws + alloc(N_EDGES * 4));
    int*   flag     = (int*)  (ws + alloc(N_NODES * 4));
    int*   pos      = (int*)  (ws + alloc(N_NODES * 4));
    int*   nodelist = (int*)  (ws + alloc(BATCH * 4));
    int*   pcnt     = (int*)  (ws + alloc(4));
    int*   bsum     = (int*)  (ws + alloc(64 * 4));
    float* xw1    = (float*)(ws + alloc((size_t)N_NODES * HID * 4));
    float* h      = (float*)(ws + alloc((size_t)N_NODES * HID * 4));
    float* g2in   = (float*)(ws + alloc((size_t)BATCH * HID * 4));    // (A-hat h) on compact rows
    float* g2out  = (float*)(ws + alloc((size_t)BATCH * DIM * 4));    // compact gout rows
    float* himg   = (float*)(ws + alloc((size_t)BATCH * HID * 4));
    float* img    = (float*)(ws + alloc((size_t)BATCH * DIM * 4));
    unsigned short* Aext = (unsigned short*)(ws + alloc((size_t)BATCH * KEXT * 2));
    unsigned short* Bext = (unsigned short*)(ws + alloc((size_t)BATCH * KEXT * 2));
    float* pmax   = (float*)(ws + alloc((size_t)BATCH * 64 * 4));
    float* psum   = (float*)(ws + alloc((size_t)BATCH * 64 * 4));
    float* diagv  = (float*)(ws + alloc(BATCH * 4));
    float* terms  = (float*)(ws + alloc(BATCH * 4));

    const int SCAN_BLOCKS = (N_NODES + 255) / 256;   // 40

    // graph build: CSR by dst + symmetric-norm coefficients + label compaction
    zero_init_kernel<<<SCAN_BLOCKS, 256, 0, stream>>>(cnt, cursor, flag, pcnt);
    count_deg_kernel<<<(N_EDGES + 255) / 256, 256, 0, stream>>>(dst, cnt);
    mark_labels_kernel<<<(BATCH + 255) / 256, 256, 0, stream>>>(label, flag);
    scanA_kernel<<<SCAN_BLOCKS, 256, 0, stream>>>(cnt, offs, bsum, dinv);
    scanB_kernel<<<1, 64, 0, stream>>>(bsum, SCAN_BLOCKS);
    scanC_kernel<<<SCAN_BLOCKS, 256, 0, stream>>>(offs, bsum);
    fill_csr_kernel<<<(N_EDGES + 255) / 256, 256, 0, stream>>>(dst, offs, cursor, csr);
    compact_kernel<<<SCAN_BLOCKS, 256, 0, stream>>>(flag, pcnt, nodelist, pos);

    // GCN layer 1: xw1 = x_nodes @ W_g1 ; h = relu(A-hat xw1 + b1)
    gemm_nn_kernel<0, 0><<<dim3(HID / BN, (N_NODES + BM - 1) / BM), 256, 0, stream>>>(
        x_nodes, W_g1, nullptr, xw1, N_NODES, HID, DIM);
    agg256_kernel<1, 1, 0><<<(N_NODES + 3) / 4, 256, 0, stream>>>(
        xw1, dinv, src, offs, csr, b_g1, h, nullptr, nullptr);

    // GCN layer 2 (reordered, compact): g2in = A-hat h (label rows only);
    // g2out = g2in @ W_g2 + b2
    agg256_kernel<0, 0, 1><<<BATCH / 4, 256, 0, stream>>>(
        h, dinv, src, offs, csr, nullptr, g2in, nodelist, pcnt);
    gemm_nn_kernel<1, 0><<<dim3(DIM / BN, BATCH / BM), 256, 0, stream>>>(
        g2in, W_g2, b_g2, g2out, BATCH, DIM, HID);

    // image MLP: himg = relu(image@W1+b1) ; img = relu(himg@W2+b2)
    gemm_nn_kernel<1, 1><<<dim3(HID / BN, BATCH / BM), 256, 0, stream>>>(
        image, W_img1, b_img1, himg, BATCH, HID, DIM);
    gemm_nn_kernel<1, 1><<<dim3(DIM / BN, BATCH / BM), 256, 0, stream>>>(
        himg, W_img2, b_img2, img, BATCH, DIM, HID);

    // split-bf16 K-extended operand build (A gathers compact gout rows via pos[label])
    build_ext_kernel<0><<<(BATCH * 128) / 256, 256, 0, stream>>>(g2out, label, pos, Aext);
    build_ext_kernel<1><<<(BATCH * 128) / 256, 256, 0, stream>>>(img, label, pos, Bext);

    // fused logits (bf16x3 MFMA, barrier-free pipelined) + online softmax partials
    logits_mfma_kernel<<<dim3(BATCH / 128, BATCH / 128), 256, 0, stream>>>(
        Aext, Bext, pmax, psum, diagv);
    row_finalize_kernel<<<(BATCH * 64) / 256, 256, 0, stream>>>(pmax, psum, diagv, label, terms);
    final_sum_kernel<<<1, 256, 0, stream>>>(terms, (float*)d_out);
}

// Round 5
// 464.657 us; speedup vs baseline: 1.1550x; 1.1550x over previous
//
#include <hip/hip_runtime.h>
#include <hip/hip_bf16.h>
#include <math.h>

// Problem constants (fixed by the reference)
#define N_NODES 10000
#define N_EDGES 160000
#define BATCH   4096
#define DIM     512
#define HID     256
#define KEXT    1536   // 3 x 512: split-bf16 product expansion for logits

typedef short short8 __attribute__((ext_vector_type(8)));
typedef float f32x4  __attribute__((ext_vector_type(4)));

// ---------------------------------------------------------------------------
// graph build utilities
// ---------------------------------------------------------------------------
__global__ void zero_init_kernel(int* cnt, int* cursor, int* flag, int* pcnt) {
    int i = blockIdx.x * blockDim.x + threadIdx.x;
    if (i < N_NODES) { cnt[i] = 0; cursor[i] = 0; flag[i] = 0; }
    if (i == 0) pcnt[0] = 0;
}

__global__ void count_deg_kernel(const int* __restrict__ dst, int* __restrict__ cnt) {
    int e = blockIdx.x * blockDim.x + threadIdx.x;
    if (e < N_EDGES) atomicAdd(&cnt[dst[e]], 1);
}

__global__ void mark_labels_kernel(const int* __restrict__ label, int* __restrict__ flag) {
    int b = blockIdx.x * blockDim.x + threadIdx.x;
    if (b < BATCH) flag[label[b]] = 1;          // idempotent, races benign
}

// block-local scan (256/block) + per-block sums; also computes dinv
__global__ __launch_bounds__(256) void scanA_kernel(const int* __restrict__ cnt,
        int* __restrict__ offs, int* __restrict__ bsum, float* __restrict__ dinv) {
    __shared__ int sh[256];
    int i = blockIdx.x * 256 + threadIdx.x;
    int v = (i < N_NODES) ? cnt[i] : 0;
    if (i < N_NODES) dinv[i] = rsqrtf((float)(1 + v));
    sh[threadIdx.x] = v;
    __syncthreads();
    for (int off = 1; off < 256; off <<= 1) {
        int t = (threadIdx.x >= (unsigned)off) ? sh[threadIdx.x - off] : 0;
        __syncthreads();
        sh[threadIdx.x] += t;
        __syncthreads();
    }
    if (i < N_NODES) offs[i] = sh[threadIdx.x] - v;   // exclusive within block
    if (threadIdx.x == 255) bsum[blockIdx.x] = sh[255];
}

__global__ void scanB_kernel(int* bsum, int nblocks) {
    if (threadIdx.x == 0 && blockIdx.x == 0) {
        int a = 0;
        for (int b = 0; b < nblocks; ++b) { int t = bsum[b]; bsum[b] = a; a += t; }
    }
}

__global__ __launch_bounds__(256) void scanC_kernel(int* __restrict__ offs,
                                                    const int* __restrict__ bsum) {
    int i = blockIdx.x * 256 + threadIdx.x;
    if (i < N_NODES) offs[i] += bsum[blockIdx.x];
    if (i == 0) offs[N_NODES] = N_EDGES;
}

__global__ void fill_csr_kernel(const int* __restrict__ dst, const int* __restrict__ offs,
                                int* __restrict__ cursor, int* __restrict__ csr) {
    int e = blockIdx.x * blockDim.x + threadIdx.x;
    if (e < N_EDGES) {
        int d = dst[e];
        int p = offs[d] + atomicAdd(&cursor[d], 1);
        csr[p] = e;
    }
}

__global__ void compact_kernel(const int* __restrict__ flag, int* __restrict__ pcnt,
                               int* __restrict__ nodelist, int* __restrict__ pos) {
    int n = blockIdx.x * blockDim.x + threadIdx.x;
    if (n < N_NODES && flag[n]) {
        int p = atomicAdd(pcnt, 1);
        nodelist[p] = n;
        pos[n] = p;
    }
}

// ---------------------------------------------------------------------------
// GCN aggregation over 256 channels: wave-per-node, float4 per lane.
// ---------------------------------------------------------------------------
template <int BIAS, int RELU, int COMPACT>
__global__ __launch_bounds__(256) void agg256_kernel(const float* __restrict__ xw,
        const float* __restrict__ dinv, const int* __restrict__ src,
        const int* __restrict__ offs, const int* __restrict__ csr,
        const float* __restrict__ bias, float* __restrict__ out,
        const int* __restrict__ nodelist, const int* __restrict__ pcnt) {
    int wid  = blockIdx.x * 4 + (threadIdx.x >> 6);
    int lane = threadIdx.x & 63;
    int n;
    if (COMPACT) { if (wid >= pcnt[0]) return; n = nodelist[wid]; }
    else         { if (wid >= N_NODES) return; n = wid; }
    int c4 = lane * 4;
    float di = dinv[n];
    float d2 = di * di;
    float4 self = *(const float4*)&xw[(size_t)n * 256 + c4];
    float4 a = make_float4(d2 * self.x, d2 * self.y, d2 * self.z, d2 * self.w);
    int s0 = offs[n], s1 = offs[n + 1];
    for (int i = s0; i < s1; ++i) {
        int e  = csr[i];
        int sr = src[e];
        float wgt = di * dinv[sr];
        float4 v = *(const float4*)&xw[(size_t)sr * 256 + c4];
        a.x = fmaf(wgt, v.x, a.x); a.y = fmaf(wgt, v.y, a.y);
        a.z = fmaf(wgt, v.z, a.z); a.w = fmaf(wgt, v.w, a.w);
    }
    if (BIAS) {
        float4 b = *(const float4*)&bias[c4];
        a.x += b.x; a.y += b.y; a.z += b.z; a.w += b.w;
    }
    if (RELU) {
        a.x = fmaxf(a.x, 0.f); a.y = fmaxf(a.y, 0.f);
        a.z = fmaxf(a.z, 0.f); a.w = fmaxf(a.w, 0.f);
    }
    int orow = COMPACT ? wid : n;
    *(float4*)&out[(size_t)orow * 256 + c4] = a;
}

// ---------------------------------------------------------------------------
// split-bf16 helpers
// ---------------------------------------------------------------------------
__device__ __forceinline__ unsigned short f2bf(float x) {
    unsigned u = __float_as_uint(x);
    return (unsigned short)((u + 0x7FFFu + ((u >> 16) & 1u)) >> 16);   // RNE
}
__device__ __forceinline__ float bf2f(unsigned short h) {
    return __uint_as_float(((unsigned)h) << 16);
}

// Row-ext build: src [M][K] fp32 (row-major, optional row gather) ->
// dst [M][3K] bf16. SEGB=0 (A-side): [hi|lo|hi]. SEGB=1 (B-side): [hi|hi|lo].
// grid = M*K/4/256 exactly; kshift = log2(K/4).
template <int SEGB, int GATHER>
__global__ __launch_bounds__(256) void build_rowext_kernel(const float* __restrict__ src,
        const int* __restrict__ label, const int* __restrict__ pos,
        unsigned short* __restrict__ dst, int kshift, int K) {
    int id = blockIdx.x * 256 + threadIdx.x;
    int r  = id >> kshift;
    int c4 = (id & ((1 << kshift) - 1)) << 2;
    int srow = GATHER ? pos[label[r]] : r;
    float4 v = *(const float4*)&src[(size_t)srow * K + c4];
    ushort4 h, l;
    h.x = f2bf(v.x); l.x = f2bf(v.x - bf2f(h.x));
    h.y = f2bf(v.y); l.y = f2bf(v.y - bf2f(h.y));
    h.z = f2bf(v.z); l.z = f2bf(v.z - bf2f(h.z));
    h.w = f2bf(v.w); l.w = f2bf(v.w - bf2f(h.w));
    unsigned short* base = dst + (size_t)r * 3 * K;
    *(ushort4*)&base[c4]         = h;
    *(ushort4*)&base[K + c4]     = SEGB ? h : l;
    *(ushort4*)&base[2 * K + c4] = SEGB ? l : h;
}

// Col-ext build (transpose): src [K][N] fp32 -> dst [N][3K] bf16, B-side [hi|hi|lo].
// grid = N*K/4/256 exactly; kshift = log2(K/4).
__global__ __launch_bounds__(256) void build_colext_kernel(const float* __restrict__ src,
        unsigned short* __restrict__ dst, int kshift, int K, int N) {
    int id = blockIdx.x * 256 + threadIdx.x;
    int n  = id >> kshift;
    int c4 = (id & ((1 << kshift) - 1)) << 2;
    float v0 = src[(size_t)(c4 + 0) * N + n];
    float v1 = src[(size_t)(c4 + 1) * N + n];
    float v2 = src[(size_t)(c4 + 2) * N + n];
    float v3 = src[(size_t)(c4 + 3) * N + n];
    ushort4 h, l;
    h.x = f2bf(v0); l.x = f2bf(v0 - bf2f(h.x));
    h.y = f2bf(v1); l.y = f2bf(v1 - bf2f(h.y));
    h.z = f2bf(v2); l.z = f2bf(v2 - bf2f(h.z));
    h.w = f2bf(v3); l.w = f2bf(v3 - bf2f(h.w));
    unsigned short* base = dst + (size_t)n * 3 * K;
    *(ushort4*)&base[c4]         = h;
    *(ushort4*)&base[K + c4]     = h;
    *(ushort4*)&base[2 * K + c4] = l;
}

// ---------------------------------------------------------------------------
__device__ __forceinline__ void gld_lds16(const void* g, void* l) {
    __builtin_amdgcn_global_load_lds(
        (const __attribute__((address_space(1))) unsigned int*)g,
        (__attribute__((address_space(3))) unsigned int*)l, 16, 0, 0);
}

// ---------------------------------------------------------------------------
// Dense MFMA GEMM on ext operands: C[M,N] = Aext[M,KE] . Bext[N,KE]^T
// tile 128x64, BK=32, 4 waves (2x2), wave = 64x32 via 4x2 16x16x32 MFMAs.
// Fragment-order LDS (conflict-free), global_load_lds w=16, row-clamped staging,
// guarded stores. 12 KB LDS; __launch_bounds__(256,4) targets 4 blocks/CU.
// ---------------------------------------------------------------------------
template <int BIAS, int RELU>
__global__ __launch_bounds__(256, 4) void mfma_gemm_kernel(
        const unsigned short* __restrict__ Aext, const unsigned short* __restrict__ Bext,
        const float* __restrict__ bias, float* __restrict__ C, int M, int N, int KE) {
    __shared__ __align__(16) unsigned short sh[6144];   // A 8KB + B 4KB
    int t    = threadIdx.x;
    int lane = t & 63;
    int w    = t >> 6;
    int wy   = w >> 1, wx = w & 1;
    int rt   = blockIdx.y, ct = blockIdx.x;
    int m    = lane & 15;
    int q    = lane >> 4;

    int ra0 = rt * 128 + w * 16 + m;        if (ra0 > M - 1) ra0 = M - 1;
    int ra1 = rt * 128 + (4 + w) * 16 + m;  if (ra1 > M - 1) ra1 = M - 1;
    int rb  = ct * 64 + w * 16 + m;         // always < N (grid exact in N)
    const unsigned short* pa0 = Aext + (size_t)ra0 * KE + q * 8;
    const unsigned short* pa1 = Aext + (size_t)ra1 * KE + q * 8;
    const unsigned short* pb  = Bext + (size_t)rb  * KE + q * 8;
    unsigned short* lA0 = sh + w * 512;
    unsigned short* lA1 = sh + (4 + w) * 512;
    unsigned short* lB  = sh + 4096 + w * 512;

    f32x4 acc[4][2];
#pragma unroll
    for (int i = 0; i < 4; ++i)
#pragma unroll
        for (int j = 0; j < 2; ++j) acc[i][j] = (f32x4){0.f, 0.f, 0.f, 0.f};

    for (int k0 = 0; k0 < KE; k0 += 32) {
        gld_lds16(pa0, lA0); gld_lds16(pa1, lA1); gld_lds16(pb, lB);
        pa0 += 32; pa1 += 32; pb += 32;
        __syncthreads();
        short8 af[4], bf[2];
#pragma unroll
        for (int i = 0; i < 4; ++i) af[i] = *(const short8*)&sh[(wy * 4 + i) * 512 + lane * 8];
#pragma unroll
        for (int j = 0; j < 2; ++j) bf[j] = *(const short8*)&sh[4096 + (wx * 2 + j) * 512 + lane * 8];
#pragma unroll
        for (int i = 0; i < 4; ++i)
#pragma unroll
            for (int j = 0; j < 2; ++j)
                acc[i][j] = __builtin_amdgcn_mfma_f32_16x16x32_bf16(af[i], bf[j], acc[i][j], 0, 0, 0);
        __syncthreads();
    }

    // C/D layout: col = lane&15 (=m), row = q*4 + reg within each 16x16 tile
    float b0 = 0.f, b1 = 0.f;
    if (BIAS) {
        b0 = bias[ct * 64 + wx * 32 + m];
        b1 = bias[ct * 64 + wx * 32 + 16 + m];
    }
#pragma unroll
    for (int i = 0; i < 4; ++i) {
        int rbase = rt * 128 + wy * 64 + i * 16 + q * 4;
#pragma unroll
        for (int j = 0; j < 2; ++j) {
            int col = ct * 64 + wx * 32 + j * 16 + m;
            float bb = j ? b1 : b0;
#pragma unroll
            for (int reg = 0; reg < 4; ++reg) {
                int row = rbase + reg;
                if (row < M) {
                    float v = acc[i][j][reg] + bb;
                    if (RELU) v = fmaxf(v, 0.f);
                    C[(size_t)row * N + col] = v;
                }
            }
        }
    }
}

// ---------------------------------------------------------------------------
// logits = Aext @ Bext^T (bf16x3 MFMA, K=1536) + fused online softmax partials.
// R2-proven structure: 128x128 tile, BK=32, single 16KB buffer, two barriers.
// __launch_bounds__(256,4): cap 128 unified regs -> 4 blocks/CU (kill the tail gen).
// ---------------------------------------------------------------------------
__global__ __launch_bounds__(256, 4) void logits_mfma_kernel(
        const unsigned short* __restrict__ Aext, const unsigned short* __restrict__ Bext,
        float* __restrict__ pmax, float* __restrict__ psum, float* __restrict__ diagv) {
    __shared__ __align__(16) unsigned short sh[8192];   // 16 KB: A 8KB + B 8KB
    unsigned short* As = sh;
    unsigned short* Bs = sh + 4096;

    int t    = threadIdx.x;
    int lane = t & 63;
    int w    = t >> 6;            // wave 0..3
    int wy   = w >> 1, wx = w & 1;
    int rt   = blockIdx.y, ct = blockIdx.x;
    int m    = lane & 15;         // fragment row within 16
    int q    = lane >> 4;         // k-chunk quad

    const unsigned short* ap0 = Aext + (size_t)(rt * 128 + w * 16 + m) * KEXT + q * 8;
    const unsigned short* ap1 = ap0 + (size_t)64 * KEXT;
    const unsigned short* bp0 = Bext + (size_t)(ct * 128 + w * 16 + m) * KEXT + q * 8;
    const unsigned short* bp1 = bp0 + (size_t)64 * KEXT;
    unsigned short* lA0 = As + w * 512;
    unsigned short* lA1 = As + (4 + w) * 512;
    unsigned short* lB0 = Bs + w * 512;
    unsigned short* lB1 = Bs + (4 + w) * 512;

    f32x4 acc[4][4];
#pragma unroll
    for (int i = 0; i < 4; ++i)
#pragma unroll
        for (int j = 0; j < 4; ++j) acc[i][j] = (f32x4){0.f, 0.f, 0.f, 0.f};

    for (int k0 = 0; k0 < KEXT; k0 += 32) {
        gld_lds16(ap0, lA0);  gld_lds16(ap1, lA1);
        gld_lds16(bp0, lB0);  gld_lds16(bp1, lB1);
        ap0 += 32; ap1 += 32; bp0 += 32; bp1 += 32;
        __syncthreads();                 // drains vmcnt: staging complete
        short8 af[4], bf[4];
#pragma unroll
        for (int i = 0; i < 4; ++i) af[i] = *(const short8*)&As[(wy * 4 + i) * 512 + lane * 8];
#pragma unroll
        for (int i = 0; i < 4; ++i) bf[i] = *(const short8*)&Bs[(wx * 4 + i) * 512 + lane * 8];
#pragma unroll
        for (int i = 0; i < 4; ++i)
#pragma unroll
            for (int j = 0; j < 4; ++j)
                acc[i][j] = __builtin_amdgcn_mfma_f32_16x16x32_bf16(af[i], bf[j], acc[i][j], 0, 0, 0);
        __syncthreads();                 // WAR before next staging
    }

    // C/D layout: col = lane&15, row = q*4 + reg (within each 16x16 tile)
    if (rt == ct && wy == wx) {
        int reg = m - q * 4;
        if (reg >= 0 && reg < 4) {
#pragma unroll
            for (int mt = 0; mt < 4; ++mt) {
                f32x4 dvv = acc[mt][mt];
                float dv = (reg == 0) ? dvv.x : (reg == 1) ? dvv.y : (reg == 2) ? dvv.z : dvv.w;
                diagv[rt * 128 + wy * 64 + mt * 16 + m] = dv;
            }
        }
    }

    // per-row (max, sumexp) over this wave's 64 cols
#pragma unroll
    for (int mt = 0; mt < 4; ++mt) {
#pragma unroll
        for (int reg = 0; reg < 4; ++reg) {
            float v0 = acc[mt][0][reg], v1 = acc[mt][1][reg];
            float v2 = acc[mt][2][reg], v3 = acc[mt][3][reg];
            float mx = fmaxf(fmaxf(v0, v1), fmaxf(v2, v3));
#pragma unroll
            for (int d = 1; d < 16; d <<= 1) mx = fmaxf(mx, __shfl_xor(mx, d, 64));
            float sm = __expf(v0 - mx) + __expf(v1 - mx) + __expf(v2 - mx) + __expf(v3 - mx);
#pragma unroll
            for (int d = 1; d < 16; d <<= 1) sm += __shfl_xor(sm, d, 64);
            if (m == 0) {
                int row = rt * 128 + wy * 64 + mt * 16 + q * 4 + reg;
                pmax[(size_t)row * 64 + ct * 2 + wx] = mx;
                psum[(size_t)row * 64 + ct * 2 + wx] = sm;
            }
        }
    }
}

// combine 64 col-tile partials per row -> per-row loss term
__global__ __launch_bounds__(256) void row_finalize_kernel(const float* __restrict__ pmax,
        const float* __restrict__ psum, const float* __restrict__ diagv,
        const int* __restrict__ label, float* __restrict__ terms) {
    int gid  = blockIdx.x * blockDim.x + threadIdx.x;
    int row  = gid >> 6;
    int lane = threadIdx.x & 63;
    if (row >= BATCH) return;
    float m = pmax[(size_t)row * 64 + lane];
    float s = psum[(size_t)row * 64 + lane];
    float M = m;
#pragma unroll
    for (int d = 1; d < 64; d <<= 1) M = fmaxf(M, __shfl_xor(M, d, 64));
    s *= __expf(m - M);
#pragma unroll
    for (int d = 1; d < 64; d <<= 1) s += __shfl_xor(s, d, 64);
    if (lane == 0) {
        float lse = M + __logf(s);
        terms[row] = -(float)label[row] * (diagv[row] - lse);
    }
}

__global__ __launch_bounds__(256) void final_sum_kernel(const float* __restrict__ terms,
                                                        float* __restrict__ out) {
    __shared__ float red[256];
    float s = 0.0f;
    for (int i = threadIdx.x; i < BATCH; i += 256) s += terms[i];
    red[threadIdx.x] = s;
    __syncthreads();
    for (int w = 128; w > 0; w >>= 1) {
        if (threadIdx.x < (unsigned)w) red[threadIdx.x] += red[threadIdx.x + w];
        __syncthreads();
    }
    // contrastive mean + triplet loss (identically 1.0: d_ap==d_an, relu(margin)=1)
    if (threadIdx.x == 0) out[0] = red[0] / (float)BATCH + 1.0f;
}

// ---------------------------------------------------------------------------
extern "C" void kernel_launch(void* const* d_in, const int* in_sizes, int n_in,
                              void* d_out, int out_size, void* d_ws, size_t ws_size,
                              hipStream_t stream) {
    const float* image   = (const float*)d_in[0];
    const float* x_nodes = (const float*)d_in[1];
    const int*   edge    = (const int*)d_in[2];
    const int*   label   = (const int*)d_in[3];
    const float* W_img1  = (const float*)d_in[4];
    const float* b_img1  = (const float*)d_in[5];
    const float* W_img2  = (const float*)d_in[6];
    const float* b_img2  = (const float*)d_in[7];
    const float* W_g1    = (const float*)d_in[8];
    const float* b_g1    = (const float*)d_in[9];
    const float* W_g2    = (const float*)d_in[10];
    const float* b_g2    = (const float*)d_in[11];
    const int* src = edge;              // edge_index[0]
    const int* dst = edge + N_EDGES;    // edge_index[1]

    // workspace carve-up (256B aligned regions)
    char* ws = (char*)d_ws;
    size_t off = 0;
    auto alloc = [&](size_t bytes) { size_t r = off; off = (off + bytes + 255) & ~(size_t)255; return r; };
    float* dinv     = (float*)(ws + alloc(N_NODES * 4));
    int*   cnt      = (int*)  (ws + alloc(N_NODES * 4));
    int*   offs     = (int*)  (ws + alloc((N_NODES + 1) * 4));
    int*   cursor   = (int*)  (ws + alloc(N_NODES * 4));
    int*   csr      = (int*)  (ws + alloc(N_EDGES * 4));
    int*   flag     = (int*)  (ws + alloc(N_NODES * 4));
    int*   pos      = (int*)  (ws + alloc(N_NODES * 4));
    int*   nodelist = (int*)  (ws + alloc(BATCH * 4));
    int*   pcnt     = (int*)  (ws + alloc(4));
    int*   bsum     = (int*)  (ws + alloc(64 * 4));
    float* xw1   = (float*)(ws + alloc((size_t)N_NODES * HID * 4));
    float* h     = (float*)(ws + alloc((size_t)N_NODES * HID * 4));
    float* g2in  = (float*)(ws + alloc((size_t)BATCH * HID * 4));
    float* g2out = (float*)(ws + alloc((size_t)BATCH * DIM * 4));
    float* himg  = (float*)(ws + alloc((size_t)BATCH * HID * 4));
    float* img   = (float*)(ws + alloc((size_t)BATCH * DIM * 4));
    // serially-reused ext scratch (largest user: x_nodes ext = 10000 x 1536 bf16)
    unsigned short* extbuf = (unsigned short*)(ws + alloc((size_t)N_NODES * 3 * DIM * 2));
    unsigned short* wext1  = (unsigned short*)(ws + alloc((size_t)HID * 3 * DIM * 2));
    unsigned short* wext2  = (unsigned short*)(ws + alloc((size_t)DIM * 3 * HID * 2));
    unsigned short* wext3  = (unsigned short*)(ws + alloc((size_t)HID * 3 * DIM * 2));
    unsigned short* wext4  = (unsigned short*)(ws + alloc((size_t)DIM * 3 * HID * 2));
    unsigned short* Aext   = (unsigned short*)(ws + alloc((size_t)BATCH * KEXT * 2));
    unsigned short* Bext   = (unsigned short*)(ws + alloc((size_t)BATCH * KEXT * 2));
    float* pmax  = (float*)(ws + alloc((size_t)BATCH * 64 * 4));
    float* psum  = (float*)(ws + alloc((size_t)BATCH * 64 * 4));
    float* diagv = (float*)(ws + alloc(BATCH * 4));
    float* terms = (float*)(ws + alloc(BATCH * 4));

    const int SCAN_BLOCKS = (N_NODES + 255) / 256;   // 40

    // graph build: CSR by dst + symmetric-norm coefficients + label compaction
    zero_init_kernel<<<SCAN_BLOCKS, 256, 0, stream>>>(cnt, cursor, flag, pcnt);
    count_deg_kernel<<<(N_EDGES + 255) / 256, 256, 0, stream>>>(dst, cnt);
    mark_labels_kernel<<<(BATCH + 255) / 256, 256, 0, stream>>>(label, flag);
    scanA_kernel<<<SCAN_BLOCKS, 256, 0, stream>>>(cnt, offs, bsum, dinv);
    scanB_kernel<<<1, 64, 0, stream>>>(bsum, SCAN_BLOCKS);
    scanC_kernel<<<SCAN_BLOCKS, 256, 0, stream>>>(offs, bsum);
    fill_csr_kernel<<<(N_EDGES + 255) / 256, 256, 0, stream>>>(dst, offs, cursor, csr);
    compact_kernel<<<SCAN_BLOCKS, 256, 0, stream>>>(flag, pcnt, nodelist, pos);

    // GCN layer 1: xw1 = x_nodes @ W_g1 (MFMA bf16x3); h = relu(A-hat xw1 + b1)
    build_rowext_kernel<0, 0><<<(N_NODES * (DIM / 4)) / 256, 256, 0, stream>>>(
        x_nodes, nullptr, nullptr, extbuf, 7, DIM);
    build_colext_kernel<<<(HID * (DIM / 4)) / 256, 256, 0, stream>>>(W_g1, wext1, 7, DIM, HID);
    mfma_gemm_kernel<0, 0><<<dim3(HID / 64, (N_NODES + 127) / 128), 256, 0, stream>>>(
        extbuf, wext1, nullptr, xw1, N_NODES, HID, 3 * DIM);
    agg256_kernel<1, 1, 0><<<(N_NODES + 3) / 4, 256, 0, stream>>>(
        xw1, dinv, src, offs, csr, b_g1, h, nullptr, nullptr);

    // GCN layer 2 (reordered, compact): g2in = A-hat h (label rows); g2out = g2in@W_g2+b2
    agg256_kernel<0, 0, 1><<<BATCH / 4, 256, 0, stream>>>(
        h, dinv, src, offs, csr, nullptr, g2in, nodelist, pcnt);
    build_rowext_kernel<0, 0><<<(BATCH * (HID / 4)) / 256, 256, 0, stream>>>(
        g2in, nullptr, nullptr, extbuf, 6, HID);
    build_colext_kernel<<<(DIM * (HID / 4)) / 256, 256, 0, stream>>>(W_g2, wext2, 6, HID, DIM);
    mfma_gemm_kernel<1, 0><<<dim3(DIM / 64, BATCH / 128), 256, 0, stream>>>(
        extbuf, wext2, b_g2, g2out, BATCH, DIM, 3 * HID);

    // image MLP: himg = relu(image@W1+b1) ; img = relu(himg@W2+b2)
    build_rowext_kernel<0, 0><<<(BATCH * (DIM / 4)) / 256, 256, 0, stream>>>(
        image, nullptr, nullptr, extbuf, 7, DIM);
    build_colext_kernel<<<(HID * (DIM / 4)) / 256, 256, 0, stream>>>(W_img1, wext3, 7, DIM, HID);
    mfma_gemm_kernel<1, 1><<<dim3(HID / 64, BATCH / 128), 256, 0, stream>>>(
        extbuf, wext3, b_img1, himg, BATCH, HID, 3 * DIM);
    build_rowext_kernel<0, 0><<<(BATCH * (HID / 4)) / 256, 256, 0, stream>>>(
        himg, nullptr, nullptr, extbuf, 6, HID);
    build_colext_kernel<<<(DIM * (HID / 4)) / 256, 256, 0, stream>>>(W_img2, wext4, 6, HID, DIM);
    mfma_gemm_kernel<1, 1><<<dim3(DIM / 64, BATCH / 128), 256, 0, stream>>>(
        extbuf, wext4, b_img2, img, BATCH, DIM, 3 * HID);

    // logits operands (A gathers compact g2out rows via pos[label]; B = img rows)
    build_rowext_kernel<0, 1><<<(BATCH * (DIM / 4)) / 256, 256, 0, stream>>>(
        g2out, label, pos, Aext, 7, DIM);
    build_rowext_kernel<1, 0><<<(BATCH * (DIM / 4)) / 256, 256, 0, stream>>>(
        img, nullptr, nullptr, Bext, 7, DIM);

    // fused logits (bf16x3 MFMA) + online softmax partials; then per-row LSE + mean
    logits_mfma_kernel<<<dim3(BATCH / 128, BATCH / 128), 256, 0, stream>>>(
        Aext, Bext, pmax, psum, diagv);
    row_finalize_kernel<<<(BATCH * 64) / 256, 256, 0, stream>>>(pmax, psum, diagv, label, terms);
    final_sum_kernel<<<1, 256, 0, stream>>>(terms, (float*)d_out);
}

// Round 6
// 429.108 us; speedup vs baseline: 1.2506x; 1.0828x over previous
//
#include <hip/hip_runtime.h>
#include <hip/hip_bf16.h>
#include <math.h>

// Problem constants (fixed by the reference)
#define N_NODES 10000
#define N_EDGES 160000
#define BATCH   4096
#define DIM     512
#define HID     256
#define KEXT    1536   // 3 x 512: split-bf16 product expansion for logits

typedef short short8 __attribute__((ext_vector_type(8)));
typedef float f32x4  __attribute__((ext_vector_type(4)));

// ---------------------------------------------------------------------------
// graph build utilities
// ---------------------------------------------------------------------------
__global__ void zero_init_kernel(int* cnt, int* cursor, int* flag, int* pcnt) {
    int i = blockIdx.x * blockDim.x + threadIdx.x;
    if (i < N_NODES) { cnt[i] = 0; cursor[i] = 0; flag[i] = 0; }
    if (i == 0) pcnt[0] = 0;
}

// degree count + label marking in one pass
__global__ void count_mark_kernel(const int* __restrict__ dst, const int* __restrict__ label,
                                  int* __restrict__ cnt, int* __restrict__ flag) {
    int e = blockIdx.x * blockDim.x + threadIdx.x;
    if (e < N_EDGES) atomicAdd(&cnt[dst[e]], 1);
    if (e < BATCH) flag[label[e]] = 1;          // idempotent, races benign
}

// block-local scan (256/block) + per-block sums; also computes dinv
__global__ __launch_bounds__(256) void scanA_kernel(const int* __restrict__ cnt,
        int* __restrict__ offs, int* __restrict__ bsum, float* __restrict__ dinv) {
    __shared__ int sh[256];
    int i = blockIdx.x * 256 + threadIdx.x;
    int v = (i < N_NODES) ? cnt[i] : 0;
    if (i < N_NODES) dinv[i] = rsqrtf((float)(1 + v));
    sh[threadIdx.x] = v;
    __syncthreads();
    for (int off = 1; off < 256; off <<= 1) {
        int t = (threadIdx.x >= (unsigned)off) ? sh[threadIdx.x - off] : 0;
        __syncthreads();
        sh[threadIdx.x] += t;
        __syncthreads();
    }
    if (i < N_NODES) offs[i] = sh[threadIdx.x] - v;   // exclusive within block
    if (threadIdx.x == 255) bsum[blockIdx.x] = sh[255];
}

__global__ void scanB_kernel(int* bsum, int nblocks) {
    if (threadIdx.x == 0 && blockIdx.x == 0) {
        int a = 0;
        for (int b = 0; b < nblocks; ++b) { int t = bsum[b]; bsum[b] = a; a += t; }
    }
}

__global__ __launch_bounds__(256) void scanC_kernel(int* __restrict__ offs,
                                                    const int* __restrict__ bsum) {
    int i = blockIdx.x * 256 + threadIdx.x;
    if (i < N_NODES) offs[i] += bsum[blockIdx.x];
    if (i == 0) offs[N_NODES] = N_EDGES;
}

// CSR fill storing (src id, dinv[src]) directly — one less indirection in agg
__global__ void fill_csr_kernel(const int* __restrict__ src, const int* __restrict__ dst,
                                const int* __restrict__ offs, const float* __restrict__ dinv,
                                int* __restrict__ cursor, int* __restrict__ csr_src,
                                float* __restrict__ csr_w) {
    int e = blockIdx.x * blockDim.x + threadIdx.x;
    if (e < N_EDGES) {
        int d = dst[e];
        int s = src[e];
        int p = offs[d] + atomicAdd(&cursor[d], 1);
        csr_src[p] = s;
        csr_w[p]   = dinv[s];
    }
}

__global__ void compact_kernel(const int* __restrict__ flag, int* __restrict__ pcnt,
                               int* __restrict__ nodelist, int* __restrict__ pos) {
    int n = blockIdx.x * blockDim.x + threadIdx.x;
    if (n < N_NODES && flag[n]) {
        int p = atomicAdd(pcnt, 1);
        nodelist[p] = n;
        pos[n] = p;
    }
}

// ---------------------------------------------------------------------------
// split-bf16 helpers
// ---------------------------------------------------------------------------
__device__ __forceinline__ unsigned short f2bf(float x) {
    unsigned u = __float_as_uint(x);
    return (unsigned short)((u + 0x7FFFu + ((u >> 16) & 1u)) >> 16);   // RNE
}
__device__ __forceinline__ float bf2f(unsigned short h) {
    return __uint_as_float(((unsigned)h) << 16);
}

// ---------------------------------------------------------------------------
// GCN aggregation over 256 channels: wave-per-node, float4 per lane.
// EXTOUT: emit A-side split-bf16 ext row [hi|lo|hi] (3x256) instead of fp32.
// ---------------------------------------------------------------------------
template <int BIAS, int RELU, int COMPACT, int EXTOUT>
__global__ __launch_bounds__(256) void agg256_kernel(const float* __restrict__ xw,
        const float* __restrict__ dinv, const int* __restrict__ csr_src,
        const float* __restrict__ csr_w, const int* __restrict__ offs,
        const float* __restrict__ bias, void* __restrict__ out,
        const int* __restrict__ nodelist, const int* __restrict__ pcnt) {
    int wid  = blockIdx.x * 4 + (threadIdx.x >> 6);
    int lane = threadIdx.x & 63;
    int n;
    if (COMPACT) { if (wid >= pcnt[0]) return; n = nodelist[wid]; }
    else         { if (wid >= N_NODES) return; n = wid; }
    int c4 = lane * 4;
    float di = dinv[n];
    float d2 = di * di;
    float4 self = *(const float4*)&xw[(size_t)n * 256 + c4];
    float4 a = make_float4(d2 * self.x, d2 * self.y, d2 * self.z, d2 * self.w);
    int s0 = offs[n], s1 = offs[n + 1];
    int i = s0;
    for (; i + 1 < s1; i += 2) {              // 2 gathers in flight
        int sr0 = csr_src[i], sr1 = csr_src[i + 1];
        float w0 = di * csr_w[i], w1 = di * csr_w[i + 1];
        float4 v0 = *(const float4*)&xw[(size_t)sr0 * 256 + c4];
        float4 v1 = *(const float4*)&xw[(size_t)sr1 * 256 + c4];
        a.x = fmaf(w0, v0.x, a.x); a.y = fmaf(w0, v0.y, a.y);
        a.z = fmaf(w0, v0.z, a.z); a.w = fmaf(w0, v0.w, a.w);
        a.x = fmaf(w1, v1.x, a.x); a.y = fmaf(w1, v1.y, a.y);
        a.z = fmaf(w1, v1.z, a.z); a.w = fmaf(w1, v1.w, a.w);
    }
    if (i < s1) {
        int sr = csr_src[i];
        float wgt = di * csr_w[i];
        float4 v = *(const float4*)&xw[(size_t)sr * 256 + c4];
        a.x = fmaf(wgt, v.x, a.x); a.y = fmaf(wgt, v.y, a.y);
        a.z = fmaf(wgt, v.z, a.z); a.w = fmaf(wgt, v.w, a.w);
    }
    if (BIAS) {
        float4 b = *(const float4*)&bias[c4];
        a.x += b.x; a.y += b.y; a.z += b.z; a.w += b.w;
    }
    if (RELU) {
        a.x = fmaxf(a.x, 0.f); a.y = fmaxf(a.y, 0.f);
        a.z = fmaxf(a.z, 0.f); a.w = fmaxf(a.w, 0.f);
    }
    int orow = COMPACT ? wid : n;
    if (EXTOUT) {
        ushort4 h, l;
        h.x = f2bf(a.x); l.x = f2bf(a.x - bf2f(h.x));
        h.y = f2bf(a.y); l.y = f2bf(a.y - bf2f(h.y));
        h.z = f2bf(a.z); l.z = f2bf(a.z - bf2f(h.z));
        h.w = f2bf(a.w); l.w = f2bf(a.w - bf2f(h.w));
        unsigned short* ob = (unsigned short*)out + (size_t)orow * 768;
        *(ushort4*)&ob[c4]       = h;
        *(ushort4*)&ob[256 + c4] = l;
        *(ushort4*)&ob[512 + c4] = h;
    } else {
        *(float4*)((float*)out + (size_t)orow * 256 + c4) = a;
    }
}

// Row-ext build: src [M][K] fp32 (optional row gather) -> dst [M][3K] bf16.
// SEGB=0 (A-side): [hi|lo|hi]. SEGB=1 (B-side): [hi|hi|lo]. kshift = log2(K/4).
template <int SEGB, int GATHER>
__global__ __launch_bounds__(256) void build_rowext_kernel(const float* __restrict__ src,
        const int* __restrict__ label, const int* __restrict__ pos,
        unsigned short* __restrict__ dst, int kshift, int K) {
    int id = blockIdx.x * 256 + threadIdx.x;
    int r  = id >> kshift;
    int c4 = (id & ((1 << kshift) - 1)) << 2;
    int srow = GATHER ? pos[label[r]] : r;
    float4 v = *(const float4*)&src[(size_t)srow * K + c4];
    ushort4 h, l;
    h.x = f2bf(v.x); l.x = f2bf(v.x - bf2f(h.x));
    h.y = f2bf(v.y); l.y = f2bf(v.y - bf2f(h.y));
    h.z = f2bf(v.z); l.z = f2bf(v.z - bf2f(h.z));
    h.w = f2bf(v.w); l.w = f2bf(v.w - bf2f(h.w));
    unsigned short* base = dst + (size_t)r * 3 * K;
    *(ushort4*)&base[c4]         = h;
    *(ushort4*)&base[K + c4]     = SEGB ? h : l;
    *(ushort4*)&base[2 * K + c4] = SEGB ? l : h;
}

// Col-ext build (transpose): src [K][N] fp32 -> dst [N][3K] bf16, B-side [hi|hi|lo].
__global__ __launch_bounds__(256) void build_colext_kernel(const float* __restrict__ src,
        unsigned short* __restrict__ dst, int kshift, int K, int N) {
    int id = blockIdx.x * 256 + threadIdx.x;
    int n  = id >> kshift;
    int c4 = (id & ((1 << kshift) - 1)) << 2;
    float v0 = src[(size_t)(c4 + 0) * N + n];
    float v1 = src[(size_t)(c4 + 1) * N + n];
    float v2 = src[(size_t)(c4 + 2) * N + n];
    float v3 = src[(size_t)(c4 + 3) * N + n];
    ushort4 h, l;
    h.x = f2bf(v0); l.x = f2bf(v0 - bf2f(h.x));
    h.y = f2bf(v1); l.y = f2bf(v1 - bf2f(h.y));
    h.z = f2bf(v2); l.z = f2bf(v2 - bf2f(h.z));
    h.w = f2bf(v3); l.w = f2bf(v3 - bf2f(h.w));
    unsigned short* base = dst + (size_t)n * 3 * K;
    *(ushort4*)&base[c4]         = h;
    *(ushort4*)&base[K + c4]     = h;
    *(ushort4*)&base[2 * K + c4] = l;
}

// ---------------------------------------------------------------------------
__device__ __forceinline__ void gld_lds16(const void* g, void* l) {
    __builtin_amdgcn_global_load_lds(
        (const __attribute__((address_space(1))) unsigned int*)g,
        (__attribute__((address_space(3))) unsigned int*)l, 16, 0, 0);
}

// ---------------------------------------------------------------------------
// Dense MFMA GEMM on ext operands: C[M,N] = Aext[M,KE] . Bext[N,KE]^T
// tile 128x64, BK=32, 4 waves (2x2), wave = 64x32 via 4x2 16x16x32 MFMAs.
// EXT=0: fp32 out. EXT=1: A-side ext bf16 out [hi|lo|hi]. EXT=2: B-side [hi|hi|lo].
// ---------------------------------------------------------------------------
template <int BIAS, int RELU, int EXT>
__global__ __launch_bounds__(256, 4) void mfma_gemm_kernel(
        const unsigned short* __restrict__ Aext, const unsigned short* __restrict__ Bext,
        const float* __restrict__ bias, void* __restrict__ Cout, int M, int N, int KE) {
    __shared__ __align__(16) unsigned short sh[6144];   // A 8KB + B 4KB
    int t    = threadIdx.x;
    int lane = t & 63;
    int w    = t >> 6;
    int wy   = w >> 1, wx = w & 1;
    int rt   = blockIdx.y, ct = blockIdx.x;
    int m    = lane & 15;
    int q    = lane >> 4;

    int ra0 = rt * 128 + w * 16 + m;        if (ra0 > M - 1) ra0 = M - 1;
    int ra1 = rt * 128 + (4 + w) * 16 + m;  if (ra1 > M - 1) ra1 = M - 1;
    int rb  = ct * 64 + w * 16 + m;         // always < N (grid exact in N)
    const unsigned short* pa0 = Aext + (size_t)ra0 * KE + q * 8;
    const unsigned short* pa1 = Aext + (size_t)ra1 * KE + q * 8;
    const unsigned short* pb  = Bext + (size_t)rb  * KE + q * 8;
    unsigned short* lA0 = sh + w * 512;
    unsigned short* lA1 = sh + (4 + w) * 512;
    unsigned short* lB  = sh + 4096 + w * 512;

    f32x4 acc[4][2];
#pragma unroll
    for (int i = 0; i < 4; ++i)
#pragma unroll
        for (int j = 0; j < 2; ++j) acc[i][j] = (f32x4){0.f, 0.f, 0.f, 0.f};

    for (int k0 = 0; k0 < KE; k0 += 32) {
        gld_lds16(pa0, lA0); gld_lds16(pa1, lA1); gld_lds16(pb, lB);
        pa0 += 32; pa1 += 32; pb += 32;
        __syncthreads();
        short8 af[4], bf[2];
#pragma unroll
        for (int i = 0; i < 4; ++i) af[i] = *(const short8*)&sh[(wy * 4 + i) * 512 + lane * 8];
#pragma unroll
        for (int j = 0; j < 2; ++j) bf[j] = *(const short8*)&sh[4096 + (wx * 2 + j) * 512 + lane * 8];
#pragma unroll
        for (int i = 0; i < 4; ++i)
#pragma unroll
            for (int j = 0; j < 2; ++j)
                acc[i][j] = __builtin_amdgcn_mfma_f32_16x16x32_bf16(af[i], bf[j], acc[i][j], 0, 0, 0);
        __syncthreads();
    }

    // C/D layout: col = lane&15 (=m), row = q*4 + reg within each 16x16 tile
    float b0 = 0.f, b1 = 0.f;
    if (BIAS) {
        b0 = bias[ct * 64 + wx * 32 + m];
        b1 = bias[ct * 64 + wx * 32 + 16 + m];
    }
#pragma unroll
    for (int i = 0; i < 4; ++i) {
        int rbase = rt * 128 + wy * 64 + i * 16 + q * 4;
#pragma unroll
        for (int j = 0; j < 2; ++j) {
            int col = ct * 64 + wx * 32 + j * 16 + m;
            float bb = j ? b1 : b0;
#pragma unroll
            for (int reg = 0; reg < 4; ++reg) {
                int row = rbase + reg;
                if (row < M) {
                    float v = acc[i][j][reg] + bb;
                    if (RELU) v = fmaxf(v, 0.f);
                    if (EXT == 0) {
                        ((float*)Cout)[(size_t)row * N + col] = v;
                    } else {
                        unsigned short hi = f2bf(v);
                        unsigned short lo = f2bf(v - bf2f(hi));
                        unsigned short* ob = (unsigned short*)Cout + (size_t)row * 3 * N;
                        if (EXT == 1) { ob[col] = hi; ob[N + col] = lo; ob[2 * N + col] = hi; }
                        else          { ob[col] = hi; ob[N + col] = hi; ob[2 * N + col] = lo; }
                    }
                }
            }
        }
    }
}

// ---------------------------------------------------------------------------
// logits = Aext @ Bext^T (bf16x3 MFMA, K=1536) + fused online softmax partials.
// 128x128 tile, BK=64 (32 MFMAs + 8 staging loads per barrier pair), single
// 32 KB buffer, fragment-order LDS (conflict-free), 4 blocks/CU target.
// ---------------------------------------------------------------------------
__global__ __launch_bounds__(256, 4) void logits_mfma_kernel(
        const unsigned short* __restrict__ Aext, const unsigned short* __restrict__ Bext,
        float* __restrict__ pmax, float* __restrict__ psum, float* __restrict__ diagv) {
    __shared__ __align__(16) unsigned short sh[16384];   // 32 KB: A 16KB + B 16KB
    unsigned short* As = sh;
    unsigned short* Bs = sh + 8192;

    int t    = threadIdx.x;
    int lane = t & 63;
    int w    = t >> 6;            // wave 0..3
    int wy   = w >> 1, wx = w & 1;
    int rt   = blockIdx.y, ct = blockIdx.x;
    int m    = lane & 15;         // fragment row within 16
    int q    = lane >> 4;         // k-chunk quad

    const unsigned short* ap0 = Aext + (size_t)(rt * 128 + w * 16 + m) * KEXT + q * 8;
    const unsigned short* ap1 = ap0 + (size_t)64 * KEXT;
    const unsigned short* bp0 = Bext + (size_t)(ct * 128 + w * 16 + m) * KEXT + q * 8;
    const unsigned short* bp1 = bp0 + (size_t)64 * KEXT;
    // LDS chunk (block b, k-half h) at (b*2+h)*512
    unsigned short* dA00 = As + (w * 2 + 0) * 512;
    unsigned short* dA01 = As + (w * 2 + 1) * 512;
    unsigned short* dA10 = As + ((4 + w) * 2 + 0) * 512;
    unsigned short* dA11 = As + ((4 + w) * 2 + 1) * 512;
    unsigned short* dB00 = Bs + (w * 2 + 0) * 512;
    unsigned short* dB01 = Bs + (w * 2 + 1) * 512;
    unsigned short* dB10 = Bs + ((4 + w) * 2 + 0) * 512;
    unsigned short* dB11 = Bs + ((4 + w) * 2 + 1) * 512;

    f32x4 acc[4][4];
#pragma unroll
    for (int i = 0; i < 4; ++i)
#pragma unroll
        for (int j = 0; j < 4; ++j) acc[i][j] = (f32x4){0.f, 0.f, 0.f, 0.f};

    for (int k0 = 0; k0 < KEXT; k0 += 64) {
        gld_lds16(ap0, dA00); gld_lds16(ap0 + 32, dA01);
        gld_lds16(ap1, dA10); gld_lds16(ap1 + 32, dA11);
        gld_lds16(bp0, dB00); gld_lds16(bp0 + 32, dB01);
        gld_lds16(bp1, dB10); gld_lds16(bp1 + 32, dB11);
        ap0 += 64; ap1 += 64; bp0 += 64; bp1 += 64;
        __syncthreads();                 // drains vmcnt: staging complete
#pragma unroll
        for (int h = 0; h < 2; ++h) {
            short8 af[4], bf[4];
#pragma unroll
            for (int i = 0; i < 4; ++i)
                af[i] = *(const short8*)&As[((wy * 4 + i) * 2 + h) * 512 + lane * 8];
#pragma unroll
            for (int i = 0; i < 4; ++i)
                bf[i] = *(const short8*)&Bs[((wx * 4 + i) * 2 + h) * 512 + lane * 8];
#pragma unroll
            for (int i = 0; i < 4; ++i)
#pragma unroll
                for (int j = 0; j < 4; ++j)
                    acc[i][j] = __builtin_amdgcn_mfma_f32_16x16x32_bf16(af[i], bf[j], acc[i][j], 0, 0, 0);
        }
        __syncthreads();                 // WAR before next staging
    }

    // C/D layout: col = lane&15, row = q*4 + reg (within each 16x16 tile)
    if (rt == ct && wy == wx) {
        int reg = m - q * 4;
        if (reg >= 0 && reg < 4) {
#pragma unroll
            for (int mt = 0; mt < 4; ++mt) {
                f32x4 dvv = acc[mt][mt];
                float dv = (reg == 0) ? dvv.x : (reg == 1) ? dvv.y : (reg == 2) ? dvv.z : dvv.w;
                diagv[rt * 128 + wy * 64 + mt * 16 + m] = dv;
            }
        }
    }

    // per-row (max, sumexp) over this wave's 64 cols
#pragma unroll
    for (int mt = 0; mt < 4; ++mt) {
#pragma unroll
        for (int reg = 0; reg < 4; ++reg) {
            float v0 = acc[mt][0][reg], v1 = acc[mt][1][reg];
            float v2 = acc[mt][2][reg], v3 = acc[mt][3][reg];
            float mx = fmaxf(fmaxf(v0, v1), fmaxf(v2, v3));
#pragma unroll
            for (int d = 1; d < 16; d <<= 1) mx = fmaxf(mx, __shfl_xor(mx, d, 64));
            float sm = __expf(v0 - mx) + __expf(v1 - mx) + __expf(v2 - mx) + __expf(v3 - mx);
#pragma unroll
            for (int d = 1; d < 16; d <<= 1) sm += __shfl_xor(sm, d, 64);
            if (m == 0) {
                int row = rt * 128 + wy * 64 + mt * 16 + q * 4 + reg;
                pmax[(size_t)row * 64 + ct * 2 + wx] = mx;
                psum[(size_t)row * 64 + ct * 2 + wx] = sm;
            }
        }
    }
}

// combine 64 col-tile partials per row -> per-row loss term
__global__ __launch_bounds__(256) void row_finalize_kernel(const float* __restrict__ pmax,
        const float* __restrict__ psum, const float* __restrict__ diagv,
        const int* __restrict__ label, float* __restrict__ terms) {
    int gid  = blockIdx.x * blockDim.x + threadIdx.x;
    int row  = gid >> 6;
    int lane = threadIdx.x & 63;
    if (row >= BATCH) return;
    float m = pmax[(size_t)row * 64 + lane];
    float s = psum[(size_t)row * 64 + lane];
    float M = m;
#pragma unroll
    for (int d = 1; d < 64; d <<= 1) M = fmaxf(M, __shfl_xor(M, d, 64));
    s *= __expf(m - M);
#pragma unroll
    for (int d = 1; d < 64; d <<= 1) s += __shfl_xor(s, d, 64);
    if (lane == 0) {
        float lse = M + __logf(s);
        terms[row] = -(float)label[row] * (diagv[row] - lse);
    }
}

__global__ __launch_bounds__(256) void final_sum_kernel(const float* __restrict__ terms,
                                                        float* __restrict__ out) {
    __shared__ float red[256];
    float s = 0.0f;
    for (int i = threadIdx.x; i < BATCH; i += 256) s += terms[i];
    red[threadIdx.x] = s;
    __syncthreads();
    for (int w = 128; w > 0; w >>= 1) {
        if (threadIdx.x < (unsigned)w) red[threadIdx.x] += red[threadIdx.x + w];
        __syncthreads();
    }
    // contrastive mean + triplet loss (identically 1.0: d_ap==d_an, relu(margin)=1)
    if (threadIdx.x == 0) out[0] = red[0] / (float)BATCH + 1.0f;
}

// ---------------------------------------------------------------------------
extern "C" void kernel_launch(void* const* d_in, const int* in_sizes, int n_in,
                              void* d_out, int out_size, void* d_ws, size_t ws_size,
                              hipStream_t stream) {
    const float* image   = (const float*)d_in[0];
    const float* x_nodes = (const float*)d_in[1];
    const int*   edge    = (const int*)d_in[2];
    const int*   label   = (const int*)d_in[3];
    const float* W_img1  = (const float*)d_in[4];
    const float* b_img1  = (const float*)d_in[5];
    const float* W_img2  = (const float*)d_in[6];
    const float* b_img2  = (const float*)d_in[7];
    const float* W_g1    = (const float*)d_in[8];
    const float* b_g1    = (const float*)d_in[9];
    const float* W_g2    = (const float*)d_in[10];
    const float* b_g2    = (const float*)d_in[11];
    const int* src = edge;              // edge_index[0]
    const int* dst = edge + N_EDGES;    // edge_index[1]

    // workspace carve-up (256B aligned regions)
    char* ws = (char*)d_ws;
    size_t off = 0;
    auto alloc = [&](size_t bytes) { size_t r = off; off = (off + bytes + 255) & ~(size_t)255; return r; };
    float* dinv     = (float*)(ws + alloc(N_NODES * 4));
    int*   cnt      = (int*)  (ws + alloc(N_NODES * 4));
    int*   offs     = (int*)  (ws + alloc((N_NODES + 1) * 4));
    int*   cursor   = (int*)  (ws + alloc(N_NODES * 4));
    int*   csr_src  = (int*)  (ws + alloc(N_EDGES * 4));
    float* csr_w    = (float*)(ws + alloc(N_EDGES * 4));
    int*   flag     = (int*)  (ws + alloc(N_NODES * 4));
    int*   pos      = (int*)  (ws + alloc(N_NODES * 4));
    int*   nodelist = (int*)  (ws + alloc(BATCH * 4));
    int*   pcnt     = (int*)  (ws + alloc(4));
    int*   bsum     = (int*)  (ws + alloc(64 * 4));
    float* xw1      = (float*)(ws + alloc((size_t)N_NODES * HID * 4));
    float* h        = (float*)(ws + alloc((size_t)N_NODES * HID * 4));
    unsigned short* g2inext = (unsigned short*)(ws + alloc((size_t)BATCH * 3 * HID * 2));
    float* g2out    = (float*)(ws + alloc((size_t)BATCH * DIM * 4));
    unsigned short* himgext = (unsigned short*)(ws + alloc((size_t)BATCH * 3 * HID * 2));
    // serially-reused ext scratch (largest user: x_nodes ext = 10000 x 1536 bf16)
    unsigned short* extbuf = (unsigned short*)(ws + alloc((size_t)N_NODES * 3 * DIM * 2));
    unsigned short* wext1  = (unsigned short*)(ws + alloc((size_t)HID * 3 * DIM * 2));
    unsigned short* wext2  = (unsigned short*)(ws + alloc((size_t)DIM * 3 * HID * 2));
    unsigned short* wext3  = (unsigned short*)(ws + alloc((size_t)HID * 3 * DIM * 2));
    unsigned short* wext4  = (unsigned short*)(ws + alloc((size_t)DIM * 3 * HID * 2));
    unsigned short* Aext   = (unsigned short*)(ws + alloc((size_t)BATCH * KEXT * 2));
    unsigned short* Bext   = (unsigned short*)(ws + alloc((size_t)BATCH * KEXT * 2));
    float* pmax  = (float*)(ws + alloc((size_t)BATCH * 64 * 4));
    float* psum  = (float*)(ws + alloc((size_t)BATCH * 64 * 4));
    float* diagv = (float*)(ws + alloc(BATCH * 4));
    float* terms = (float*)(ws + alloc(BATCH * 4));

    const int SCAN_BLOCKS = (N_NODES + 255) / 256;   // 40

    // graph build: CSR by dst (storing src+weight) + dinv + label compaction
    zero_init_kernel<<<SCAN_BLOCKS, 256, 0, stream>>>(cnt, cursor, flag, pcnt);
    count_mark_kernel<<<(N_EDGES + 255) / 256, 256, 0, stream>>>(dst, label, cnt, flag);
    scanA_kernel<<<SCAN_BLOCKS, 256, 0, stream>>>(cnt, offs, bsum, dinv);
    scanB_kernel<<<1, 64, 0, stream>>>(bsum, SCAN_BLOCKS);
    scanC_kernel<<<SCAN_BLOCKS, 256, 0, stream>>>(offs, bsum);
    fill_csr_kernel<<<(N_EDGES + 255) / 256, 256, 0, stream>>>(src, dst, offs, dinv,
                                                               cursor, csr_src, csr_w);
    compact_kernel<<<SCAN_BLOCKS, 256, 0, stream>>>(flag, pcnt, nodelist, pos);

    // GCN layer 1: xw1 = x_nodes @ W_g1 (MFMA bf16x3); h = relu(A-hat xw1 + b1)
    build_rowext_kernel<0, 0><<<(N_NODES * (DIM / 4)) / 256, 256, 0, stream>>>(
        x_nodes, nullptr, nullptr, extbuf, 7, DIM);
    build_colext_kernel<<<(HID * (DIM / 4)) / 256, 256, 0, stream>>>(W_g1, wext1, 7, DIM, HID);
    mfma_gemm_kernel<0, 0, 0><<<dim3(HID / 64, (N_NODES + 127) / 128), 256, 0, stream>>>(
        extbuf, wext1, nullptr, xw1, N_NODES, HID, 3 * DIM);
    agg256_kernel<1, 1, 0, 0><<<(N_NODES + 3) / 4, 256, 0, stream>>>(
        xw1, dinv, csr_src, csr_w, offs, b_g1, h, nullptr, nullptr);

    // GCN layer 2 (reordered, compact): g2inext = ext(A-hat h) on label rows;
    // g2out = g2in @ W_g2 + b2  (fp32: Aext gather needs arbitrary row access)
    agg256_kernel<0, 0, 1, 1><<<BATCH / 4, 256, 0, stream>>>(
        h, dinv, csr_src, csr_w, offs, nullptr, g2inext, nodelist, pcnt);
    build_colext_kernel<<<(DIM * (HID / 4)) / 256, 256, 0, stream>>>(W_g2, wext2, 6, HID, DIM);
    mfma_gemm_kernel<1, 0, 0><<<dim3(DIM / 64, BATCH / 128), 256, 0, stream>>>(
        g2inext, wext2, b_g2, g2out, BATCH, DIM, 3 * HID);

    // image MLP: himgext = ext(relu(image@W1+b1)); Bext = ext(relu(himg@W2+b2))
    build_rowext_kernel<0, 0><<<(BATCH * (DIM / 4)) / 256, 256, 0, stream>>>(
        image, nullptr, nullptr, extbuf, 7, DIM);
    build_colext_kernel<<<(HID * (DIM / 4)) / 256, 256, 0, stream>>>(W_img1, wext3, 7, DIM, HID);
    mfma_gemm_kernel<1, 1, 1><<<dim3(HID / 64, BATCH / 128), 256, 0, stream>>>(
        extbuf, wext3, b_img1, himgext, BATCH, HID, 3 * DIM);
    build_colext_kernel<<<(DIM * (HID / 4)) / 256, 256, 0, stream>>>(W_img2, wext4, 6, HID, DIM);
    mfma_gemm_kernel<1, 1, 2><<<dim3(DIM / 64, BATCH / 128), 256, 0, stream>>>(
        himgext, wext4, b_img2, Bext, BATCH, DIM, 3 * HID);

    // logits A operand: gather compact g2out rows via pos[label]
    build_rowext_kernel<0, 1><<<(BATCH * (DIM / 4)) / 256, 256, 0, stream>>>(
        g2out, label, pos, Aext, 7, DIM);

    // fused logits (bf16x3 MFMA, BK=64) + online softmax partials; then LSE + mean
    logits_mfma_kernel<<<dim3(BATCH / 128, BATCH / 128), 256, 0, stream>>>(
        Aext, Bext, pmax, psum, diagv);
    row_finalize_kernel<<<(BATCH * 64) / 256, 256, 0, stream>>>(pmax, psum, diagv, label, terms);
    final_sum_kernel<<<1, 256, 0, stream>>>(terms, (float*)d_out);
}

// Round 7
// 356.316 us; speedup vs baseline: 1.5061x; 1.2043x over previous
//
#include <hip/hip_runtime.h>
#include <hip/hip_bf16.h>
#include <math.h>

// Problem constants (fixed by the reference)
#define N_NODES 10000
#define N_EDGES 160000
#define BATCH   4096
#define DIM     512
#define HID     256

typedef short short8 __attribute__((ext_vector_type(8)));
typedef float f32x4  __attribute__((ext_vector_type(4)));

// ---------------------------------------------------------------------------
// graph build utilities
// ---------------------------------------------------------------------------
__global__ void zero_init_kernel(int* cnt, int* cursor, int* flag, int* pcnt) {
    int i = blockIdx.x * blockDim.x + threadIdx.x;
    if (i < N_NODES) { cnt[i] = 0; cursor[i] = 0; flag[i] = 0; }
    if (i == 0) pcnt[0] = 0;
}

// degree count + label marking in one pass
__global__ void count_mark_kernel(const int* __restrict__ dst, const int* __restrict__ label,
                                  int* __restrict__ cnt, int* __restrict__ flag) {
    int e = blockIdx.x * blockDim.x + threadIdx.x;
    if (e < N_EDGES) atomicAdd(&cnt[dst[e]], 1);
    if (e < BATCH) flag[label[e]] = 1;          // idempotent, races benign
}

// block-local scan (256/block) + per-block sums; also computes dinv
__global__ __launch_bounds__(256) void scanA_kernel(const int* __restrict__ cnt,
        int* __restrict__ offs, int* __restrict__ bsum, float* __restrict__ dinv) {
    __shared__ int sh[256];
    int i = blockIdx.x * 256 + threadIdx.x;
    int v = (i < N_NODES) ? cnt[i] : 0;
    if (i < N_NODES) dinv[i] = rsqrtf((float)(1 + v));
    sh[threadIdx.x] = v;
    __syncthreads();
    for (int off = 1; off < 256; off <<= 1) {
        int t = (threadIdx.x >= (unsigned)off) ? sh[threadIdx.x - off] : 0;
        __syncthreads();
        sh[threadIdx.x] += t;
        __syncthreads();
    }
    if (i < N_NODES) offs[i] = sh[threadIdx.x] - v;   // exclusive within block
    if (threadIdx.x == 255) bsum[blockIdx.x] = sh[255];
}

__global__ void scanB_kernel(int* bsum, int nblocks) {
    if (threadIdx.x == 0 && blockIdx.x == 0) {
        int a = 0;
        for (int b = 0; b < nblocks; ++b) { int t = bsum[b]; bsum[b] = a; a += t; }
    }
}

__global__ __launch_bounds__(256) void scanC_kernel(int* __restrict__ offs,
                                                    const int* __restrict__ bsum) {
    int i = blockIdx.x * 256 + threadIdx.x;
    if (i < N_NODES) offs[i] += bsum[blockIdx.x];
    if (i == 0) offs[N_NODES] = N_EDGES;
}

// CSR fill storing (src id, dinv[src]) directly
__global__ void fill_csr_kernel(const int* __restrict__ src, const int* __restrict__ dst,
                                const int* __restrict__ offs, const float* __restrict__ dinv,
                                int* __restrict__ cursor, int* __restrict__ csr_src,
                                float* __restrict__ csr_w) {
    int e = blockIdx.x * blockDim.x + threadIdx.x;
    if (e < N_EDGES) {
        int d = dst[e];
        int s = src[e];
        int p = offs[d] + atomicAdd(&cursor[d], 1);
        csr_src[p] = s;
        csr_w[p]   = dinv[s];
    }
}

__global__ void compact_kernel(const int* __restrict__ flag, int* __restrict__ pcnt,
                               int* __restrict__ nodelist, int* __restrict__ pos) {
    int n = blockIdx.x * blockDim.x + threadIdx.x;
    if (n < N_NODES && flag[n]) {
        int p = atomicAdd(pcnt, 1);
        nodelist[p] = n;
        pos[n] = p;
    }
}

// ---------------------------------------------------------------------------
// split-bf16 helpers
// ---------------------------------------------------------------------------
__device__ __forceinline__ unsigned short f2bf(float x) {
    unsigned u = __float_as_uint(x);
    return (unsigned short)((u + 0x7FFFu + ((u >> 16) & 1u)) >> 16);   // RNE
}
__device__ __forceinline__ float bf2f(unsigned short h) {
    return __uint_as_float(((unsigned)h) << 16);
}

// ---------------------------------------------------------------------------
// GCN aggregation over 256 channels: wave-per-node, float4 per lane.
// EXTOUT: emit split-bf16 [hi|lo] row (2x256) instead of fp32.
// ---------------------------------------------------------------------------
template <int BIAS, int RELU, int COMPACT, int EXTOUT>
__global__ __launch_bounds__(256) void agg256_kernel(const float* __restrict__ xw,
        const float* __restrict__ dinv, const int* __restrict__ csr_src,
        const float* __restrict__ csr_w, const int* __restrict__ offs,
        const float* __restrict__ bias, void* __restrict__ out,
        const int* __restrict__ nodelist, const int* __restrict__ pcnt) {
    int wid  = blockIdx.x * 4 + (threadIdx.x >> 6);
    int lane = threadIdx.x & 63;
    int n;
    if (COMPACT) { if (wid >= pcnt[0]) return; n = nodelist[wid]; }
    else         { if (wid >= N_NODES) return; n = wid; }
    int c4 = lane * 4;
    float di = dinv[n];
    float d2 = di * di;
    float4 self = *(const float4*)&xw[(size_t)n * 256 + c4];
    float4 a = make_float4(d2 * self.x, d2 * self.y, d2 * self.z, d2 * self.w);
    int s0 = offs[n], s1 = offs[n + 1];
    int i = s0;
    for (; i + 1 < s1; i += 2) {              // 2 gathers in flight
        int sr0 = csr_src[i], sr1 = csr_src[i + 1];
        float w0 = di * csr_w[i], w1 = di * csr_w[i + 1];
        float4 v0 = *(const float4*)&xw[(size_t)sr0 * 256 + c4];
        float4 v1 = *(const float4*)&xw[(size_t)sr1 * 256 + c4];
        a.x = fmaf(w0, v0.x, a.x); a.y = fmaf(w0, v0.y, a.y);
        a.z = fmaf(w0, v0.z, a.z); a.w = fmaf(w0, v0.w, a.w);
        a.x = fmaf(w1, v1.x, a.x); a.y = fmaf(w1, v1.y, a.y);
        a.z = fmaf(w1, v1.z, a.z); a.w = fmaf(w1, v1.w, a.w);
    }
    if (i < s1) {
        int sr = csr_src[i];
        float wgt = di * csr_w[i];
        float4 v = *(const float4*)&xw[(size_t)sr * 256 + c4];
        a.x = fmaf(wgt, v.x, a.x); a.y = fmaf(wgt, v.y, a.y);
        a.z = fmaf(wgt, v.z, a.z); a.w = fmaf(wgt, v.w, a.w);
    }
    if (BIAS) {
        float4 b = *(const float4*)&bias[c4];
        a.x += b.x; a.y += b.y; a.z += b.z; a.w += b.w;
    }
    if (RELU) {
        a.x = fmaxf(a.x, 0.f); a.y = fmaxf(a.y, 0.f);
        a.z = fmaxf(a.z, 0.f); a.w = fmaxf(a.w, 0.f);
    }
    int orow = COMPACT ? wid : n;
    if (EXTOUT) {
        ushort4 h, l;
        h.x = f2bf(a.x); l.x = f2bf(a.x - bf2f(h.x));
        h.y = f2bf(a.y); l.y = f2bf(a.y - bf2f(h.y));
        h.z = f2bf(a.z); l.z = f2bf(a.z - bf2f(h.z));
        h.w = f2bf(a.w); l.w = f2bf(a.w - bf2f(h.w));
        unsigned short* ob = (unsigned short*)out + (size_t)orow * 512;
        *(ushort4*)&ob[c4]       = h;
        *(ushort4*)&ob[256 + c4] = l;
    } else {
        *(float4*)((float*)out + (size_t)orow * 256 + c4) = a;
    }
}

// Row-ext build: src [M][K] fp32 (optional gather) -> dst [M][2K] bf16 [hi|lo].
template <int GATHER>
__global__ __launch_bounds__(256) void build_rowext_kernel(const float* __restrict__ src,
        const int* __restrict__ label, const int* __restrict__ pos,
        unsigned short* __restrict__ dst, int kshift, int K) {
    int id = blockIdx.x * 256 + threadIdx.x;
    int r  = id >> kshift;
    int c4 = (id & ((1 << kshift) - 1)) << 2;
    int srow = GATHER ? pos[label[r]] : r;
    float4 v = *(const float4*)&src[(size_t)srow * K + c4];
    ushort4 h, l;
    h.x = f2bf(v.x); l.x = f2bf(v.x - bf2f(h.x));
    h.y = f2bf(v.y); l.y = f2bf(v.y - bf2f(h.y));
    h.z = f2bf(v.z); l.z = f2bf(v.z - bf2f(h.z));
    h.w = f2bf(v.w); l.w = f2bf(v.w - bf2f(h.w));
    unsigned short* base = dst + (size_t)r * 2 * K;
    *(ushort4*)&base[c4]     = h;
    *(ushort4*)&base[K + c4] = l;
}

// Col-ext build (transpose): src [K][N] fp32 -> dst [N][2K] bf16 [hi|lo].
__global__ __launch_bounds__(256) void build_colext_kernel(const float* __restrict__ src,
        unsigned short* __restrict__ dst, int kshift, int K, int N) {
    int id = blockIdx.x * 256 + threadIdx.x;
    int n  = id >> kshift;
    int c4 = (id & ((1 << kshift) - 1)) << 2;
    float v0 = src[(size_t)(c4 + 0) * N + n];
    float v1 = src[(size_t)(c4 + 1) * N + n];
    float v2 = src[(size_t)(c4 + 2) * N + n];
    float v3 = src[(size_t)(c4 + 3) * N + n];
    ushort4 h, l;
    h.x = f2bf(v0); l.x = f2bf(v0 - bf2f(h.x));
    h.y = f2bf(v1); l.y = f2bf(v1 - bf2f(h.y));
    h.z = f2bf(v2); l.z = f2bf(v2 - bf2f(h.z));
    h.w = f2bf(v3); l.w = f2bf(v3 - bf2f(h.w));
    unsigned short* base = dst + (size_t)n * 2 * K;
    *(ushort4*)&base[c4]     = h;
    *(ushort4*)&base[K + c4] = l;
}

// ---------------------------------------------------------------------------
__device__ __forceinline__ void gld_lds16(const void* g, void* l) {
    __builtin_amdgcn_global_load_lds(
        (const __attribute__((address_space(1))) unsigned int*)g,
        (__attribute__((address_space(3))) unsigned int*)l, 16, 0, 0);
}

// ---------------------------------------------------------------------------
// Dense MFMA GEMM on [hi|lo] ext operands: C[M,N] = A.B^T with 3-product
// split-bf16 (AhiBhi + AloBhi + AhiBlo) per staged 32-K chunk. tile 128x64,
// 4 waves (2x2), wave = 64x32. 24 KB LDS. EXT=0: fp32 out; EXT=1: [hi|lo] out.
// ---------------------------------------------------------------------------
template <int BIAS, int RELU, int EXT>
__global__ __launch_bounds__(256, 4) void mfma_gemm_kernel(
        const unsigned short* __restrict__ Aext, const unsigned short* __restrict__ Bext,
        const float* __restrict__ bias, void* __restrict__ Cout, int M, int N, int K) {
    __shared__ __align__(16) unsigned short sh[12288];  // A 16KB (16 slots) + B 4KB... (16+8)*1KB
    int t    = threadIdx.x;
    int lane = t & 63;
    int w    = t >> 6;
    int wy   = w >> 1, wx = w & 1;
    int rt   = blockIdx.y, ct = blockIdx.x;
    int m    = lane & 15;
    int q    = lane >> 4;

    int ra0 = rt * 128 + w * 16 + m;        if (ra0 > M - 1) ra0 = M - 1;
    int ra1 = rt * 128 + (4 + w) * 16 + m;  if (ra1 > M - 1) ra1 = M - 1;
    int rb  = ct * 64 + w * 16 + m;
    const unsigned short* pa0 = Aext + (size_t)ra0 * 2 * K + q * 8;
    const unsigned short* pa1 = Aext + (size_t)ra1 * 2 * K + q * 8;
    const unsigned short* pb  = Bext + (size_t)rb  * 2 * K + q * 8;
    unsigned short* Bs = sh + 8192;

    f32x4 acc[4][2];
#pragma unroll
    for (int i = 0; i < 4; ++i)
#pragma unroll
        for (int j = 0; j < 2; ++j) acc[i][j] = (f32x4){0.f, 0.f, 0.f, 0.f};

    for (int k0 = 0; k0 < K; k0 += 32) {
        gld_lds16(pa0 + k0,     sh + (w * 2 + 0) * 512);
        gld_lds16(pa0 + K + k0, sh + (w * 2 + 1) * 512);
        gld_lds16(pa1 + k0,     sh + ((4 + w) * 2 + 0) * 512);
        gld_lds16(pa1 + K + k0, sh + ((4 + w) * 2 + 1) * 512);
        gld_lds16(pb + k0,      Bs + (w * 2 + 0) * 512);
        gld_lds16(pb + K + k0,  Bs + (w * 2 + 1) * 512);
        __syncthreads();
        short8 ah[4], al[4];
#pragma unroll
        for (int i = 0; i < 4; ++i) {
            ah[i] = *(const short8*)&sh[((wy * 4 + i) * 2 + 0) * 512 + lane * 8];
            al[i] = *(const short8*)&sh[((wy * 4 + i) * 2 + 1) * 512 + lane * 8];
        }
#pragma unroll
        for (int j = 0; j < 2; ++j) {
            short8 bh = *(const short8*)&Bs[((wx * 2 + j) * 2 + 0) * 512 + lane * 8];
            short8 bl = *(const short8*)&Bs[((wx * 2 + j) * 2 + 1) * 512 + lane * 8];
#pragma unroll
            for (int i = 0; i < 4; ++i) {
                acc[i][j] = __builtin_amdgcn_mfma_f32_16x16x32_bf16(ah[i], bh, acc[i][j], 0, 0, 0);
                acc[i][j] = __builtin_amdgcn_mfma_f32_16x16x32_bf16(al[i], bh, acc[i][j], 0, 0, 0);
                acc[i][j] = __builtin_amdgcn_mfma_f32_16x16x32_bf16(ah[i], bl, acc[i][j], 0, 0, 0);
            }
        }
        __syncthreads();
    }

    // C/D layout: col = lane&15 (=m), row = q*4 + reg within each 16x16 tile
    float b0 = 0.f, b1 = 0.f;
    if (BIAS) {
        b0 = bias[ct * 64 + wx * 32 + m];
        b1 = bias[ct * 64 + wx * 32 + 16 + m];
    }
#pragma unroll
    for (int i = 0; i < 4; ++i) {
        int rbase = rt * 128 + wy * 64 + i * 16 + q * 4;
#pragma unroll
        for (int j = 0; j < 2; ++j) {
            int col = ct * 64 + wx * 32 + j * 16 + m;
            float bb = j ? b1 : b0;
#pragma unroll
            for (int reg = 0; reg < 4; ++reg) {
                int row = rbase + reg;
                if (row < M) {
                    float v = acc[i][j][reg] + bb;
                    if (RELU) v = fmaxf(v, 0.f);
                    if (EXT == 0) {
                        ((float*)Cout)[(size_t)row * N + col] = v;
                    } else {
                        unsigned short hi = f2bf(v);
                        unsigned short lo = f2bf(v - bf2f(hi));
                        unsigned short* ob = (unsigned short*)Cout + (size_t)row * 2 * N;
                        ob[col] = hi; ob[N + col] = lo;
                    }
                }
            }
        }
    }
}

// ---------------------------------------------------------------------------
// logits = A @ B^T on [hi|lo] ext (K=512, 3-product split-bf16) + fused online
// softmax partials. 128x128 tile, 16 K-iters of (8 gld + 48 MFMA)/wave.
// 32 KB LDS; XCD-aware block swizzle (8x16 tile region per XCD).
// ---------------------------------------------------------------------------
__global__ __launch_bounds__(256, 4) void logits_mfma_kernel(
        const unsigned short* __restrict__ Aext, const unsigned short* __restrict__ Bext,
        float* __restrict__ pmax, float* __restrict__ psum, float* __restrict__ diagv) {
    __shared__ __align__(16) unsigned short sh[16384];   // 32 KB: A 16 slots + B 16 slots
    unsigned short* Bs = sh + 8192;

    int t    = threadIdx.x;
    int lane = t & 63;
    int w    = t >> 6;            // wave 0..3
    int wy   = w >> 1, wx = w & 1;
    // XCD-aware swizzle: 1024 blocks; xcd = g&7 gets an 8(rt) x 16(ct) region
    int g   = blockIdx.x;
    int xcd = g & 7, s = g >> 3;
    int rt  = (xcd >> 1) * 8 + (s & 7);
    int ct  = (xcd & 1) * 16 + (s >> 3);
    int m    = lane & 15;         // fragment row within 16
    int q    = lane >> 4;         // k-chunk quad

    const unsigned short* ap0 = Aext + (size_t)(rt * 128 + w * 16 + m) * 1024 + q * 8;
    const unsigned short* ap1 = ap0 + (size_t)64 * 1024;
    const unsigned short* bp0 = Bext + (size_t)(ct * 128 + w * 16 + m) * 1024 + q * 8;
    const unsigned short* bp1 = bp0 + (size_t)64 * 1024;

    f32x4 acc[4][4];
#pragma unroll
    for (int i = 0; i < 4; ++i)
#pragma unroll
        for (int j = 0; j < 4; ++j) acc[i][j] = (f32x4){0.f, 0.f, 0.f, 0.f};

    for (int k0 = 0; k0 < 512; k0 += 32) {
        gld_lds16(ap0 + k0,       sh + (w * 2 + 0) * 512);
        gld_lds16(ap0 + 512 + k0, sh + (w * 2 + 1) * 512);
        gld_lds16(ap1 + k0,       sh + ((4 + w) * 2 + 0) * 512);
        gld_lds16(ap1 + 512 + k0, sh + ((4 + w) * 2 + 1) * 512);
        gld_lds16(bp0 + k0,       Bs + (w * 2 + 0) * 512);
        gld_lds16(bp0 + 512 + k0, Bs + (w * 2 + 1) * 512);
        gld_lds16(bp1 + k0,       Bs + ((4 + w) * 2 + 0) * 512);
        gld_lds16(bp1 + 512 + k0, Bs + ((4 + w) * 2 + 1) * 512);
        __syncthreads();                 // drains vmcnt: staging complete
        short8 ah[4], al[4];
#pragma unroll
        for (int i = 0; i < 4; ++i) {
            ah[i] = *(const short8*)&sh[((wy * 4 + i) * 2 + 0) * 512 + lane * 8];
            al[i] = *(const short8*)&sh[((wy * 4 + i) * 2 + 1) * 512 + lane * 8];
        }
#pragma unroll
        for (int j = 0; j < 4; ++j) {
            short8 bh = *(const short8*)&Bs[((wx * 4 + j) * 2 + 0) * 512 + lane * 8];
            short8 bl = *(const short8*)&Bs[((wx * 4 + j) * 2 + 1) * 512 + lane * 8];
#pragma unroll
            for (int i = 0; i < 4; ++i) {
                acc[i][j] = __builtin_amdgcn_mfma_f32_16x16x32_bf16(ah[i], bh, acc[i][j], 0, 0, 0);
                acc[i][j] = __builtin_amdgcn_mfma_f32_16x16x32_bf16(al[i], bh, acc[i][j], 0, 0, 0);
                acc[i][j] = __builtin_amdgcn_mfma_f32_16x16x32_bf16(ah[i], bl, acc[i][j], 0, 0, 0);
            }
        }
        __syncthreads();                 // WAR before next staging
    }

    // C/D layout: col = lane&15, row = q*4 + reg (within each 16x16 tile)
    if (rt == ct && wy == wx) {
        int reg = m - q * 4;
        if (reg >= 0 && reg < 4) {
#pragma unroll
            for (int mt = 0; mt < 4; ++mt) {
                f32x4 dvv = acc[mt][mt];
                float dv = (reg == 0) ? dvv.x : (reg == 1) ? dvv.y : (reg == 2) ? dvv.z : dvv.w;
                diagv[rt * 128 + wy * 64 + mt * 16 + m] = dv;
            }
        }
    }

    // per-row (max, sumexp) over this wave's 64 cols
#pragma unroll
    for (int mt = 0; mt < 4; ++mt) {
#pragma unroll
        for (int reg = 0; reg < 4; ++reg) {
            float v0 = acc[mt][0][reg], v1 = acc[mt][1][reg];
            float v2 = acc[mt][2][reg], v3 = acc[mt][3][reg];
            float mx = fmaxf(fmaxf(v0, v1), fmaxf(v2, v3));
#pragma unroll
            for (int d = 1; d < 16; d <<= 1) mx = fmaxf(mx, __shfl_xor(mx, d, 64));
            float sm = __expf(v0 - mx) + __expf(v1 - mx) + __expf(v2 - mx) + __expf(v3 - mx);
#pragma unroll
            for (int d = 1; d < 16; d <<= 1) sm += __shfl_xor(sm, d, 64);
            if (m == 0) {
                int row = rt * 128 + wy * 64 + mt * 16 + q * 4 + reg;
                pmax[(size_t)row * 64 + ct * 2 + wx] = mx;
                psum[(size_t)row * 64 + ct * 2 + wx] = sm;
            }
        }
    }
}

// combine 64 col-tile partials per row -> per-row loss term
__global__ __launch_bounds__(256) void row_finalize_kernel(const float* __restrict__ pmax,
        const float* __restrict__ psum, const float* __restrict__ diagv,
        const int* __restrict__ label, float* __restrict__ terms) {
    int gid  = blockIdx.x * blockDim.x + threadIdx.x;
    int row  = gid >> 6;
    int lane = threadIdx.x & 63;
    if (row >= BATCH) return;
    float m = pmax[(size_t)row * 64 + lane];
    float s = psum[(size_t)row * 64 + lane];
    float M = m;
#pragma unroll
    for (int d = 1; d < 64; d <<= 1) M = fmaxf(M, __shfl_xor(M, d, 64));
    s *= __expf(m - M);
#pragma unroll
    for (int d = 1; d < 64; d <<= 1) s += __shfl_xor(s, d, 64);
    if (lane == 0) {
        float lse = M + __logf(s);
        terms[row] = -(float)label[row] * (diagv[row] - lse);
    }
}

__global__ __launch_bounds__(256) void final_sum_kernel(const float* __restrict__ terms,
                                                        float* __restrict__ out) {
    __shared__ float red[256];
    float s = 0.0f;
    for (int i = threadIdx.x; i < BATCH; i += 256) s += terms[i];
    red[threadIdx.x] = s;
    __syncthreads();
    for (int w = 128; w > 0; w >>= 1) {
        if (threadIdx.x < (unsigned)w) red[threadIdx.x] += red[threadIdx.x + w];
        __syncthreads();
    }
    // contrastive mean + triplet loss (identically 1.0: d_ap==d_an, relu(margin)=1)
    if (threadIdx.x == 0) out[0] = red[0] / (float)BATCH + 1.0f;
}

// ---------------------------------------------------------------------------
extern "C" void kernel_launch(void* const* d_in, const int* in_sizes, int n_in,
                              void* d_out, int out_size, void* d_ws, size_t ws_size,
                              hipStream_t stream) {
    const float* image   = (const float*)d_in[0];
    const float* x_nodes = (const float*)d_in[1];
    const int*   edge    = (const int*)d_in[2];
    const int*   label   = (const int*)d_in[3];
    const float* W_img1  = (const float*)d_in[4];
    const float* b_img1  = (const float*)d_in[5];
    const float* W_img2  = (const float*)d_in[6];
    const float* b_img2  = (const float*)d_in[7];
    const float* W_g1    = (const float*)d_in[8];
    const float* b_g1    = (const float*)d_in[9];
    const float* W_g2    = (const float*)d_in[10];
    const float* b_g2    = (const float*)d_in[11];
    const int* src = edge;              // edge_index[0]
    const int* dst = edge + N_EDGES;    // edge_index[1]

    // workspace carve-up (256B aligned regions)
    char* ws = (char*)d_ws;
    size_t off = 0;
    auto alloc = [&](size_t bytes) { size_t r = off; off = (off + bytes + 255) & ~(size_t)255; return r; };
    float* dinv     = (float*)(ws + alloc(N_NODES * 4));
    int*   cnt      = (int*)  (ws + alloc(N_NODES * 4));
    int*   offs     = (int*)  (ws + alloc((N_NODES + 1) * 4));
    int*   cursor   = (int*)  (ws + alloc(N_NODES * 4));
    int*   csr_src  = (int*)  (ws + alloc(N_EDGES * 4));
    float* csr_w    = (float*)(ws + alloc(N_EDGES * 4));
    int*   flag     = (int*)  (ws + alloc(N_NODES * 4));
    int*   pos      = (int*)  (ws + alloc(N_NODES * 4));
    int*   nodelist = (int*)  (ws + alloc(BATCH * 4));
    int*   pcnt     = (int*)  (ws + alloc(4));
    int*   bsum     = (int*)  (ws + alloc(64 * 4));
    float* xw1      = (float*)(ws + alloc((size_t)N_NODES * HID * 4));
    float* h        = (float*)(ws + alloc((size_t)N_NODES * HID * 4));
    unsigned short* g2inext = (unsigned short*)(ws + alloc((size_t)BATCH * 2 * HID * 2));
    float* g2out    = (float*)(ws + alloc((size_t)BATCH * DIM * 4));
    unsigned short* himgext = (unsigned short*)(ws + alloc((size_t)BATCH * 2 * HID * 2));
    unsigned short* extbuf  = (unsigned short*)(ws + alloc((size_t)N_NODES * 2 * DIM * 2));
    unsigned short* wext1   = (unsigned short*)(ws + alloc((size_t)HID * 2 * DIM * 2));
    unsigned short* wext2   = (unsigned short*)(ws + alloc((size_t)DIM * 2 * HID * 2));
    unsigned short* wext3   = (unsigned short*)(ws + alloc((size_t)HID * 2 * DIM * 2));
    unsigned short* wext4   = (unsigned short*)(ws + alloc((size_t)DIM * 2 * HID * 2));
    unsigned short* Aext    = (unsigned short*)(ws + alloc((size_t)BATCH * 2 * DIM * 2));
    unsigned short* Bext    = (unsigned short*)(ws + alloc((size_t)BATCH * 2 * DIM * 2));
    float* pmax  = (float*)(ws + alloc((size_t)BATCH * 64 * 4));
    float* psum  = (float*)(ws + alloc((size_t)BATCH * 64 * 4));
    float* diagv = (float*)(ws + alloc(BATCH * 4));
    float* terms = (float*)(ws + alloc(BATCH * 4));

    const int SCAN_BLOCKS = (N_NODES + 255) / 256;   // 40

    // graph build: CSR by dst (storing src+weight) + dinv + label compaction
    zero_init_kernel<<<SCAN_BLOCKS, 256, 0, stream>>>(cnt, cursor, flag, pcnt);
    count_mark_kernel<<<(N_EDGES + 255) / 256, 256, 0, stream>>>(dst, label, cnt, flag);
    scanA_kernel<<<SCAN_BLOCKS, 256, 0, stream>>>(cnt, offs, bsum, dinv);
    scanB_kernel<<<1, 64, 0, stream>>>(bsum, SCAN_BLOCKS);
    scanC_kernel<<<SCAN_BLOCKS, 256, 0, stream>>>(offs, bsum);
    fill_csr_kernel<<<(N_EDGES + 255) / 256, 256, 0, stream>>>(src, dst, offs, dinv,
                                                               cursor, csr_src, csr_w);
    compact_kernel<<<SCAN_BLOCKS, 256, 0, stream>>>(flag, pcnt, nodelist, pos);

    // GCN layer 1: xw1 = x_nodes @ W_g1 (split-bf16 MFMA); h = relu(A-hat xw1 + b1)
    build_rowext_kernel<0><<<(N_NODES * (DIM / 4)) / 256, 256, 0, stream>>>(
        x_nodes, nullptr, nullptr, extbuf, 7, DIM);
    build_colext_kernel<<<(HID * (DIM / 4)) / 256, 256, 0, stream>>>(W_g1, wext1, 7, DIM, HID);
    mfma_gemm_kernel<0, 0, 0><<<dim3(HID / 64, (N_NODES + 127) / 128), 256, 0, stream>>>(
        extbuf, wext1, nullptr, xw1, N_NODES, HID, DIM);
    agg256_kernel<1, 1, 0, 0><<<(N_NODES + 3) / 4, 256, 0, stream>>>(
        xw1, dinv, csr_src, csr_w, offs, b_g1, h, nullptr, nullptr);

    // GCN layer 2 (reordered, compact): g2inext = ext(A-hat h) on label rows;
    // g2out = g2in @ W_g2 + b2 (fp32 out: logits-A gather needs row access)
    agg256_kernel<0, 0, 1, 1><<<BATCH / 4, 256, 0, stream>>>(
        h, dinv, csr_src, csr_w, offs, nullptr, g2inext, nodelist, pcnt);
    build_colext_kernel<<<(DIM * (HID / 4)) / 256, 256, 0, stream>>>(W_g2, wext2, 6, HID, DIM);
    mfma_gemm_kernel<1, 0, 0><<<dim3(DIM / 64, BATCH / 128), 256, 0, stream>>>(
        g2inext, wext2, b_g2, g2out, BATCH, DIM, HID);

    // image MLP: himgext = ext(relu(image@W1+b1)); Bext = ext(relu(himg@W2+b2))
    build_rowext_kernel<0><<<(BATCH * (DIM / 4)) / 256, 256, 0, stream>>>(
        image, nullptr, nullptr, extbuf, 7, DIM);
    build_colext_kernel<<<(HID * (DIM / 4)) / 256, 256, 0, stream>>>(W_img1, wext3, 7, DIM, HID);
    mfma_gemm_kernel<1, 1, 1><<<dim3(HID / 64, BATCH / 128), 256, 0, stream>>>(
        extbuf, wext3, b_img1, himgext, BATCH, HID, DIM);
    build_colext_kernel<<<(DIM * (HID / 4)) / 256, 256, 0, stream>>>(W_img2, wext4, 6, HID, DIM);
    mfma_gemm_kernel<1, 1, 1><<<dim3(DIM / 64, BATCH / 128), 256, 0, stream>>>(
        himgext, wext4, b_img2, Bext, BATCH, DIM, HID);

    // logits A operand: gather compact g2out rows via pos[label]
    build_rowext_kernel<1><<<(BATCH * (DIM / 4)) / 256, 256, 0, stream>>>(
        g2out, label, pos, Aext, 7, DIM);

    // fused logits (split-bf16 MFMA) + online softmax partials; then LSE + mean
    logits_mfma_kernel<<<1024, 256, 0, stream>>>(Aext, Bext, pmax, psum, diagv);
    row_finalize_kernel<<<(BATCH * 64) / 256, 256, 0, stream>>>(pmax, psum, diagv, label, terms);
    final_sum_kernel<<<1, 256, 0, stream>>>(terms, (float*)d_out);
}

// Round 8
// 336.422 us; speedup vs baseline: 1.5952x; 1.0591x over previous
//
#include <hip/hip_runtime.h>
#include <hip/hip_bf16.h>
#include <math.h>

// Problem constants (fixed by the reference)
#define N_NODES 10000
#define N_EDGES 160000
#define BATCH   4096
#define DIM     512
#define HID     256

typedef short short8 __attribute__((ext_vector_type(8)));
typedef float f32x4  __attribute__((ext_vector_type(4)));

// ---------------------------------------------------------------------------
// graph build utilities
// ---------------------------------------------------------------------------
__global__ void zero_init_kernel(int* cnt, int* cursor, int* flag, int* pcnt) {
    int i = blockIdx.x * blockDim.x + threadIdx.x;
    if (i < N_NODES) { cnt[i] = 0; cursor[i] = 0; flag[i] = 0; }
    if (i == 0) pcnt[0] = 0;
}

// degree count + label marking in one pass
__global__ void count_mark_kernel(const int* __restrict__ dst, const int* __restrict__ label,
                                  int* __restrict__ cnt, int* __restrict__ flag) {
    int e = blockIdx.x * blockDim.x + threadIdx.x;
    if (e < N_EDGES) atomicAdd(&cnt[dst[e]], 1);
    if (e < BATCH) flag[label[e]] = 1;          // idempotent, races benign
}

// block-local scan (256/block) + per-block sums; also computes dinv
__global__ __launch_bounds__(256) void scanA_kernel(const int* __restrict__ cnt,
        int* __restrict__ offs, int* __restrict__ bsum, float* __restrict__ dinv) {
    __shared__ int sh[256];
    int i = blockIdx.x * 256 + threadIdx.x;
    int v = (i < N_NODES) ? cnt[i] : 0;
    if (i < N_NODES) dinv[i] = rsqrtf((float)(1 + v));
    sh[threadIdx.x] = v;
    __syncthreads();
    for (int off = 1; off < 256; off <<= 1) {
        int t = (threadIdx.x >= (unsigned)off) ? sh[threadIdx.x - off] : 0;
        __syncthreads();
        sh[threadIdx.x] += t;
        __syncthreads();
    }
    if (i < N_NODES) offs[i] = sh[threadIdx.x] - v;   // exclusive within block
    if (threadIdx.x == 255) bsum[blockIdx.x] = sh[255];
}

// adds prefix of bsum (computed in-kernel; 40 entries) — scanB folded in
__global__ __launch_bounds__(256) void scanC_kernel(int* __restrict__ offs,
                                                    const int* __restrict__ bsum) {
    int pre = 0;
    for (int b = 0; b < (int)blockIdx.x; ++b) pre += bsum[b];
    int i = blockIdx.x * 256 + threadIdx.x;
    if (i < N_NODES) offs[i] += pre;
    if (i == 0) offs[N_NODES] = N_EDGES;
}

// CSR fill storing (src id, dinv[src]) directly
__global__ void fill_csr_kernel(const int* __restrict__ src, const int* __restrict__ dst,
                                const int* __restrict__ offs, const float* __restrict__ dinv,
                                int* __restrict__ cursor, int* __restrict__ csr_src,
                                float* __restrict__ csr_w) {
    int e = blockIdx.x * blockDim.x + threadIdx.x;
    if (e < N_EDGES) {
        int d = dst[e];
        int s = src[e];
        int p = offs[d] + atomicAdd(&cursor[d], 1);
        csr_src[p] = s;
        csr_w[p]   = dinv[s];
    }
}

__global__ void compact_kernel(const int* __restrict__ flag, int* __restrict__ pcnt,
                               int* __restrict__ nodelist, int* __restrict__ pos) {
    int n = blockIdx.x * blockDim.x + threadIdx.x;
    if (n < N_NODES && flag[n]) {
        int p = atomicAdd(pcnt, 1);
        nodelist[p] = n;
        pos[n] = p;
    }
}

// ---------------------------------------------------------------------------
// split-bf16 helpers
// ---------------------------------------------------------------------------
__device__ __forceinline__ unsigned short f2bf(float x) {
    unsigned u = __float_as_uint(x);
    return (unsigned short)((u + 0x7FFFu + ((u >> 16) & 1u)) >> 16);   // RNE
}
__device__ __forceinline__ float bf2f(unsigned short h) {
    return __uint_as_float(((unsigned)h) << 16);
}

// ---------------------------------------------------------------------------
// GCN aggregation over 256 channels: wave-per-node, float4 per lane.
// EXTOUT: emit split-bf16 [hi|lo] row (2x256) instead of fp32.
// ---------------------------------------------------------------------------
template <int BIAS, int RELU, int COMPACT, int EXTOUT>
__global__ __launch_bounds__(256) void agg256_kernel(const float* __restrict__ xw,
        const float* __restrict__ dinv, const int* __restrict__ csr_src,
        const float* __restrict__ csr_w, const int* __restrict__ offs,
        const float* __restrict__ bias, void* __restrict__ out,
        const int* __restrict__ nodelist, const int* __restrict__ pcnt) {
    int wid  = blockIdx.x * 4 + (threadIdx.x >> 6);
    int lane = threadIdx.x & 63;
    int n;
    if (COMPACT) { if (wid >= pcnt[0]) return; n = nodelist[wid]; }
    else         { if (wid >= N_NODES) return; n = wid; }
    int c4 = lane * 4;
    float di = dinv[n];
    float d2 = di * di;
    float4 self = *(const float4*)&xw[(size_t)n * 256 + c4];
    float4 a = make_float4(d2 * self.x, d2 * self.y, d2 * self.z, d2 * self.w);
    int s0 = offs[n], s1 = offs[n + 1];
    int i = s0;
    for (; i + 1 < s1; i += 2) {              // 2 gathers in flight
        int sr0 = csr_src[i], sr1 = csr_src[i + 1];
        float w0 = di * csr_w[i], w1 = di * csr_w[i + 1];
        float4 v0 = *(const float4*)&xw[(size_t)sr0 * 256 + c4];
        float4 v1 = *(const float4*)&xw[(size_t)sr1 * 256 + c4];
        a.x = fmaf(w0, v0.x, a.x); a.y = fmaf(w0, v0.y, a.y);
        a.z = fmaf(w0, v0.z, a.z); a.w = fmaf(w0, v0.w, a.w);
        a.x = fmaf(w1, v1.x, a.x); a.y = fmaf(w1, v1.y, a.y);
        a.z = fmaf(w1, v1.z, a.z); a.w = fmaf(w1, v1.w, a.w);
    }
    if (i < s1) {
        int sr = csr_src[i];
        float wgt = di * csr_w[i];
        float4 v = *(const float4*)&xw[(size_t)sr * 256 + c4];
        a.x = fmaf(wgt, v.x, a.x); a.y = fmaf(wgt, v.y, a.y);
        a.z = fmaf(wgt, v.z, a.z); a.w = fmaf(wgt, v.w, a.w);
    }
    if (BIAS) {
        float4 b = *(const float4*)&bias[c4];
        a.x += b.x; a.y += b.y; a.z += b.z; a.w += b.w;
    }
    if (RELU) {
        a.x = fmaxf(a.x, 0.f); a.y = fmaxf(a.y, 0.f);
        a.z = fmaxf(a.z, 0.f); a.w = fmaxf(a.w, 0.f);
    }
    int orow = COMPACT ? wid : n;
    if (EXTOUT) {
        ushort4 h, l;
        h.x = f2bf(a.x); l.x = f2bf(a.x - bf2f(h.x));
        h.y = f2bf(a.y); l.y = f2bf(a.y - bf2f(h.y));
        h.z = f2bf(a.z); l.z = f2bf(a.z - bf2f(h.z));
        h.w = f2bf(a.w); l.w = f2bf(a.w - bf2f(h.w));
        unsigned short* ob = (unsigned short*)out + (size_t)orow * 512;
        *(ushort4*)&ob[c4]       = h;
        *(ushort4*)&ob[256 + c4] = l;
    } else {
        *(float4*)((float*)out + (size_t)orow * 256 + c4) = a;
    }
}

// Fused row-ext build for x_nodes (10000x512) AND image (4096x512) -> [hi|lo].
__global__ __launch_bounds__(256) void build_rowext2_kernel(const float* __restrict__ xn,
        const float* __restrict__ im, unsigned short* __restrict__ dxn,
        unsigned short* __restrict__ dim_) {
    int id = blockIdx.x * 256 + threadIdx.x;
    const int NA = N_NODES * 128;
    int lid = (id < NA) ? id : id - NA;
    const float* src = (id < NA) ? xn : im;
    unsigned short* dst = (id < NA) ? dxn : dim_;
    int r  = lid >> 7;
    int c4 = (lid & 127) << 2;
    float4 v = *(const float4*)&src[(size_t)r * DIM + c4];
    ushort4 h, l;
    h.x = f2bf(v.x); l.x = f2bf(v.x - bf2f(h.x));
    h.y = f2bf(v.y); l.y = f2bf(v.y - bf2f(h.y));
    h.z = f2bf(v.z); l.z = f2bf(v.z - bf2f(h.z));
    h.w = f2bf(v.w); l.w = f2bf(v.w - bf2f(h.w));
    unsigned short* base = dst + (size_t)r * 1024;
    *(ushort4*)&base[c4]       = h;
    *(ushort4*)&base[512 + c4] = l;
}

// Fused col-ext (transpose) build for all 4 weight matrices -> [N][2K] [hi|lo].
__global__ __launch_bounds__(256) void build_colext4_kernel(
        const float* __restrict__ Wg1, const float* __restrict__ Wi1,
        const float* __restrict__ Wg2, const float* __restrict__ Wi2,
        unsigned short* __restrict__ o1, unsigned short* __restrict__ o3,
        unsigned short* __restrict__ o2, unsigned short* __restrict__ o4) {
    int id  = blockIdx.x * 256 + threadIdx.x;
    int seg = id >> 15;            // 32768 threads per segment
    int lid = id & 32767;
    const float* src; unsigned short* dst; int K, N, kshift;
    if (seg == 0)      { src = Wg1; dst = o1; K = 512; N = 256; kshift = 7; }
    else if (seg == 1) { src = Wi1; dst = o3; K = 512; N = 256; kshift = 7; }
    else if (seg == 2) { src = Wg2; dst = o2; K = 256; N = 512; kshift = 6; }
    else               { src = Wi2; dst = o4; K = 256; N = 512; kshift = 6; }
    int n  = lid >> kshift;
    int c4 = (lid & ((1 << kshift) - 1)) << 2;
    float v0 = src[(size_t)(c4 + 0) * N + n];
    float v1 = src[(size_t)(c4 + 1) * N + n];
    float v2 = src[(size_t)(c4 + 2) * N + n];
    float v3 = src[(size_t)(c4 + 3) * N + n];
    ushort4 h, l;
    h.x = f2bf(v0); l.x = f2bf(v0 - bf2f(h.x));
    h.y = f2bf(v1); l.y = f2bf(v1 - bf2f(h.y));
    h.z = f2bf(v2); l.z = f2bf(v2 - bf2f(h.z));
    h.w = f2bf(v3); l.w = f2bf(v3 - bf2f(h.w));
    unsigned short* base = dst + (size_t)n * 2 * K;
    *(ushort4*)&base[c4]     = h;
    *(ushort4*)&base[K + c4] = l;
}

// ---------------------------------------------------------------------------
__device__ __forceinline__ void gld_lds16(const void* g, void* l) {
    __builtin_amdgcn_global_load_lds(
        (const __attribute__((address_space(1))) unsigned int*)g,
        (__attribute__((address_space(3))) unsigned int*)l, 16, 0, 0);
}

// ---------------------------------------------------------------------------
// Dense MFMA GEMM on [hi|lo] ext operands: C[M,N] = A.B^T, 3-product split-bf16.
// tile 128x64, 4 waves (2x2), wave = 64x32. Mptr (optional): device-side M.
// EXT=0: fp32 out; EXT=1: [hi|lo] ext out (row stride 2N).
// ---------------------------------------------------------------------------
template <int BIAS, int RELU, int EXT>
__global__ __launch_bounds__(256, 4) void mfma_gemm_kernel(
        const unsigned short* __restrict__ Aext, const unsigned short* __restrict__ Bext,
        const float* __restrict__ bias, void* __restrict__ Cout, int M, int N, int K,
        const int* __restrict__ Mptr) {
    __shared__ __align__(16) unsigned short sh[12288];
    if (Mptr) M = Mptr[0];
    int t    = threadIdx.x;
    int lane = t & 63;
    int w    = t >> 6;
    int wy   = w >> 1, wx = w & 1;
    int rt   = blockIdx.y, ct = blockIdx.x;
    int m    = lane & 15;
    int q    = lane >> 4;

    int ra0 = rt * 128 + w * 16 + m;        if (ra0 > M - 1) ra0 = M - 1;
    int ra1 = rt * 128 + (4 + w) * 16 + m;  if (ra1 > M - 1) ra1 = M - 1;
    int rb  = ct * 64 + w * 16 + m;
    const unsigned short* pa0 = Aext + (size_t)ra0 * 2 * K + q * 8;
    const unsigned short* pa1 = Aext + (size_t)ra1 * 2 * K + q * 8;
    const unsigned short* pb  = Bext + (size_t)rb  * 2 * K + q * 8;
    unsigned short* Bs = sh + 8192;

    f32x4 acc[4][2];
#pragma unroll
    for (int i = 0; i < 4; ++i)
#pragma unroll
        for (int j = 0; j < 2; ++j) acc[i][j] = (f32x4){0.f, 0.f, 0.f, 0.f};

    for (int k0 = 0; k0 < K; k0 += 32) {
        gld_lds16(pa0 + k0,     sh + (w * 2 + 0) * 512);
        gld_lds16(pa0 + K + k0, sh + (w * 2 + 1) * 512);
        gld_lds16(pa1 + k0,     sh + ((4 + w) * 2 + 0) * 512);
        gld_lds16(pa1 + K + k0, sh + ((4 + w) * 2 + 1) * 512);
        gld_lds16(pb + k0,      Bs + (w * 2 + 0) * 512);
        gld_lds16(pb + K + k0,  Bs + (w * 2 + 1) * 512);
        __syncthreads();
        short8 ah[4], al[4];
#pragma unroll
        for (int i = 0; i < 4; ++i) {
            ah[i] = *(const short8*)&sh[((wy * 4 + i) * 2 + 0) * 512 + lane * 8];
            al[i] = *(const short8*)&sh[((wy * 4 + i) * 2 + 1) * 512 + lane * 8];
        }
#pragma unroll
        for (int j = 0; j < 2; ++j) {
            short8 bh = *(const short8*)&Bs[((wx * 2 + j) * 2 + 0) * 512 + lane * 8];
            short8 bl = *(const short8*)&Bs[((wx * 2 + j) * 2 + 1) * 512 + lane * 8];
#pragma unroll
            for (int i = 0; i < 4; ++i) {
                acc[i][j] = __builtin_amdgcn_mfma_f32_16x16x32_bf16(ah[i], bh, acc[i][j], 0, 0, 0);
                acc[i][j] = __builtin_amdgcn_mfma_f32_16x16x32_bf16(al[i], bh, acc[i][j], 0, 0, 0);
                acc[i][j] = __builtin_amdgcn_mfma_f32_16x16x32_bf16(ah[i], bl, acc[i][j], 0, 0, 0);
            }
        }
        __syncthreads();
    }

    float b0 = 0.f, b1 = 0.f;
    if (BIAS) {
        b0 = bias[ct * 64 + wx * 32 + m];
        b1 = bias[ct * 64 + wx * 32 + 16 + m];
    }
#pragma unroll
    for (int i = 0; i < 4; ++i) {
        int rbase = rt * 128 + wy * 64 + i * 16 + q * 4;
#pragma unroll
        for (int j = 0; j < 2; ++j) {
            int col = ct * 64 + wx * 32 + j * 16 + m;
            float bb = j ? b1 : b0;
#pragma unroll
            for (int reg = 0; reg < 4; ++reg) {
                int row = rbase + reg;
                if (row < M) {
                    float v = acc[i][j][reg] + bb;
                    if (RELU) v = fmaxf(v, 0.f);
                    if (EXT == 0) {
                        ((float*)Cout)[(size_t)row * N + col] = v;
                    } else {
                        unsigned short hi = f2bf(v);
                        unsigned short lo = f2bf(v - bf2f(hi));
                        unsigned short* ob = (unsigned short*)Cout + (size_t)row * 2 * N;
                        ob[col] = hi; ob[N + col] = lo;
                    }
                }
            }
        }
    }
}

// ---------------------------------------------------------------------------
// logits = A @ B^T on [hi|lo] ext (K=512, 3-product split-bf16) + fused online
// softmax partials. A rows gathered in-kernel via pos[label[row]] from compact
// g2ext. Overlap restructure: {sync1; frags->regs; sync2; gld(k+1); MFMAs} —
// staging flies behind 48 MFMAs instead of zero. XCD swizzle. 32 KB LDS.
// ---------------------------------------------------------------------------
__global__ __launch_bounds__(256, 3) void logits_mfma_kernel(
        const unsigned short* __restrict__ Aext, const unsigned short* __restrict__ Bext,
        const int* __restrict__ label, const int* __restrict__ pos,
        float* __restrict__ pmax, float* __restrict__ psum, float* __restrict__ diagv) {
    __shared__ __align__(16) unsigned short sh[16384];   // 32 KB: A 16KB + B 16KB
    unsigned short* Bs = sh + 8192;

    int t    = threadIdx.x;
    int lane = t & 63;
    int w    = t >> 6;
    int wy   = w >> 1, wx = w & 1;
    int g   = blockIdx.x;                 // XCD swizzle: 8(rt) x 16(ct) region per XCD
    int xcd = g & 7, s = g >> 3;
    int rt  = (xcd >> 1) * 8 + (s & 7);
    int ct  = (xcd & 1) * 16 + (s >> 3);
    int m    = lane & 15;
    int q    = lane >> 4;

    int ar0 = pos[label[rt * 128 + w * 16 + m]];
    int ar1 = pos[label[rt * 128 + (4 + w) * 16 + m]];
    const unsigned short* ap0 = Aext + (size_t)ar0 * 1024 + q * 8;
    const unsigned short* ap1 = Aext + (size_t)ar1 * 1024 + q * 8;
    const unsigned short* bp0 = Bext + (size_t)(ct * 128 + w * 16 + m) * 1024 + q * 8;
    const unsigned short* bp1 = bp0 + (size_t)64 * 1024;

    f32x4 acc[4][4];
#pragma unroll
    for (int i = 0; i < 4; ++i)
#pragma unroll
        for (int j = 0; j < 4; ++j) acc[i][j] = (f32x4){0.f, 0.f, 0.f, 0.f};

    // prologue: stage k0 = 0
    {
        gld_lds16(ap0,       sh + (w * 2 + 0) * 512);
        gld_lds16(ap0 + 512, sh + (w * 2 + 1) * 512);
        gld_lds16(ap1,       sh + ((4 + w) * 2 + 0) * 512);
        gld_lds16(ap1 + 512, sh + ((4 + w) * 2 + 1) * 512);
        gld_lds16(bp0,       Bs + (w * 2 + 0) * 512);
        gld_lds16(bp0 + 512, Bs + (w * 2 + 1) * 512);
        gld_lds16(bp1,       Bs + ((4 + w) * 2 + 0) * 512);
        gld_lds16(bp1 + 512, Bs + ((4 + w) * 2 + 1) * 512);
    }

    for (int k0 = 0; k0 < 512; k0 += 32) {
        __syncthreads();              // sync1: drains vmcnt — staging of k0 complete
        short8 ah[4], al[4], bh[4], bl[4];
#pragma unroll
        for (int i = 0; i < 4; ++i) {
            ah[i] = *(const short8*)&sh[((wy * 4 + i) * 2 + 0) * 512 + lane * 8];
            al[i] = *(const short8*)&sh[((wy * 4 + i) * 2 + 1) * 512 + lane * 8];
            bh[i] = *(const short8*)&Bs[((wx * 4 + i) * 2 + 0) * 512 + lane * 8];
            bl[i] = *(const short8*)&Bs[((wx * 4 + i) * 2 + 1) * 512 + lane * 8];
        }
        __syncthreads();              // sync2: all waves done reading LDS
        if (k0 + 32 < 512) {          // stage k0+32 — in flight across the MFMAs below
            int kn = k0 + 32;
            gld_lds16(ap0 + kn,       sh + (w * 2 + 0) * 512);
            gld_lds16(ap0 + 512 + kn, sh + (w * 2 + 1) * 512);
            gld_lds16(ap1 + kn,       sh + ((4 + w) * 2 + 0) * 512);
            gld_lds16(ap1 + 512 + kn, sh + ((4 + w) * 2 + 1) * 512);
            gld_lds16(bp0 + kn,       Bs + (w * 2 + 0) * 512);
            gld_lds16(bp0 + 512 + kn, Bs + (w * 2 + 1) * 512);
            gld_lds16(bp1 + kn,       Bs + ((4 + w) * 2 + 0) * 512);
            gld_lds16(bp1 + 512 + kn, Bs + ((4 + w) * 2 + 1) * 512);
        }
        __builtin_amdgcn_sched_barrier(0);   // keep MFMAs below the staging issues
#pragma unroll
        for (int j = 0; j < 4; ++j)
#pragma unroll
            for (int i = 0; i < 4; ++i) {
                acc[i][j] = __builtin_amdgcn_mfma_f32_16x16x32_bf16(ah[i], bh[j], acc[i][j], 0, 0, 0);
                acc[i][j] = __builtin_amdgcn_mfma_f32_16x16x32_bf16(al[i], bh[j], acc[i][j], 0, 0, 0);
                acc[i][j] = __builtin_amdgcn_mfma_f32_16x16x32_bf16(ah[i], bl[j], acc[i][j], 0, 0, 0);
            }
    }

    // C/D layout: col = lane&15, row = q*4 + reg (within each 16x16 tile)
    if (rt == ct && wy == wx) {
        int reg = m - q * 4;
        if (reg >= 0 && reg < 4) {
#pragma unroll
            for (int mt = 0; mt < 4; ++mt) {
                f32x4 dvv = acc[mt][mt];
                float dv = (reg == 0) ? dvv.x : (reg == 1) ? dvv.y : (reg == 2) ? dvv.z : dvv.w;
                diagv[rt * 128 + wy * 64 + mt * 16 + m] = dv;
            }
        }
    }

    // per-row (max, sumexp) over this wave's 64 cols
#pragma unroll
    for (int mt = 0; mt < 4; ++mt) {
#pragma unroll
        for (int reg = 0; reg < 4; ++reg) {
            float v0 = acc[mt][0][reg], v1 = acc[mt][1][reg];
            float v2 = acc[mt][2][reg], v3 = acc[mt][3][reg];
            float mx = fmaxf(fmaxf(v0, v1), fmaxf(v2, v3));
#pragma unroll
            for (int d = 1; d < 16; d <<= 1) mx = fmaxf(mx, __shfl_xor(mx, d, 64));
            float sm = __expf(v0 - mx) + __expf(v1 - mx) + __expf(v2 - mx) + __expf(v3 - mx);
#pragma unroll
            for (int d = 1; d < 16; d <<= 1) sm += __shfl_xor(sm, d, 64);
            if (m == 0) {
                int row = rt * 128 + wy * 64 + mt * 16 + q * 4 + reg;
                pmax[(size_t)row * 64 + ct * 2 + wx] = mx;
                psum[(size_t)row * 64 + ct * 2 + wx] = sm;
            }
        }
    }
}

// combine 64 col-tile partials per row -> per-row loss term
__global__ __launch_bounds__(256) void row_finalize_kernel(const float* __restrict__ pmax,
        const float* __restrict__ psum, const float* __restrict__ diagv,
        const int* __restrict__ label, float* __restrict__ terms) {
    int gid  = blockIdx.x * blockDim.x + threadIdx.x;
    int row  = gid >> 6;
    int lane = threadIdx.x & 63;
    if (row >= BATCH) return;
    float m = pmax[(size_t)row * 64 + lane];
    float s = psum[(size_t)row * 64 + lane];
    float M = m;
#pragma unroll
    for (int d = 1; d < 64; d <<= 1) M = fmaxf(M, __shfl_xor(M, d, 64));
    s *= __expf(m - M);
#pragma unroll
    for (int d = 1; d < 64; d <<= 1) s += __shfl_xor(s, d, 64);
    if (lane == 0) {
        float lse = M + __logf(s);
        terms[row] = -(float)label[row] * (diagv[row] - lse);
    }
}

__global__ __launch_bounds__(256) void final_sum_kernel(const float* __restrict__ terms,
                                                        float* __restrict__ out) {
    __shared__ float red[256];
    float s = 0.0f;
    for (int i = threadIdx.x; i < BATCH; i += 256) s += terms[i];
    red[threadIdx.x] = s;
    __syncthreads();
    for (int w = 128; w > 0; w >>= 1) {
        if (threadIdx.x < (unsigned)w) red[threadIdx.x] += red[threadIdx.x + w];
        __syncthreads();
    }
    // contrastive mean + triplet loss (identically 1.0: d_ap==d_an, relu(margin)=1)
    if (threadIdx.x == 0) out[0] = red[0] / (float)BATCH + 1.0f;
}

// ---------------------------------------------------------------------------
extern "C" void kernel_launch(void* const* d_in, const int* in_sizes, int n_in,
                              void* d_out, int out_size, void* d_ws, size_t ws_size,
                              hipStream_t stream) {
    const float* image   = (const float*)d_in[0];
    const float* x_nodes = (const float*)d_in[1];
    const int*   edge    = (const int*)d_in[2];
    const int*   label   = (const int*)d_in[3];
    const float* W_img1  = (const float*)d_in[4];
    const float* b_img1  = (const float*)d_in[5];
    const float* W_img2  = (const float*)d_in[6];
    const float* b_img2  = (const float*)d_in[7];
    const float* W_g1    = (const float*)d_in[8];
    const float* b_g1    = (const float*)d_in[9];
    const float* W_g2    = (const float*)d_in[10];
    const float* b_g2    = (const float*)d_in[11];
    const int* src = edge;              // edge_index[0]
    const int* dst = edge + N_EDGES;    // edge_index[1]

    // workspace carve-up (256B aligned regions)
    char* ws = (char*)d_ws;
    size_t off = 0;
    auto alloc = [&](size_t bytes) { size_t r = off; off = (off + bytes + 255) & ~(size_t)255; return r; };
    float* dinv     = (float*)(ws + alloc(N_NODES * 4));
    int*   cnt      = (int*)  (ws + alloc(N_NODES * 4));
    int*   offs     = (int*)  (ws + alloc((N_NODES + 1) * 4));
    int*   cursor   = (int*)  (ws + alloc(N_NODES * 4));
    int*   csr_src  = (int*)  (ws + alloc(N_EDGES * 4));
    float* csr_w    = (float*)(ws + alloc(N_EDGES * 4));
    int*   flag     = (int*)  (ws + alloc(N_NODES * 4));
    int*   pos      = (int*)  (ws + alloc(N_NODES * 4));
    int*   nodelist = (int*)  (ws + alloc(BATCH * 4));
    int*   pcnt     = (int*)  (ws + alloc(4));
    int*   bsum     = (int*)  (ws + alloc(64 * 4));
    float* xw1      = (float*)(ws + alloc((size_t)N_NODES * HID * 4));
    float* h        = (float*)(ws + alloc((size_t)N_NODES * HID * 4));
    unsigned short* g2inext = (unsigned short*)(ws + alloc((size_t)BATCH * 2 * HID * 2));
    unsigned short* g2ext   = (unsigned short*)(ws + alloc((size_t)BATCH * 2 * DIM * 2));
    unsigned short* himgext = (unsigned short*)(ws + alloc((size_t)BATCH * 2 * HID * 2));
    unsigned short* extbuf  = (unsigned short*)(ws + alloc((size_t)N_NODES * 2 * DIM * 2));
    unsigned short* imgext  = (unsigned short*)(ws + alloc((size_t)BATCH * 2 * DIM * 2));
    unsigned short* wext1   = (unsigned short*)(ws + alloc((size_t)HID * 2 * DIM * 2));
    unsigned short* wext2   = (unsigned short*)(ws + alloc((size_t)DIM * 2 * HID * 2));
    unsigned short* wext3   = (unsigned short*)(ws + alloc((size_t)HID * 2 * DIM * 2));
    unsigned short* wext4   = (unsigned short*)(ws + alloc((size_t)DIM * 2 * HID * 2));
    unsigned short* Bext    = (unsigned short*)(ws + alloc((size_t)BATCH * 2 * DIM * 2));
    float* pmax  = (float*)(ws + alloc((size_t)BATCH * 64 * 4));
    float* psum  = (float*)(ws + alloc((size_t)BATCH * 64 * 4));
    float* diagv = (float*)(ws + alloc(BATCH * 4));
    float* terms = (float*)(ws + alloc(BATCH * 4));

    const int SCAN_BLOCKS = (N_NODES + 255) / 256;   // 40

    // graph build: CSR by dst (storing src+weight) + dinv + label compaction
    zero_init_kernel<<<SCAN_BLOCKS, 256, 0, stream>>>(cnt, cursor, flag, pcnt);
    count_mark_kernel<<<(N_EDGES + 255) / 256, 256, 0, stream>>>(dst, label, cnt, flag);
    scanA_kernel<<<SCAN_BLOCKS, 256, 0, stream>>>(cnt, offs, bsum, dinv);
    scanC_kernel<<<SCAN_BLOCKS, 256, 0, stream>>>(offs, bsum);
    fill_csr_kernel<<<(N_EDGES + 255) / 256, 256, 0, stream>>>(src, dst, offs, dinv,
                                                               cursor, csr_src, csr_w);
    compact_kernel<<<SCAN_BLOCKS, 256, 0, stream>>>(flag, pcnt, nodelist, pos);

    // fused operand builds: x_nodes + image row-ext; all 4 weight col-ext
    build_rowext2_kernel<<<((N_NODES + BATCH) * 128) / 256, 256, 0, stream>>>(
        x_nodes, image, extbuf, imgext);
    build_colext4_kernel<<<512, 256, 0, stream>>>(W_g1, W_img1, W_g2, W_img2,
                                                  wext1, wext3, wext2, wext4);

    // GCN layer 1: xw1 = x_nodes @ W_g1 (split-bf16 MFMA); h = relu(A-hat xw1 + b1)
    mfma_gemm_kernel<0, 0, 0><<<dim3(HID / 64, (N_NODES + 127) / 128), 256, 0, stream>>>(
        extbuf, wext1, nullptr, xw1, N_NODES, HID, DIM, nullptr);
    agg256_kernel<1, 1, 0, 0><<<(N_NODES + 3) / 4, 256, 0, stream>>>(
        xw1, dinv, csr_src, csr_w, offs, b_g1, h, nullptr, nullptr);

    // GCN layer 2 (reordered, compact): g2inext = ext(A-hat h) on label rows;
    // g2ext = ext(g2in @ W_g2 + b2) on compact rows (M = pcnt, device-side)
    agg256_kernel<0, 0, 1, 1><<<BATCH / 4, 256, 0, stream>>>(
        h, dinv, csr_src, csr_w, offs, nullptr, g2inext, nodelist, pcnt);
    mfma_gemm_kernel<1, 0, 1><<<dim3(DIM / 64, BATCH / 128), 256, 0, stream>>>(
        g2inext, wext2, b_g2, g2ext, BATCH, DIM, HID, pcnt);

    // image MLP: himgext = ext(relu(image@W1+b1)); Bext = ext(relu(himg@W2+b2))
    mfma_gemm_kernel<1, 1, 1><<<dim3(HID / 64, BATCH / 128), 256, 0, stream>>>(
        imgext, wext3, b_img1, himgext, BATCH, HID, DIM, nullptr);
    mfma_gemm_kernel<1, 1, 1><<<dim3(DIM / 64, BATCH / 128), 256, 0, stream>>>(
        himgext, wext4, b_img2, Bext, BATCH, DIM, HID, nullptr);

    // fused logits (split-bf16 MFMA, overlapped staging, in-kernel A-gather)
    logits_mfma_kernel<<<1024, 256, 0, stream>>>(g2ext, Bext, label, pos,
                                                 pmax, psum, diagv);
    row_finalize_kernel<<<(BATCH * 64) / 256, 256, 0, stream>>>(pmax, psum, diagv, label, terms);
    final_sum_kernel<<<1, 256, 0, stream>>>(terms, (float*)d_out);
}

// Round 9
// 334.022 us; speedup vs baseline: 1.6067x; 1.0072x over previous
//
#include <hip/hip_runtime.h>
#include <hip/hip_bf16.h>
#include <math.h>

// Problem constants (fixed by the reference)
#define N_NODES 10000
#define N_EDGES 160000
#define BATCH   4096
#define DIM     512
#define HID     256

typedef short short8 __attribute__((ext_vector_type(8)));
typedef float f32x4  __attribute__((ext_vector_type(4)));

// ---------------------------------------------------------------------------
// graph build utilities
// ---------------------------------------------------------------------------
__global__ void zero_init_kernel(int* cnt, int* cursor, int* flag, int* pcnt) {
    int i = blockIdx.x * blockDim.x + threadIdx.x;
    if (i < N_NODES) { cnt[i] = 0; cursor[i] = 0; flag[i] = 0; }
    if (i == 0) pcnt[0] = 0;
}

// degree count + label marking in one pass
__global__ void count_mark_kernel(const int* __restrict__ dst, const int* __restrict__ label,
                                  int* __restrict__ cnt, int* __restrict__ flag) {
    int e = blockIdx.x * blockDim.x + threadIdx.x;
    if (e < N_EDGES) atomicAdd(&cnt[dst[e]], 1);
    if (e < BATCH) flag[label[e]] = 1;          // idempotent, races benign
}

// block-local scan (256/block) + per-block sums; also computes dinv
__global__ __launch_bounds__(256) void scanA_kernel(const int* __restrict__ cnt,
        int* __restrict__ offs, int* __restrict__ bsum, float* __restrict__ dinv) {
    __shared__ int sh[256];
    int i = blockIdx.x * 256 + threadIdx.x;
    int v = (i < N_NODES) ? cnt[i] : 0;
    if (i < N_NODES) dinv[i] = rsqrtf((float)(1 + v));
    sh[threadIdx.x] = v;
    __syncthreads();
    for (int off = 1; off < 256; off <<= 1) {
        int t = (threadIdx.x >= (unsigned)off) ? sh[threadIdx.x - off] : 0;
        __syncthreads();
        sh[threadIdx.x] += t;
        __syncthreads();
    }
    if (i < N_NODES) offs[i] = sh[threadIdx.x] - v;   // exclusive within block
    if (threadIdx.x == 255) bsum[blockIdx.x] = sh[255];
}

// adds prefix of bsum (computed in-kernel; 40 entries) — scanB folded in
__global__ __launch_bounds__(256) void scanC_kernel(int* __restrict__ offs,
                                                    const int* __restrict__ bsum) {
    int pre = 0;
    for (int b = 0; b < (int)blockIdx.x; ++b) pre += bsum[b];
    int i = blockIdx.x * 256 + threadIdx.x;
    if (i < N_NODES) offs[i] += pre;
    if (i == 0) offs[N_NODES] = N_EDGES;
}

// CSR fill storing (src id, dinv[src]) directly
__global__ void fill_csr_kernel(const int* __restrict__ src, const int* __restrict__ dst,
                                const int* __restrict__ offs, const float* __restrict__ dinv,
                                int* __restrict__ cursor, int* __restrict__ csr_src,
                                float* __restrict__ csr_w) {
    int e = blockIdx.x * blockDim.x + threadIdx.x;
    if (e < N_EDGES) {
        int d = dst[e];
        int s = src[e];
        int p = offs[d] + atomicAdd(&cursor[d], 1);
        csr_src[p] = s;
        csr_w[p]   = dinv[s];
    }
}

__global__ void compact_kernel(const int* __restrict__ flag, int* __restrict__ pcnt,
                               int* __restrict__ nodelist, int* __restrict__ pos) {
    int n = blockIdx.x * blockDim.x + threadIdx.x;
    if (n < N_NODES && flag[n]) {
        int p = atomicAdd(pcnt, 1);
        nodelist[p] = n;
        pos[n] = p;
    }
}

// ---------------------------------------------------------------------------
// split-bf16 helpers
// ---------------------------------------------------------------------------
__device__ __forceinline__ unsigned short f2bf(float x) {
    unsigned u = __float_as_uint(x);
    return (unsigned short)((u + 0x7FFFu + ((u >> 16) & 1u)) >> 16);   // RNE
}
__device__ __forceinline__ float bf2f(unsigned short h) {
    return __uint_as_float(((unsigned)h) << 16);
}

// ---------------------------------------------------------------------------
// GCN aggregation over 256 channels: wave-per-node, float4 per lane.
// EXTOUT: emit split-bf16 [hi|lo] row (2x256) instead of fp32.
// ---------------------------------------------------------------------------
template <int BIAS, int RELU, int COMPACT, int EXTOUT>
__global__ __launch_bounds__(256) void agg256_kernel(const float* __restrict__ xw,
        const float* __restrict__ dinv, const int* __restrict__ csr_src,
        const float* __restrict__ csr_w, const int* __restrict__ offs,
        const float* __restrict__ bias, void* __restrict__ out,
        const int* __restrict__ nodelist, const int* __restrict__ pcnt) {
    int wid  = blockIdx.x * 4 + (threadIdx.x >> 6);
    int lane = threadIdx.x & 63;
    int n;
    if (COMPACT) { if (wid >= pcnt[0]) return; n = nodelist[wid]; }
    else         { if (wid >= N_NODES) return; n = wid; }
    int c4 = lane * 4;
    float di = dinv[n];
    float d2 = di * di;
    float4 self = *(const float4*)&xw[(size_t)n * 256 + c4];
    float4 a = make_float4(d2 * self.x, d2 * self.y, d2 * self.z, d2 * self.w);
    int s0 = offs[n], s1 = offs[n + 1];
    int i = s0;
    for (; i + 1 < s1; i += 2) {              // 2 gathers in flight
        int sr0 = csr_src[i], sr1 = csr_src[i + 1];
        float w0 = di * csr_w[i], w1 = di * csr_w[i + 1];
        float4 v0 = *(const float4*)&xw[(size_t)sr0 * 256 + c4];
        float4 v1 = *(const float4*)&xw[(size_t)sr1 * 256 + c4];
        a.x = fmaf(w0, v0.x, a.x); a.y = fmaf(w0, v0.y, a.y);
        a.z = fmaf(w0, v0.z, a.z); a.w = fmaf(w0, v0.w, a.w);
        a.x = fmaf(w1, v1.x, a.x); a.y = fmaf(w1, v1.y, a.y);
        a.z = fmaf(w1, v1.z, a.z); a.w = fmaf(w1, v1.w, a.w);
    }
    if (i < s1) {
        int sr = csr_src[i];
        float wgt = di * csr_w[i];
        float4 v = *(const float4*)&xw[(size_t)sr * 256 + c4];
        a.x = fmaf(wgt, v.x, a.x); a.y = fmaf(wgt, v.y, a.y);
        a.z = fmaf(wgt, v.z, a.z); a.w = fmaf(wgt, v.w, a.w);
    }
    if (BIAS) {
        float4 b = *(const float4*)&bias[c4];
        a.x += b.x; a.y += b.y; a.z += b.z; a.w += b.w;
    }
    if (RELU) {
        a.x = fmaxf(a.x, 0.f); a.y = fmaxf(a.y, 0.f);
        a.z = fmaxf(a.z, 0.f); a.w = fmaxf(a.w, 0.f);
    }
    int orow = COMPACT ? wid : n;
    if (EXTOUT) {
        ushort4 h, l;
        h.x = f2bf(a.x); l.x = f2bf(a.x - bf2f(h.x));
        h.y = f2bf(a.y); l.y = f2bf(a.y - bf2f(h.y));
        h.z = f2bf(a.z); l.z = f2bf(a.z - bf2f(h.z));
        h.w = f2bf(a.w); l.w = f2bf(a.w - bf2f(h.w));
        unsigned short* ob = (unsigned short*)out + (size_t)orow * 512;
        *(ushort4*)&ob[c4]       = h;
        *(ushort4*)&ob[256 + c4] = l;
    } else {
        *(float4*)((float*)out + (size_t)orow * 256 + c4) = a;
    }
}

// Fused row-ext build for x_nodes (10000x512) AND image (4096x512) -> [hi|lo].
__global__ __launch_bounds__(256) void build_rowext2_kernel(const float* __restrict__ xn,
        const float* __restrict__ im, unsigned short* __restrict__ dxn,
        unsigned short* __restrict__ dim_) {
    int id = blockIdx.x * 256 + threadIdx.x;
    const int NA = N_NODES * 128;
    int lid = (id < NA) ? id : id - NA;
    const float* src = (id < NA) ? xn : im;
    unsigned short* dst = (id < NA) ? dxn : dim_;
    int r  = lid >> 7;
    int c4 = (lid & 127) << 2;
    float4 v = *(const float4*)&src[(size_t)r * DIM + c4];
    ushort4 h, l;
    h.x = f2bf(v.x); l.x = f2bf(v.x - bf2f(h.x));
    h.y = f2bf(v.y); l.y = f2bf(v.y - bf2f(h.y));
    h.z = f2bf(v.z); l.z = f2bf(v.z - bf2f(h.z));
    h.w = f2bf(v.w); l.w = f2bf(v.w - bf2f(h.w));
    unsigned short* base = dst + (size_t)r * 1024;
    *(ushort4*)&base[c4]       = h;
    *(ushort4*)&base[512 + c4] = l;
}

// Fused col-ext (transpose) build for all 4 weight matrices -> [N][2K] [hi|lo].
__global__ __launch_bounds__(256) void build_colext4_kernel(
        const float* __restrict__ Wg1, const float* __restrict__ Wi1,
        const float* __restrict__ Wg2, const float* __restrict__ Wi2,
        unsigned short* __restrict__ o1, unsigned short* __restrict__ o3,
        unsigned short* __restrict__ o2, unsigned short* __restrict__ o4) {
    int id  = blockIdx.x * 256 + threadIdx.x;
    int seg = id >> 15;            // 32768 threads per segment
    int lid = id & 32767;
    const float* src; unsigned short* dst; int K, N, kshift;
    if (seg == 0)      { src = Wg1; dst = o1; K = 512; N = 256; kshift = 7; }
    else if (seg == 1) { src = Wi1; dst = o3; K = 512; N = 256; kshift = 7; }
    else if (seg == 2) { src = Wg2; dst = o2; K = 256; N = 512; kshift = 6; }
    else               { src = Wi2; dst = o4; K = 256; N = 512; kshift = 6; }
    int n  = lid >> kshift;
    int c4 = (lid & ((1 << kshift) - 1)) << 2;
    float v0 = src[(size_t)(c4 + 0) * N + n];
    float v1 = src[(size_t)(c4 + 1) * N + n];
    float v2 = src[(size_t)(c4 + 2) * N + n];
    float v3 = src[(size_t)(c4 + 3) * N + n];
    ushort4 h, l;
    h.x = f2bf(v0); l.x = f2bf(v0 - bf2f(h.x));
    h.y = f2bf(v1); l.y = f2bf(v1 - bf2f(h.y));
    h.z = f2bf(v2); l.z = f2bf(v2 - bf2f(h.z));
    h.w = f2bf(v3); l.w = f2bf(v3 - bf2f(h.w));
    unsigned short* base = dst + (size_t)n * 2 * K;
    *(ushort4*)&base[c4]     = h;
    *(ushort4*)&base[K + c4] = l;
}

// ---------------------------------------------------------------------------
__device__ __forceinline__ void gld_lds16(const void* g, void* l) {
    __builtin_amdgcn_global_load_lds(
        (const __attribute__((address_space(1))) unsigned int*)g,
        (__attribute__((address_space(3))) unsigned int*)l, 16, 0, 0);
}

// ---------------------------------------------------------------------------
// Dense MFMA GEMM on [hi|lo] ext operands: C[M,N] = A.B^T, 3-product split-bf16.
// tile 128x64, 4 waves (2x2), wave = 64x32. Mptr (optional): device-side M.
// EXT=0: fp32 out; EXT=1: [hi|lo] ext out (row stride 2N).
// ---------------------------------------------------------------------------
template <int BIAS, int RELU, int EXT>
__global__ __launch_bounds__(256, 4) void mfma_gemm_kernel(
        const unsigned short* __restrict__ Aext, const unsigned short* __restrict__ Bext,
        const float* __restrict__ bias, void* __restrict__ Cout, int M, int N, int K,
        const int* __restrict__ Mptr) {
    __shared__ __align__(16) unsigned short sh[12288];
    if (Mptr) M = Mptr[0];
    int t    = threadIdx.x;
    int lane = t & 63;
    int w    = t >> 6;
    int wy   = w >> 1, wx = w & 1;
    int rt   = blockIdx.y, ct = blockIdx.x;
    int m    = lane & 15;
    int q    = lane >> 4;

    int ra0 = rt * 128 + w * 16 + m;        if (ra0 > M - 1) ra0 = M - 1;
    int ra1 = rt * 128 + (4 + w) * 16 + m;  if (ra1 > M - 1) ra1 = M - 1;
    int rb  = ct * 64 + w * 16 + m;
    const unsigned short* pa0 = Aext + (size_t)ra0 * 2 * K + q * 8;
    const unsigned short* pa1 = Aext + (size_t)ra1 * 2 * K + q * 8;
    const unsigned short* pb  = Bext + (size_t)rb  * 2 * K + q * 8;
    unsigned short* Bs = sh + 8192;

    f32x4 acc[4][2];
#pragma unroll
    for (int i = 0; i < 4; ++i)
#pragma unroll
        for (int j = 0; j < 2; ++j) acc[i][j] = (f32x4){0.f, 0.f, 0.f, 0.f};

    for (int k0 = 0; k0 < K; k0 += 32) {
        gld_lds16(pa0 + k0,     sh + (w * 2 + 0) * 512);
        gld_lds16(pa0 + K + k0, sh + (w * 2 + 1) * 512);
        gld_lds16(pa1 + k0,     sh + ((4 + w) * 2 + 0) * 512);
        gld_lds16(pa1 + K + k0, sh + ((4 + w) * 2 + 1) * 512);
        gld_lds16(pb + k0,      Bs + (w * 2 + 0) * 512);
        gld_lds16(pb + K + k0,  Bs + (w * 2 + 1) * 512);
        __syncthreads();
        short8 ah[4], al[4];
#pragma unroll
        for (int i = 0; i < 4; ++i) {
            ah[i] = *(const short8*)&sh[((wy * 4 + i) * 2 + 0) * 512 + lane * 8];
            al[i] = *(const short8*)&sh[((wy * 4 + i) * 2 + 1) * 512 + lane * 8];
        }
#pragma unroll
        for (int j = 0; j < 2; ++j) {
            short8 bh = *(const short8*)&Bs[((wx * 2 + j) * 2 + 0) * 512 + lane * 8];
            short8 bl = *(const short8*)&Bs[((wx * 2 + j) * 2 + 1) * 512 + lane * 8];
#pragma unroll
            for (int i = 0; i < 4; ++i) {
                acc[i][j] = __builtin_amdgcn_mfma_f32_16x16x32_bf16(ah[i], bh, acc[i][j], 0, 0, 0);
                acc[i][j] = __builtin_amdgcn_mfma_f32_16x16x32_bf16(al[i], bh, acc[i][j], 0, 0, 0);
                acc[i][j] = __builtin_amdgcn_mfma_f32_16x16x32_bf16(ah[i], bl, acc[i][j], 0, 0, 0);
            }
        }
        __syncthreads();
    }

    float b0 = 0.f, b1 = 0.f;
    if (BIAS) {
        b0 = bias[ct * 64 + wx * 32 + m];
        b1 = bias[ct * 64 + wx * 32 + 16 + m];
    }
#pragma unroll
    for (int i = 0; i < 4; ++i) {
        int rbase = rt * 128 + wy * 64 + i * 16 + q * 4;
#pragma unroll
        for (int j = 0; j < 2; ++j) {
            int col = ct * 64 + wx * 32 + j * 16 + m;
            float bb = j ? b1 : b0;
#pragma unroll
            for (int reg = 0; reg < 4; ++reg) {
                int row = rbase + reg;
                if (row < M) {
                    float v = acc[i][j][reg] + bb;
                    if (RELU) v = fmaxf(v, 0.f);
                    if (EXT == 0) {
                        ((float*)Cout)[(size_t)row * N + col] = v;
                    } else {
                        unsigned short hi = f2bf(v);
                        unsigned short lo = f2bf(v - bf2f(hi));
                        unsigned short* ob = (unsigned short*)Cout + (size_t)row * 2 * N;
                        ob[col] = hi; ob[N + col] = lo;
                    }
                }
            }
        }
    }
}

// ---------------------------------------------------------------------------
// logits = A @ B^T on [hi|lo] ext (K=512, 3-product split-bf16) + fused online
// softmax partials. 256x128 tile, 512 thr = 8 waves (4x2), wave = 64x64.
// Staged bytes/output = 0.75x of the 128x128 tile (A 32KB + B 16KB per chunk
// for 2x the output). 48 KB LDS -> 2 blocks/CU; 512 blocks = full residency.
// In-kernel A-gather via pos[label]; fragment-order LDS (conflict-free);
// XCD swizzle (per-XCD ~6 MB region). Proven two-barrier structure.
// ---------------------------------------------------------------------------
__global__ __launch_bounds__(512, 4) void logits_mfma_kernel(
        const unsigned short* __restrict__ Aext, const unsigned short* __restrict__ Bext,
        const int* __restrict__ label, const int* __restrict__ pos,
        float* __restrict__ pmax, float* __restrict__ psum, float* __restrict__ diagv) {
    __shared__ __align__(16) unsigned short sh[24576];   // 48 KB: A 32KB (16 chunks) + B 16KB (8)
    unsigned short* Bs = sh + 16384;

    int t    = threadIdx.x;
    int lane = t & 63;
    int w    = t >> 6;            // wave 0..7
    int wy   = w >> 1, wx = w & 1;
    // XCD swizzle over 512 blocks = 16 rt x 32 ct; per-XCD region 8rt x 8ct
    int g   = blockIdx.x;
    int xcd = g & 7, s = g >> 3;              // s in 0..63
    int rt  = (xcd & 1) * 8 + (s & 7);        // 0..15 (256-row tiles)
    int ct  = (xcd >> 1) * 8 + (s >> 3);      // 0..31 (128-col tiles)
    int m    = lane & 15;
    int q    = lane >> 4;

    // staging: wave w owns A chunks (w*2, w*2+1) and B chunk w (16 rows each)
    int ar0 = pos[label[rt * 256 + (w * 2 + 0) * 16 + m]];
    int ar1 = pos[label[rt * 256 + (w * 2 + 1) * 16 + m]];
    const unsigned short* ap0 = Aext + (size_t)ar0 * 1024 + q * 8;
    const unsigned short* ap1 = Aext + (size_t)ar1 * 1024 + q * 8;
    const unsigned short* bp  = Bext + (size_t)(ct * 128 + w * 16 + m) * 1024 + q * 8;

    f32x4 acc[4][4];
#pragma unroll
    for (int i = 0; i < 4; ++i)
#pragma unroll
        for (int j = 0; j < 4; ++j) acc[i][j] = (f32x4){0.f, 0.f, 0.f, 0.f};

    for (int k0 = 0; k0 < 512; k0 += 32) {
        gld_lds16(ap0 + k0,       sh + ((w * 2 + 0) * 2 + 0) * 512);
        gld_lds16(ap0 + 512 + k0, sh + ((w * 2 + 0) * 2 + 1) * 512);
        gld_lds16(ap1 + k0,       sh + ((w * 2 + 1) * 2 + 0) * 512);
        gld_lds16(ap1 + 512 + k0, sh + ((w * 2 + 1) * 2 + 1) * 512);
        gld_lds16(bp + k0,        Bs + (w * 2 + 0) * 512);
        gld_lds16(bp + 512 + k0,  Bs + (w * 2 + 1) * 512);
        __syncthreads();                 // drains vmcnt: staging complete
        short8 ah[4], al[4];
#pragma unroll
        for (int i = 0; i < 4; ++i) {
            ah[i] = *(const short8*)&sh[((wy * 4 + i) * 2 + 0) * 512 + lane * 8];
            al[i] = *(const short8*)&sh[((wy * 4 + i) * 2 + 1) * 512 + lane * 8];
        }
#pragma unroll
        for (int j = 0; j < 4; ++j) {
            short8 bh = *(const short8*)&Bs[((wx * 4 + j) * 2 + 0) * 512 + lane * 8];
            short8 bl = *(const short8*)&Bs[((wx * 4 + j) * 2 + 1) * 512 + lane * 8];
#pragma unroll
            for (int i = 0; i < 4; ++i) {
                acc[i][j] = __builtin_amdgcn_mfma_f32_16x16x32_bf16(ah[i], bh, acc[i][j], 0, 0, 0);
                acc[i][j] = __builtin_amdgcn_mfma_f32_16x16x32_bf16(al[i], bh, acc[i][j], 0, 0, 0);
                acc[i][j] = __builtin_amdgcn_mfma_f32_16x16x32_bf16(ah[i], bl, acc[i][j], 0, 0, 0);
            }
        }
        __syncthreads();                 // WAR before next staging
    }

    // C/D layout: col = lane&15, row = q*4 + reg (within each 16x16 tile)
    // diagonal: block rows [rt*256,+256) x cols [ct*128,+128) touch it iff ct>>1==rt
    if ((ct >> 1) == rt) {
#pragma unroll
        for (int i = 0; i < 4; ++i)
#pragma unroll
            for (int j = 0; j < 4; ++j)
#pragma unroll
                for (int reg = 0; reg < 4; ++reg) {
                    int row = rt * 256 + wy * 64 + i * 16 + q * 4 + reg;
                    int col = ct * 128 + wx * 64 + j * 16 + m;
                    if (row == col) diagv[row] = acc[i][j][reg];
                }
    }

    // per-row (max, sumexp) over this wave's 64 cols
#pragma unroll
    for (int mt = 0; mt < 4; ++mt) {
#pragma unroll
        for (int reg = 0; reg < 4; ++reg) {
            float v0 = acc[mt][0][reg], v1 = acc[mt][1][reg];
            float v2 = acc[mt][2][reg], v3 = acc[mt][3][reg];
            float mx = fmaxf(fmaxf(v0, v1), fmaxf(v2, v3));
#pragma unroll
            for (int d = 1; d < 16; d <<= 1) mx = fmaxf(mx, __shfl_xor(mx, d, 64));
            float sm = __expf(v0 - mx) + __expf(v1 - mx) + __expf(v2 - mx) + __expf(v3 - mx);
#pragma unroll
            for (int d = 1; d < 16; d <<= 1) sm += __shfl_xor(sm, d, 64);
            if (m == 0) {
                int row = rt * 256 + wy * 64 + mt * 16 + q * 4 + reg;
                pmax[(size_t)row * 64 + ct * 2 + wx] = mx;
                psum[(size_t)row * 64 + ct * 2 + wx] = sm;
            }
        }
    }
}

// combine 64 col-tile partials per row -> per-row loss term
__global__ __launch_bounds__(256) void row_finalize_kernel(const float* __restrict__ pmax,
        const float* __restrict__ psum, const float* __restrict__ diagv,
        const int* __restrict__ label, float* __restrict__ terms) {
    int gid  = blockIdx.x * blockDim.x + threadIdx.x;
    int row  = gid >> 6;
    int lane = threadIdx.x & 63;
    if (row >= BATCH) return;
    float m = pmax[(size_t)row * 64 + lane];
    float s = psum[(size_t)row * 64 + lane];
    float M = m;
#pragma unroll
    for (int d = 1; d < 64; d <<= 1) M = fmaxf(M, __shfl_xor(M, d, 64));
    s *= __expf(m - M);
#pragma unroll
    for (int d = 1; d < 64; d <<= 1) s += __shfl_xor(s, d, 64);
    if (lane == 0) {
        float lse = M + __logf(s);
        terms[row] = -(float)label[row] * (diagv[row] - lse);
    }
}

__global__ __launch_bounds__(256) void final_sum_kernel(const float* __restrict__ terms,
                                                        float* __restrict__ out) {
    __shared__ float red[256];
    float s = 0.0f;
    for (int i = threadIdx.x; i < BATCH; i += 256) s += terms[i];
    red[threadIdx.x] = s;
    __syncthreads();
    for (int w = 128; w > 0; w >>= 1) {
        if (threadIdx.x < (unsigned)w) red[threadIdx.x] += red[threadIdx.x + w];
        __syncthreads();
    }
    // contrastive mean + triplet loss (identically 1.0: d_ap==d_an, relu(margin)=1)
    if (threadIdx.x == 0) out[0] = red[0] / (float)BATCH + 1.0f;
}

// ---------------------------------------------------------------------------
extern "C" void kernel_launch(void* const* d_in, const int* in_sizes, int n_in,
                              void* d_out, int out_size, void* d_ws, size_t ws_size,
                              hipStream_t stream) {
    const float* image   = (const float*)d_in[0];
    const float* x_nodes = (const float*)d_in[1];
    const int*   edge    = (const int*)d_in[2];
    const int*   label   = (const int*)d_in[3];
    const float* W_img1  = (const float*)d_in[4];
    const float* b_img1  = (const float*)d_in[5];
    const float* W_img2  = (const float*)d_in[6];
    const float* b_img2  = (const float*)d_in[7];
    const float* W_g1    = (const float*)d_in[8];
    const float* b_g1    = (const float*)d_in[9];
    const float* W_g2    = (const float*)d_in[10];
    const float* b_g2    = (const float*)d_in[11];
    const int* src = edge;              // edge_index[0]
    const int* dst = edge + N_EDGES;    // edge_index[1]

    // workspace carve-up (256B aligned regions)
    char* ws = (char*)d_ws;
    size_t off = 0;
    auto alloc = [&](size_t bytes) { size_t r = off; off = (off + bytes + 255) & ~(size_t)255; return r; };
    float* dinv     = (float*)(ws + alloc(N_NODES * 4));
    int*   cnt      = (int*)  (ws + alloc(N_NODES * 4));
    int*   offs     = (int*)  (ws + alloc((N_NODES + 1) * 4));
    int*   cursor   = (int*)  (ws + alloc(N_NODES * 4));
    int*   csr_src  = (int*)  (ws + alloc(N_EDGES * 4));
    float* csr_w    = (float*)(ws + alloc(N_EDGES * 4));
    int*   flag     = (int*)  (ws + alloc(N_NODES * 4));
    int*   pos      = (int*)  (ws + alloc(N_NODES * 4));
    int*   nodelist = (int*)  (ws + alloc(BATCH * 4));
    int*   pcnt     = (int*)  (ws + alloc(4));
    int*   bsum     = (int*)  (ws + alloc(64 * 4));
    float* xw1      = (float*)(ws + alloc((size_t)N_NODES * HID * 4));
    float* h        = (float*)(ws + alloc((size_t)N_NODES * HID * 4));
    unsigned short* g2inext = (unsigned short*)(ws + alloc((size_t)BATCH * 2 * HID * 2));
    unsigned short* g2ext   = (unsigned short*)(ws + alloc((size_t)BATCH * 2 * DIM * 2));
    unsigned short* himgext = (unsigned short*)(ws + alloc((size_t)BATCH * 2 * HID * 2));
    unsigned short* extbuf  = (unsigned short*)(ws + alloc((size_t)N_NODES * 2 * DIM * 2));
    unsigned short* imgext  = (unsigned short*)(ws + alloc((size_t)BATCH * 2 * DIM * 2));
    unsigned short* wext1   = (unsigned short*)(ws + alloc((size_t)HID * 2 * DIM * 2));
    unsigned short* wext2   = (unsigned short*)(ws + alloc((size_t)DIM * 2 * HID * 2));
    unsigned short* wext3   = (unsigned short*)(ws + alloc((size_t)HID * 2 * DIM * 2));
    unsigned short* wext4   = (unsigned short*)(ws + alloc((size_t)DIM * 2 * HID * 2));
    unsigned short* Bext    = (unsigned short*)(ws + alloc((size_t)BATCH * 2 * DIM * 2));
    float* pmax  = (float*)(ws + alloc((size_t)BATCH * 64 * 4));
    float* psum  = (float*)(ws + alloc((size_t)BATCH * 64 * 4));
    float* diagv = (float*)(ws + alloc(BATCH * 4));
    float* terms = (float*)(ws + alloc(BATCH * 4));

    const int SCAN_BLOCKS = (N_NODES + 255) / 256;   // 40

    // graph build: CSR by dst (storing src+weight) + dinv + label compaction
    zero_init_kernel<<<SCAN_BLOCKS, 256, 0, stream>>>(cnt, cursor, flag, pcnt);
    count_mark_kernel<<<(N_EDGES + 255) / 256, 256, 0, stream>>>(dst, label, cnt, flag);
    scanA_kernel<<<SCAN_BLOCKS, 256, 0, stream>>>(cnt, offs, bsum, dinv);
    scanC_kernel<<<SCAN_BLOCKS, 256, 0, stream>>>(offs, bsum);
    fill_csr_kernel<<<(N_EDGES + 255) / 256, 256, 0, stream>>>(src, dst, offs, dinv,
                                                               cursor, csr_src, csr_w);
    compact_kernel<<<SCAN_BLOCKS, 256, 0, stream>>>(flag, pcnt, nodelist, pos);

    // fused operand builds: x_nodes + image row-ext; all 4 weight col-ext
    build_rowext2_kernel<<<((N_NODES + BATCH) * 128) / 256, 256, 0, stream>>>(
        x_nodes, image, extbuf, imgext);
    build_colext4_kernel<<<512, 256, 0, stream>>>(W_g1, W_img1, W_g2, W_img2,
                                                  wext1, wext3, wext2, wext4);

    // GCN layer 1: xw1 = x_nodes @ W_g1 (split-bf16 MFMA); h = relu(A-hat xw1 + b1)
    mfma_gemm_kernel<0, 0, 0><<<dim3(HID / 64, (N_NODES + 127) / 128), 256, 0, stream>>>(
        extbuf, wext1, nullptr, xw1, N_NODES, HID, DIM, nullptr);
    agg256_kernel<1, 1, 0, 0><<<(N_NODES + 3) / 4, 256, 0, stream>>>(
        xw1, dinv, csr_src, csr_w, offs, b_g1, h, nullptr, nullptr);

    // GCN layer 2 (reordered, compact): g2inext = ext(A-hat h) on label rows;
    // g2ext = ext(g2in @ W_g2 + b2) on compact rows (M = pcnt, device-side)
    agg256_kernel<0, 0, 1, 1><<<BATCH / 4, 256, 0, stream>>>(
        h, dinv, csr_src, csr_w, offs, nullptr, g2inext, nodelist, pcnt);
    mfma_gemm_kernel<1, 0, 1><<<dim3(DIM / 64, BATCH / 128), 256, 0, stream>>>(
        g2inext, wext2, b_g2, g2ext, BATCH, DIM, HID, pcnt);

    // image MLP: himgext = ext(relu(image@W1+b1)); Bext = ext(relu(himg@W2+b2))
    mfma_gemm_kernel<1, 1, 1><<<dim3(HID / 64, BATCH / 128), 256, 0, stream>>>(
        imgext, wext3, b_img1, himgext, BATCH, HID, DIM, nullptr);
    mfma_gemm_kernel<1, 1, 1><<<dim3(DIM / 64, BATCH / 128), 256, 0, stream>>>(
        himgext, wext4, b_img2, Bext, BATCH, DIM, HID, nullptr);

    // fused logits (split-bf16 MFMA, 256x128 tile) + online softmax partials
    logits_mfma_kernel<<<512, 512, 0, stream>>>(g2ext, Bext, label, pos,
                                                pmax, psum, diagv);
    row_finalize_kernel<<<(BATCH * 64) / 256, 256, 0, stream>>>(pmax, psum, diagv, label, terms);
    final_sum_kernel<<<1, 256, 0, stream>>>(terms, (float*)d_out);
}

// Round 10
// 331.039 us; speedup vs baseline: 1.6211x; 1.0090x over previous
//
#include <hip/hip_runtime.h>
#include <hip/hip_bf16.h>
#include <math.h>

// Problem constants (fixed by the reference)
#define N_NODES 10000
#define N_EDGES 160000
#define BATCH   4096
#define DIM     512
#define HID     256

typedef short short8 __attribute__((ext_vector_type(8)));
typedef float f32x4  __attribute__((ext_vector_type(4)));

// ---------------------------------------------------------------------------
// graph build utilities
// ---------------------------------------------------------------------------
__global__ void zero_init_kernel(int* cnt, int* cursor, int* flag, int* pcnt,
                                 float* facc, int* fcnt) {
    int i = blockIdx.x * blockDim.x + threadIdx.x;
    if (i < N_NODES) { cnt[i] = 0; cursor[i] = 0; flag[i] = 0; }
    if (i == 0) { pcnt[0] = 0; facc[0] = 0.0f; fcnt[0] = 0; }
}

// degree count + label marking in one pass
__global__ void count_mark_kernel(const int* __restrict__ dst, const int* __restrict__ label,
                                  int* __restrict__ cnt, int* __restrict__ flag) {
    int e = blockIdx.x * blockDim.x + threadIdx.x;
    if (e < N_EDGES) atomicAdd(&cnt[dst[e]], 1);
    if (e < BATCH) flag[label[e]] = 1;          // idempotent, races benign
}

// block-local scan (256/block) + per-block sums; also computes dinv
__global__ __launch_bounds__(256) void scanA_kernel(const int* __restrict__ cnt,
        int* __restrict__ offs, int* __restrict__ bsum, float* __restrict__ dinv) {
    __shared__ int sh[256];
    int i = blockIdx.x * 256 + threadIdx.x;
    int v = (i < N_NODES) ? cnt[i] : 0;
    if (i < N_NODES) dinv[i] = rsqrtf((float)(1 + v));
    sh[threadIdx.x] = v;
    __syncthreads();
    for (int off = 1; off < 256; off <<= 1) {
        int t = (threadIdx.x >= (unsigned)off) ? sh[threadIdx.x - off] : 0;
        __syncthreads();
        sh[threadIdx.x] += t;
        __syncthreads();
    }
    if (i < N_NODES) offs[i] = sh[threadIdx.x] - v;   // exclusive within block
    if (threadIdx.x == 255) bsum[blockIdx.x] = sh[255];
}

// adds prefix of bsum (computed in-kernel; 40 entries)
__global__ __launch_bounds__(256) void scanC_kernel(int* __restrict__ offs,
                                                    const int* __restrict__ bsum) {
    int pre = 0;
    for (int b = 0; b < (int)blockIdx.x; ++b) pre += bsum[b];
    int i = blockIdx.x * 256 + threadIdx.x;
    if (i < N_NODES) offs[i] += pre;
    if (i == 0) offs[N_NODES] = N_EDGES;
}

// CSR fill (storing src id + dinv[src]) fused with label-set compaction
__global__ void fill_compact_kernel(const int* __restrict__ src, const int* __restrict__ dst,
                                    const int* __restrict__ offs, const float* __restrict__ dinv,
                                    int* __restrict__ cursor, int* __restrict__ csr_src,
                                    float* __restrict__ csr_w, const int* __restrict__ flag,
                                    int* __restrict__ pcnt, int* __restrict__ nodelist,
                                    int* __restrict__ pos) {
    int e = blockIdx.x * blockDim.x + threadIdx.x;
    if (e < N_EDGES) {
        int d = dst[e];
        int s = src[e];
        int p = offs[d] + atomicAdd(&cursor[d], 1);
        csr_src[p] = s;
        csr_w[p]   = dinv[s];
    }
    if (e < N_NODES && flag[e]) {
        int p = atomicAdd(pcnt, 1);
        nodelist[p] = e;
        pos[e] = p;
    }
}

// ---------------------------------------------------------------------------
// split-bf16 helpers
// ---------------------------------------------------------------------------
__device__ __forceinline__ unsigned short f2bf(float x) {
    unsigned u = __float_as_uint(x);
    return (unsigned short)((u + 0x7FFFu + ((u >> 16) & 1u)) >> 16);   // RNE
}
__device__ __forceinline__ float bf2f(unsigned short h) {
    return __uint_as_float(((unsigned)h) << 16);
}

// ---------------------------------------------------------------------------
// GCN aggregation over 256 channels: wave-per-node, float4 per lane.
// EXTOUT: emit split-bf16 [hi|lo] row (2x256) instead of fp32.
// ---------------------------------------------------------------------------
template <int BIAS, int RELU, int COMPACT, int EXTOUT>
__global__ __launch_bounds__(256) void agg256_kernel(const float* __restrict__ xw,
        const float* __restrict__ dinv, const int* __restrict__ csr_src,
        const float* __restrict__ csr_w, const int* __restrict__ offs,
        const float* __restrict__ bias, void* __restrict__ out,
        const int* __restrict__ nodelist, const int* __restrict__ pcnt) {
    int wid  = blockIdx.x * 4 + (threadIdx.x >> 6);
    int lane = threadIdx.x & 63;
    int n;
    if (COMPACT) { if (wid >= pcnt[0]) return; n = nodelist[wid]; }
    else         { if (wid >= N_NODES) return; n = wid; }
    int c4 = lane * 4;
    float di = dinv[n];
    float d2 = di * di;
    float4 self = *(const float4*)&xw[(size_t)n * 256 + c4];
    float4 a = make_float4(d2 * self.x, d2 * self.y, d2 * self.z, d2 * self.w);
    int s0 = offs[n], s1 = offs[n + 1];
    int i = s0;
    for (; i + 1 < s1; i += 2) {              // 2 gathers in flight
        int sr0 = csr_src[i], sr1 = csr_src[i + 1];
        float w0 = di * csr_w[i], w1 = di * csr_w[i + 1];
        float4 v0 = *(const float4*)&xw[(size_t)sr0 * 256 + c4];
        float4 v1 = *(const float4*)&xw[(size_t)sr1 * 256 + c4];
        a.x = fmaf(w0, v0.x, a.x); a.y = fmaf(w0, v0.y, a.y);
        a.z = fmaf(w0, v0.z, a.z); a.w = fmaf(w0, v0.w, a.w);
        a.x = fmaf(w1, v1.x, a.x); a.y = fmaf(w1, v1.y, a.y);
        a.z = fmaf(w1, v1.z, a.z); a.w = fmaf(w1, v1.w, a.w);
    }
    if (i < s1) {
        int sr = csr_src[i];
        float wgt = di * csr_w[i];
        float4 v = *(const float4*)&xw[(size_t)sr * 256 + c4];
        a.x = fmaf(wgt, v.x, a.x); a.y = fmaf(wgt, v.y, a.y);
        a.z = fmaf(wgt, v.z, a.z); a.w = fmaf(wgt, v.w, a.w);
    }
    if (BIAS) {
        float4 b = *(const float4*)&bias[c4];
        a.x += b.x; a.y += b.y; a.z += b.z; a.w += b.w;
    }
    if (RELU) {
        a.x = fmaxf(a.x, 0.f); a.y = fmaxf(a.y, 0.f);
        a.z = fmaxf(a.z, 0.f); a.w = fmaxf(a.w, 0.f);
    }
    int orow = COMPACT ? wid : n;
    if (EXTOUT) {
        ushort4 h, l;
        h.x = f2bf(a.x); l.x = f2bf(a.x - bf2f(h.x));
        h.y = f2bf(a.y); l.y = f2bf(a.y - bf2f(h.y));
        h.z = f2bf(a.z); l.z = f2bf(a.z - bf2f(h.z));
        h.w = f2bf(a.w); l.w = f2bf(a.w - bf2f(h.w));
        unsigned short* ob = (unsigned short*)out + (size_t)orow * 512;
        *(ushort4*)&ob[c4]       = h;
        *(ushort4*)&ob[256 + c4] = l;
    } else {
        *(float4*)((float*)out + (size_t)orow * 256 + c4) = a;
    }
}

// ---------------------------------------------------------------------------
// ALL operand builds in one launch: row-ext for x_nodes + image, col-ext for
// the 4 weight matrices. Segmented flat grid.
// ---------------------------------------------------------------------------
__global__ __launch_bounds__(256) void build_all_kernel(
        const float* __restrict__ xn, const float* __restrict__ im,
        const float* __restrict__ Wg1, const float* __restrict__ Wi1,
        const float* __restrict__ Wg2, const float* __restrict__ Wi2,
        unsigned short* __restrict__ dxn, unsigned short* __restrict__ dim_,
        unsigned short* __restrict__ o1, unsigned short* __restrict__ o3,
        unsigned short* __restrict__ o2, unsigned short* __restrict__ o4) {
    int id = blockIdx.x * 256 + threadIdx.x;
    const int NA = (N_NODES + BATCH) * 128;        // row-ext domain
    if (id < NA) {
        const int NX = N_NODES * 128;
        int lid = (id < NX) ? id : id - NX;
        const float* src = (id < NX) ? xn : im;
        unsigned short* dst = (id < NX) ? dxn : dim_;
        int r  = lid >> 7;
        int c4 = (lid & 127) << 2;
        float4 v = *(const float4*)&src[(size_t)r * DIM + c4];
        ushort4 h, l;
        h.x = f2bf(v.x); l.x = f2bf(v.x - bf2f(h.x));
        h.y = f2bf(v.y); l.y = f2bf(v.y - bf2f(h.y));
        h.z = f2bf(v.z); l.z = f2bf(v.z - bf2f(h.z));
        h.w = f2bf(v.w); l.w = f2bf(v.w - bf2f(h.w));
        unsigned short* base = dst + (size_t)r * 1024;
        *(ushort4*)&base[c4]       = h;
        *(ushort4*)&base[512 + c4] = l;
    } else {
        int lid2 = id - NA;                        // [0, 131072)
        int seg  = lid2 >> 15;
        int lid  = lid2 & 32767;
        const float* src; unsigned short* dst; int K, N, kshift;
        if (seg == 0)      { src = Wg1; dst = o1; K = 512; N = 256; kshift = 7; }
        else if (seg == 1) { src = Wi1; dst = o3; K = 512; N = 256; kshift = 7; }
        else if (seg == 2) { src = Wg2; dst = o2; K = 256; N = 512; kshift = 6; }
        else               { src = Wi2; dst = o4; K = 256; N = 512; kshift = 6; }
        int n  = lid >> kshift;
        int c4 = (lid & ((1 << kshift) - 1)) << 2;
        float v0 = src[(size_t)(c4 + 0) * N + n];
        float v1 = src[(size_t)(c4 + 1) * N + n];
        float v2 = src[(size_t)(c4 + 2) * N + n];
        float v3 = src[(size_t)(c4 + 3) * N + n];
        ushort4 h, l;
        h.x = f2bf(v0); l.x = f2bf(v0 - bf2f(h.x));
        h.y = f2bf(v1); l.y = f2bf(v1 - bf2f(h.y));
        h.z = f2bf(v2); l.z = f2bf(v2 - bf2f(h.z));
        h.w = f2bf(v3); l.w = f2bf(v3 - bf2f(h.w));
        unsigned short* base = dst + (size_t)n * 2 * K;
        *(ushort4*)&base[c4]     = h;
        *(ushort4*)&base[K + c4] = l;
    }
}

// ---------------------------------------------------------------------------
__device__ __forceinline__ void gld_lds16(const void* g, void* l) {
    __builtin_amdgcn_global_load_lds(
        (const __attribute__((address_space(1))) unsigned int*)g,
        (__attribute__((address_space(3))) unsigned int*)l, 16, 0, 0);
}

// ---------------------------------------------------------------------------
// Dense MFMA GEMM body on [hi|lo] ext operands: C = A.B^T, 3-product split-bf16.
// tile 128x64, 4 waves (2x2), wave = 64x32. Runtime bias/relu/ext flags are
// block-uniform (scalar branches). sh = 12288 ushorts (A 16KB + B 8KB).
// ---------------------------------------------------------------------------
__device__ __forceinline__ void gemm_body(
        const unsigned short* __restrict__ Aext, const unsigned short* __restrict__ Bext,
        const float* __restrict__ bias, void* __restrict__ Cout,
        int M, int N, int K, int rt, int ct, int relu, int ext,
        unsigned short* sh) {
    int t    = threadIdx.x;
    int lane = t & 63;
    int w    = t >> 6;
    int wy   = w >> 1, wx = w & 1;
    int m    = lane & 15;
    int q    = lane >> 4;

    int ra0 = rt * 128 + w * 16 + m;        if (ra0 > M - 1) ra0 = M - 1;
    int ra1 = rt * 128 + (4 + w) * 16 + m;  if (ra1 > M - 1) ra1 = M - 1;
    int rb  = ct * 64 + w * 16 + m;
    const unsigned short* pa0 = Aext + (size_t)ra0 * 2 * K + q * 8;
    const unsigned short* pa1 = Aext + (size_t)ra1 * 2 * K + q * 8;
    const unsigned short* pb  = Bext + (size_t)rb  * 2 * K + q * 8;
    unsigned short* Bs = sh + 8192;

    f32x4 acc[4][2];
#pragma unroll
    for (int i = 0; i < 4; ++i)
#pragma unroll
        for (int j = 0; j < 2; ++j) acc[i][j] = (f32x4){0.f, 0.f, 0.f, 0.f};

    for (int k0 = 0; k0 < K; k0 += 32) {
        gld_lds16(pa0 + k0,     sh + (w * 2 + 0) * 512);
        gld_lds16(pa0 + K + k0, sh + (w * 2 + 1) * 512);
        gld_lds16(pa1 + k0,     sh + ((4 + w) * 2 + 0) * 512);
        gld_lds16(pa1 + K + k0, sh + ((4 + w) * 2 + 1) * 512);
        gld_lds16(pb + k0,      Bs + (w * 2 + 0) * 512);
        gld_lds16(pb + K + k0,  Bs + (w * 2 + 1) * 512);
        __syncthreads();
        short8 ah[4], al[4];
#pragma unroll
        for (int i = 0; i < 4; ++i) {
            ah[i] = *(const short8*)&sh[((wy * 4 + i) * 2 + 0) * 512 + lane * 8];
            al[i] = *(const short8*)&sh[((wy * 4 + i) * 2 + 1) * 512 + lane * 8];
        }
#pragma unroll
        for (int j = 0; j < 2; ++j) {
            short8 bh = *(const short8*)&Bs[((wx * 2 + j) * 2 + 0) * 512 + lane * 8];
            short8 bl = *(const short8*)&Bs[((wx * 2 + j) * 2 + 1) * 512 + lane * 8];
#pragma unroll
            for (int i = 0; i < 4; ++i) {
                acc[i][j] = __builtin_amdgcn_mfma_f32_16x16x32_bf16(ah[i], bh, acc[i][j], 0, 0, 0);
                acc[i][j] = __builtin_amdgcn_mfma_f32_16x16x32_bf16(al[i], bh, acc[i][j], 0, 0, 0);
                acc[i][j] = __builtin_amdgcn_mfma_f32_16x16x32_bf16(ah[i], bl, acc[i][j], 0, 0, 0);
            }
        }
        __syncthreads();
    }

    float b0 = 0.f, b1 = 0.f;
    if (bias) {
        b0 = bias[ct * 64 + wx * 32 + m];
        b1 = bias[ct * 64 + wx * 32 + 16 + m];
    }
#pragma unroll
    for (int i = 0; i < 4; ++i) {
        int rbase = rt * 128 + wy * 64 + i * 16 + q * 4;
#pragma unroll
        for (int j = 0; j < 2; ++j) {
            int col = ct * 64 + wx * 32 + j * 16 + m;
            float bb = j ? b1 : b0;
#pragma unroll
            for (int reg = 0; reg < 4; ++reg) {
                int row = rbase + reg;
                if (row < M) {
                    float v = acc[i][j][reg] + bb;
                    if (relu) v = fmaxf(v, 0.f);
                    if (ext == 0) {
                        ((float*)Cout)[(size_t)row * N + col] = v;
                    } else {
                        unsigned short hi = f2bf(v);
                        unsigned short lo = f2bf(v - bf2f(hi));
                        unsigned short* ob = (unsigned short*)Cout + (size_t)row * 2 * N;
                        ob[col] = hi; ob[N + col] = lo;
                    }
                }
            }
        }
    }
}

__global__ __launch_bounds__(256, 4) void mfma_gemm_kernel(
        const unsigned short* __restrict__ Aext, const unsigned short* __restrict__ Bext,
        const float* __restrict__ bias, void* __restrict__ Cout, int M, int N, int K,
        int relu, int ext) {
    __shared__ __align__(16) unsigned short sh[12288];
    gemm_body(Aext, Bext, bias, Cout, M, N, K, blockIdx.y, blockIdx.x, relu, ext, sh);
}

// GCN2 (ct 0..N0/64) + MLP1 (ct N0/64..) in one launch — independent GEMMs.
__global__ __launch_bounds__(256, 4) void mfma_gemm_dual_kernel(
        const unsigned short* __restrict__ A0, const unsigned short* __restrict__ B0,
        const float* __restrict__ bias0, void* __restrict__ C0,
        const int* __restrict__ Mptr0, int N0, int K0,
        const unsigned short* __restrict__ A1, const unsigned short* __restrict__ B1,
        const float* __restrict__ bias1, void* __restrict__ C1,
        int M1, int N1, int K1) {
    __shared__ __align__(16) unsigned short sh[12288];
    int split = N0 / 64;
    if ((int)blockIdx.x < split) {
        gemm_body(A0, B0, bias0, C0, Mptr0[0], N0, K0, blockIdx.y, blockIdx.x, 0, 1, sh);
    } else {
        gemm_body(A1, B1, bias1, C1, M1, N1, K1, blockIdx.y, blockIdx.x - split, 1, 1, sh);
    }
}

// ---------------------------------------------------------------------------
// logits = A @ B^T on [hi|lo] ext (K=512, 3-product split-bf16) + fused online
// softmax partials. 256x128 tile, 512 thr = 8 waves (4x2), wave = 64x64.
// 48 KB LDS -> 2 blocks/CU; 512 blocks full residency. In-kernel A-gather via
// pos[label]; fragment-order LDS (conflict-free); XCD swizzle.
// ---------------------------------------------------------------------------
__global__ __launch_bounds__(512, 4) void logits_mfma_kernel(
        const unsigned short* __restrict__ Aext, const unsigned short* __restrict__ Bext,
        const int* __restrict__ label, const int* __restrict__ pos,
        float* __restrict__ pmax, float* __restrict__ psum, float* __restrict__ diagv) {
    __shared__ __align__(16) unsigned short sh[24576];   // 48 KB: A 32KB (16 chunks) + B 16KB (8)
    unsigned short* Bs = sh + 16384;

    int t    = threadIdx.x;
    int lane = t & 63;
    int w    = t >> 6;            // wave 0..7
    int wy   = w >> 1, wx = w & 1;
    // XCD swizzle over 512 blocks = 16 rt x 32 ct; per-XCD region 8rt x 8ct
    int g   = blockIdx.x;
    int xcd = g & 7, s = g >> 3;              // s in 0..63
    int rt  = (xcd & 1) * 8 + (s & 7);        // 0..15 (256-row tiles)
    int ct  = (xcd >> 1) * 8 + (s >> 3);      // 0..31 (128-col tiles)
    int m    = lane & 15;
    int q    = lane >> 4;

    // staging: wave w owns A chunks (w*2, w*2+1) and B chunk w (16 rows each)
    int ar0 = pos[label[rt * 256 + (w * 2 + 0) * 16 + m]];
    int ar1 = pos[label[rt * 256 + (w * 2 + 1) * 16 + m]];
    const unsigned short* ap0 = Aext + (size_t)ar0 * 1024 + q * 8;
    const unsigned short* ap1 = Aext + (size_t)ar1 * 1024 + q * 8;
    const unsigned short* bp  = Bext + (size_t)(ct * 128 + w * 16 + m) * 1024 + q * 8;

    f32x4 acc[4][4];
#pragma unroll
    for (int i = 0; i < 4; ++i)
#pragma unroll
        for (int j = 0; j < 4; ++j) acc[i][j] = (f32x4){0.f, 0.f, 0.f, 0.f};

    for (int k0 = 0; k0 < 512; k0 += 32) {
        gld_lds16(ap0 + k0,       sh + ((w * 2 + 0) * 2 + 0) * 512);
        gld_lds16(ap0 + 512 + k0, sh + ((w * 2 + 0) * 2 + 1) * 512);
        gld_lds16(ap1 + k0,       sh + ((w * 2 + 1) * 2 + 0) * 512);
        gld_lds16(ap1 + 512 + k0, sh + ((w * 2 + 1) * 2 + 1) * 512);
        gld_lds16(bp + k0,        Bs + (w * 2 + 0) * 512);
        gld_lds16(bp + 512 + k0,  Bs + (w * 2 + 1) * 512);
        __syncthreads();                 // drains vmcnt: staging complete
        short8 ah[4], al[4];
#pragma unroll
        for (int i = 0; i < 4; ++i) {
            ah[i] = *(const short8*)&sh[((wy * 4 + i) * 2 + 0) * 512 + lane * 8];
            al[i] = *(const short8*)&sh[((wy * 4 + i) * 2 + 1) * 512 + lane * 8];
        }
#pragma unroll
        for (int j = 0; j < 4; ++j) {
            short8 bh = *(const short8*)&Bs[((wx * 4 + j) * 2 + 0) * 512 + lane * 8];
            short8 bl = *(const short8*)&Bs[((wx * 4 + j) * 2 + 1) * 512 + lane * 8];
#pragma unroll
            for (int i = 0; i < 4; ++i) {
                acc[i][j] = __builtin_amdgcn_mfma_f32_16x16x32_bf16(ah[i], bh, acc[i][j], 0, 0, 0);
                acc[i][j] = __builtin_amdgcn_mfma_f32_16x16x32_bf16(al[i], bh, acc[i][j], 0, 0, 0);
                acc[i][j] = __builtin_amdgcn_mfma_f32_16x16x32_bf16(ah[i], bl, acc[i][j], 0, 0, 0);
            }
        }
        __syncthreads();                 // WAR before next staging
    }

    // C/D layout: col = lane&15, row = q*4 + reg (within each 16x16 tile)
    // diagonal: block touches it iff ct>>1 == rt
    if ((ct >> 1) == rt) {
#pragma unroll
        for (int i = 0; i < 4; ++i)
#pragma unroll
            for (int j = 0; j < 4; ++j)
#pragma unroll
                for (int reg = 0; reg < 4; ++reg) {
                    int row = rt * 256 + wy * 64 + i * 16 + q * 4 + reg;
                    int col = ct * 128 + wx * 64 + j * 16 + m;
                    if (row == col) diagv[row] = acc[i][j][reg];
                }
    }

    // per-row (max, sumexp) over this wave's 64 cols
#pragma unroll
    for (int mt = 0; mt < 4; ++mt) {
#pragma unroll
        for (int reg = 0; reg < 4; ++reg) {
            float v0 = acc[mt][0][reg], v1 = acc[mt][1][reg];
            float v2 = acc[mt][2][reg], v3 = acc[mt][3][reg];
            float mx = fmaxf(fmaxf(v0, v1), fmaxf(v2, v3));
#pragma unroll
            for (int d = 1; d < 16; d <<= 1) mx = fmaxf(mx, __shfl_xor(mx, d, 64));
            float sm = __expf(v0 - mx) + __expf(v1 - mx) + __expf(v2 - mx) + __expf(v3 - mx);
#pragma unroll
            for (int d = 1; d < 16; d <<= 1) sm += __shfl_xor(sm, d, 64);
            if (m == 0) {
                int row = rt * 256 + wy * 64 + mt * 16 + q * 4 + reg;
                pmax[(size_t)row * 64 + ct * 2 + wx] = mx;
                psum[(size_t)row * 64 + ct * 2 + wx] = sm;
            }
        }
    }
}

// combine 64 col-tile partials per row -> per-row loss term; fused final
// reduction via device-scope atomics (last block writes out[0]).
__global__ __launch_bounds__(256) void row_finalize_kernel(const float* __restrict__ pmax,
        const float* __restrict__ psum, const float* __restrict__ diagv,
        const int* __restrict__ label, float* __restrict__ facc, int* __restrict__ fcnt,
        float* __restrict__ out) {
    __shared__ float wsum[4];
    int gid  = blockIdx.x * blockDim.x + threadIdx.x;
    int row  = gid >> 6;
    int lane = threadIdx.x & 63;
    int wv   = threadIdx.x >> 6;
    float term = 0.0f;
    if (row < BATCH) {
        float m = pmax[(size_t)row * 64 + lane];
        float s = psum[(size_t)row * 64 + lane];
        float M = m;
#pragma unroll
        for (int d = 1; d < 64; d <<= 1) M = fmaxf(M, __shfl_xor(M, d, 64));
        s *= __expf(m - M);
#pragma unroll
        for (int d = 1; d < 64; d <<= 1) s += __shfl_xor(s, d, 64);
        float lse = M + __logf(s);
        term = -(float)label[row] * (diagv[row] - lse);
    }
    if (lane == 0) wsum[wv] = (row < BATCH) ? term : 0.0f;
    __syncthreads();
    if (threadIdx.x == 0) {
        float p = wsum[0] + wsum[1] + wsum[2] + wsum[3];
        atomicAdd(facc, p);
        __threadfence();
        int old = atomicAdd(fcnt, 1);
        if (old == (int)gridDim.x - 1) {
            float tot = atomicAdd(facc, 0.0f);   // device-scope coherent read
            // contrastive mean + triplet loss (identically 1.0: d_ap==d_an)
            out[0] = tot / (float)BATCH + 1.0f;
        }
    }
}

// ---------------------------------------------------------------------------
extern "C" void kernel_launch(void* const* d_in, const int* in_sizes, int n_in,
                              void* d_out, int out_size, void* d_ws, size_t ws_size,
                              hipStream_t stream) {
    const float* image   = (const float*)d_in[0];
    const float* x_nodes = (const float*)d_in[1];
    const int*   edge    = (const int*)d_in[2];
    const int*   label   = (const int*)d_in[3];
    const float* W_img1  = (const float*)d_in[4];
    const float* b_img1  = (const float*)d_in[5];
    const float* W_img2  = (const float*)d_in[6];
    const float* b_img2  = (const float*)d_in[7];
    const float* W_g1    = (const float*)d_in[8];
    const float* b_g1    = (const float*)d_in[9];
    const float* W_g2    = (const float*)d_in[10];
    const float* b_g2    = (const float*)d_in[11];
    const int* src = edge;              // edge_index[0]
    const int* dst = edge + N_EDGES;    // edge_index[1]

    // workspace carve-up (256B aligned regions)
    char* ws = (char*)d_ws;
    size_t off = 0;
    auto alloc = [&](size_t bytes) { size_t r = off; off = (off + bytes + 255) & ~(size_t)255; return r; };
    float* dinv     = (float*)(ws + alloc(N_NODES * 4));
    int*   cnt      = (int*)  (ws + alloc(N_NODES * 4));
    int*   offs     = (int*)  (ws + alloc((N_NODES + 1) * 4));
    int*   cursor   = (int*)  (ws + alloc(N_NODES * 4));
    int*   csr_src  = (int*)  (ws + alloc(N_EDGES * 4));
    float* csr_w    = (float*)(ws + alloc(N_EDGES * 4));
    int*   flag     = (int*)  (ws + alloc(N_NODES * 4));
    int*   pos      = (int*)  (ws + alloc(N_NODES * 4));
    int*   nodelist = (int*)  (ws + alloc(BATCH * 4));
    int*   pcnt     = (int*)  (ws + alloc(4));
    int*   bsum     = (int*)  (ws + alloc(64 * 4));
    float* facc     = (float*)(ws + alloc(4));
    int*   fcnt     = (int*)  (ws + alloc(4));
    float* xw1      = (float*)(ws + alloc((size_t)N_NODES * HID * 4));
    float* h        = (float*)(ws + alloc((size_t)N_NODES * HID * 4));
    unsigned short* g2inext = (unsigned short*)(ws + alloc((size_t)BATCH * 2 * HID * 2));
    unsigned short* g2ext   = (unsigned short*)(ws + alloc((size_t)BATCH * 2 * DIM * 2));
    unsigned short* himgext = (unsigned short*)(ws + alloc((size_t)BATCH * 2 * HID * 2));
    unsigned short* extbuf  = (unsigned short*)(ws + alloc((size_t)N_NODES * 2 * DIM * 2));
    unsigned short* imgext  = (unsigned short*)(ws + alloc((size_t)BATCH * 2 * DIM * 2));
    unsigned short* wext1   = (unsigned short*)(ws + alloc((size_t)HID * 2 * DIM * 2));
    unsigned short* wext2   = (unsigned short*)(ws + alloc((size_t)DIM * 2 * HID * 2));
    unsigned short* wext3   = (unsigned short*)(ws + alloc((size_t)HID * 2 * DIM * 2));
    unsigned short* wext4   = (unsigned short*)(ws + alloc((size_t)DIM * 2 * HID * 2));
    unsigned short* Bext    = (unsigned short*)(ws + alloc((size_t)BATCH * 2 * DIM * 2));
    float* pmax  = (float*)(ws + alloc((size_t)BATCH * 64 * 4));
    float* psum  = (float*)(ws + alloc((size_t)BATCH * 64 * 4));
    float* diagv = (float*)(ws + alloc(BATCH * 4));

    const int SCAN_BLOCKS = (N_NODES + 255) / 256;   // 40

    // graph build: CSR by dst (storing src+weight) + dinv + label compaction
    zero_init_kernel<<<SCAN_BLOCKS, 256, 0, stream>>>(cnt, cursor, flag, pcnt, facc, fcnt);
    count_mark_kernel<<<(N_EDGES + 255) / 256, 256, 0, stream>>>(dst, label, cnt, flag);
    scanA_kernel<<<SCAN_BLOCKS, 256, 0, stream>>>(cnt, offs, bsum, dinv);
    scanC_kernel<<<SCAN_BLOCKS, 256, 0, stream>>>(offs, bsum);
    fill_compact_kernel<<<(N_EDGES + 255) / 256, 256, 0, stream>>>(
        src, dst, offs, dinv, cursor, csr_src, csr_w, flag, pcnt, nodelist, pos);

    // all operand builds (x_nodes + image row-ext, 4 weight col-ext) in one launch
    build_all_kernel<<<((N_NODES + BATCH) * 128 + 4 * 32768) / 256, 256, 0, stream>>>(
        x_nodes, image, W_g1, W_img1, W_g2, W_img2,
        extbuf, imgext, wext1, wext3, wext2, wext4);

    // GCN layer 1: xw1 = x_nodes @ W_g1 (split-bf16 MFMA); h = relu(A-hat xw1 + b1)
    mfma_gemm_kernel<<<dim3(HID / 64, (N_NODES + 127) / 128), 256, 0, stream>>>(
        extbuf, wext1, nullptr, xw1, N_NODES, HID, DIM, 0, 0);
    agg256_kernel<1, 1, 0, 0><<<(N_NODES + 3) / 4, 256, 0, stream>>>(
        xw1, dinv, csr_src, csr_w, offs, b_g1, h, nullptr, nullptr);

    // GCN layer 2 aggregation (compact label rows)
    agg256_kernel<0, 0, 1, 1><<<BATCH / 4, 256, 0, stream>>>(
        h, dinv, csr_src, csr_w, offs, nullptr, g2inext, nodelist, pcnt);

    // dual GEMM: GCN2 (g2ext = ext(g2in@W_g2+b2), M=pcnt) + MLP1 (himgext)
    mfma_gemm_dual_kernel<<<dim3(DIM / 64 + HID / 64, BATCH / 128), 256, 0, stream>>>(
        g2inext, wext2, b_g2, g2ext, pcnt, DIM, HID,
        imgext, wext3, b_img1, himgext, BATCH, HID, DIM);

    // MLP2: Bext = ext(relu(himg@W2+b2))
    mfma_gemm_kernel<<<dim3(DIM / 64, BATCH / 128), 256, 0, stream>>>(
        himgext, wext4, b_img2, Bext, BATCH, DIM, HID, 1, 1);

    // fused logits (split-bf16 MFMA, 256x128 tile) + online softmax partials
    logits_mfma_kernel<<<512, 512, 0, stream>>>(g2ext, Bext, label, pos,
                                                pmax, psum, diagv);
    // per-row LSE + fused mean + triplet constant
    row_finalize_kernel<<<(BATCH * 64) / 256, 256, 0, stream>>>(
        pmax, psum, diagv, label, facc, fcnt, (float*)d_out);
}

// Round 11
// 316.519 us; speedup vs baseline: 1.6955x; 1.0459x over previous
//
#include <hip/hip_runtime.h>
#include <hip/hip_bf16.h>
#include <math.h>

// Problem constants (fixed by the reference)
#define N_NODES 10000
#define N_EDGES 160000
#define BATCH   4096
#define DIM     512
#define HID     256

typedef short short8 __attribute__((ext_vector_type(8)));
typedef float f32x4  __attribute__((ext_vector_type(4)));

// ---------------------------------------------------------------------------
// graph build utilities
// ---------------------------------------------------------------------------
__global__ void zero_init_kernel(int* cnt, int* cursor, int* flag, int* pcnt,
                                 float* facc, int* fcnt) {
    int i = blockIdx.x * blockDim.x + threadIdx.x;
    if (i < N_NODES) { cnt[i] = 0; cursor[i] = 0; flag[i] = 0; }
    if (i == 0) { pcnt[0] = 0; facc[0] = 0.0f; fcnt[0] = 0; }
}

// degree count + label marking in one pass
__global__ void count_mark_kernel(const int* __restrict__ dst, const int* __restrict__ label,
                                  int* __restrict__ cnt, int* __restrict__ flag) {
    int e = blockIdx.x * blockDim.x + threadIdx.x;
    if (e < N_EDGES) atomicAdd(&cnt[dst[e]], 1);
    if (e < BATCH) flag[label[e]] = 1;          // idempotent, races benign
}

// block-local scan (256/block) + per-block sums; also computes dinv
__global__ __launch_bounds__(256) void scanA_kernel(const int* __restrict__ cnt,
        int* __restrict__ offs, int* __restrict__ bsum, float* __restrict__ dinv) {
    __shared__ int sh[256];
    int i = blockIdx.x * 256 + threadIdx.x;
    int v = (i < N_NODES) ? cnt[i] : 0;
    if (i < N_NODES) dinv[i] = rsqrtf((float)(1 + v));
    sh[threadIdx.x] = v;
    __syncthreads();
    for (int off = 1; off < 256; off <<= 1) {
        int t = (threadIdx.x >= (unsigned)off) ? sh[threadIdx.x - off] : 0;
        __syncthreads();
        sh[threadIdx.x] += t;
        __syncthreads();
    }
    if (i < N_NODES) offs[i] = sh[threadIdx.x] - v;   // exclusive within block
    if (threadIdx.x == 255) bsum[blockIdx.x] = sh[255];
}

// adds prefix of bsum (computed in-kernel; 40 entries)
__global__ __launch_bounds__(256) void scanC_kernel(int* __restrict__ offs,
                                                    const int* __restrict__ bsum) {
    int pre = 0;
    for (int b = 0; b < (int)blockIdx.x; ++b) pre += bsum[b];
    int i = blockIdx.x * 256 + threadIdx.x;
    if (i < N_NODES) offs[i] += pre;
    if (i == 0) offs[N_NODES] = N_EDGES;
}

// CSR fill (storing src id + dinv[src]) fused with label-set compaction
__global__ void fill_compact_kernel(const int* __restrict__ src, const int* __restrict__ dst,
                                    const int* __restrict__ offs, const float* __restrict__ dinv,
                                    int* __restrict__ cursor, int* __restrict__ csr_src,
                                    float* __restrict__ csr_w, const int* __restrict__ flag,
                                    int* __restrict__ pcnt, int* __restrict__ nodelist,
                                    int* __restrict__ pos) {
    int e = blockIdx.x * blockDim.x + threadIdx.x;
    if (e < N_EDGES) {
        int d = dst[e];
        int s = src[e];
        int p = offs[d] + atomicAdd(&cursor[d], 1);
        csr_src[p] = s;
        csr_w[p]   = dinv[s];
    }
    if (e < N_NODES && flag[e]) {
        int p = atomicAdd(pcnt, 1);
        nodelist[p] = e;
        pos[e] = p;
    }
}

// ---------------------------------------------------------------------------
// split-bf16 helpers
// ---------------------------------------------------------------------------
__device__ __forceinline__ unsigned short f2bf(float x) {
    unsigned u = __float_as_uint(x);
    return (unsigned short)((u + 0x7FFFu + ((u >> 16) & 1u)) >> 16);   // RNE
}
__device__ __forceinline__ float bf2f(unsigned short h) {
    return __uint_as_float(((unsigned)h) << 16);
}

// ---------------------------------------------------------------------------
// GCN aggregation over 256 channels: wave-per-node, float4 per lane,
// 4 gathers in flight. EXTOUT: emit split-bf16 [hi|lo] row (2x256).
// ---------------------------------------------------------------------------
template <int BIAS, int RELU, int COMPACT, int EXTOUT>
__global__ __launch_bounds__(256) void agg256_kernel(const float* __restrict__ xw,
        const float* __restrict__ dinv, const int* __restrict__ csr_src,
        const float* __restrict__ csr_w, const int* __restrict__ offs,
        const float* __restrict__ bias, void* __restrict__ out,
        const int* __restrict__ nodelist, const int* __restrict__ pcnt) {
    int wid  = blockIdx.x * 4 + (threadIdx.x >> 6);
    int lane = threadIdx.x & 63;
    int n;
    if (COMPACT) { if (wid >= pcnt[0]) return; n = nodelist[wid]; }
    else         { if (wid >= N_NODES) return; n = wid; }
    int c4 = lane * 4;
    float di = dinv[n];
    float d2 = di * di;
    float4 self = *(const float4*)&xw[(size_t)n * 256 + c4];
    float4 a = make_float4(d2 * self.x, d2 * self.y, d2 * self.z, d2 * self.w);
    int s0 = offs[n], s1 = offs[n + 1];
    int i = s0;
    for (; i + 3 < s1; i += 4) {              // 4 gathers in flight
        int   sr0 = csr_src[i],     sr1 = csr_src[i + 1];
        int   sr2 = csr_src[i + 2], sr3 = csr_src[i + 3];
        float w0 = di * csr_w[i],     w1 = di * csr_w[i + 1];
        float w2 = di * csr_w[i + 2], w3 = di * csr_w[i + 3];
        float4 v0 = *(const float4*)&xw[(size_t)sr0 * 256 + c4];
        float4 v1 = *(const float4*)&xw[(size_t)sr1 * 256 + c4];
        float4 v2 = *(const float4*)&xw[(size_t)sr2 * 256 + c4];
        float4 v3 = *(const float4*)&xw[(size_t)sr3 * 256 + c4];
        a.x = fmaf(w0, v0.x, a.x); a.y = fmaf(w0, v0.y, a.y);
        a.z = fmaf(w0, v0.z, a.z); a.w = fmaf(w0, v0.w, a.w);
        a.x = fmaf(w1, v1.x, a.x); a.y = fmaf(w1, v1.y, a.y);
        a.z = fmaf(w1, v1.z, a.z); a.w = fmaf(w1, v1.w, a.w);
        a.x = fmaf(w2, v2.x, a.x); a.y = fmaf(w2, v2.y, a.y);
        a.z = fmaf(w2, v2.z, a.z); a.w = fmaf(w2, v2.w, a.w);
        a.x = fmaf(w3, v3.x, a.x); a.y = fmaf(w3, v3.y, a.y);
        a.z = fmaf(w3, v3.z, a.z); a.w = fmaf(w3, v3.w, a.w);
    }
    for (; i < s1; ++i) {
        int sr = csr_src[i];
        float wgt = di * csr_w[i];
        float4 v = *(const float4*)&xw[(size_t)sr * 256 + c4];
        a.x = fmaf(wgt, v.x, a.x); a.y = fmaf(wgt, v.y, a.y);
        a.z = fmaf(wgt, v.z, a.z); a.w = fmaf(wgt, v.w, a.w);
    }
    if (BIAS) {
        float4 b = *(const float4*)&bias[c4];
        a.x += b.x; a.y += b.y; a.z += b.z; a.w += b.w;
    }
    if (RELU) {
        a.x = fmaxf(a.x, 0.f); a.y = fmaxf(a.y, 0.f);
        a.z = fmaxf(a.z, 0.f); a.w = fmaxf(a.w, 0.f);
    }
    int orow = COMPACT ? wid : n;
    if (EXTOUT) {
        ushort4 h, l;
        h.x = f2bf(a.x); l.x = f2bf(a.x - bf2f(h.x));
        h.y = f2bf(a.y); l.y = f2bf(a.y - bf2f(h.y));
        h.z = f2bf(a.z); l.z = f2bf(a.z - bf2f(h.z));
        h.w = f2bf(a.w); l.w = f2bf(a.w - bf2f(h.w));
        unsigned short* ob = (unsigned short*)out + (size_t)orow * 512;
        *(ushort4*)&ob[c4]       = h;
        *(ushort4*)&ob[256 + c4] = l;
    } else {
        *(float4*)((float*)out + (size_t)orow * 256 + c4) = a;
    }
}

// ---------------------------------------------------------------------------
// ALL operand builds in one launch: row-ext for x_nodes + image, col-ext for
// the 4 weight matrices. Segmented flat grid.
// ---------------------------------------------------------------------------
__global__ __launch_bounds__(256) void build_all_kernel(
        const float* __restrict__ xn, const float* __restrict__ im,
        const float* __restrict__ Wg1, const float* __restrict__ Wi1,
        const float* __restrict__ Wg2, const float* __restrict__ Wi2,
        unsigned short* __restrict__ dxn, unsigned short* __restrict__ dim_,
        unsigned short* __restrict__ o1, unsigned short* __restrict__ o3,
        unsigned short* __restrict__ o2, unsigned short* __restrict__ o4) {
    int id = blockIdx.x * 256 + threadIdx.x;
    const int NA = (N_NODES + BATCH) * 128;        // row-ext domain
    if (id < NA) {
        const int NX = N_NODES * 128;
        int lid = (id < NX) ? id : id - NX;
        const float* src = (id < NX) ? xn : im;
        unsigned short* dst = (id < NX) ? dxn : dim_;
        int r  = lid >> 7;
        int c4 = (lid & 127) << 2;
        float4 v = *(const float4*)&src[(size_t)r * DIM + c4];
        ushort4 h, l;
        h.x = f2bf(v.x); l.x = f2bf(v.x - bf2f(h.x));
        h.y = f2bf(v.y); l.y = f2bf(v.y - bf2f(h.y));
        h.z = f2bf(v.z); l.z = f2bf(v.z - bf2f(h.z));
        h.w = f2bf(v.w); l.w = f2bf(v.w - bf2f(h.w));
        unsigned short* base = dst + (size_t)r * 1024;
        *(ushort4*)&base[c4]       = h;
        *(ushort4*)&base[512 + c4] = l;
    } else {
        int lid2 = id - NA;                        // [0, 131072)
        int seg  = lid2 >> 15;
        int lid  = lid2 & 32767;
        const float* src; unsigned short* dst; int K, N, kshift;
        if (seg == 0)      { src = Wg1; dst = o1; K = 512; N = 256; kshift = 7; }
        else if (seg == 1) { src = Wi1; dst = o3; K = 512; N = 256; kshift = 7; }
        else if (seg == 2) { src = Wg2; dst = o2; K = 256; N = 512; kshift = 6; }
        else               { src = Wi2; dst = o4; K = 256; N = 512; kshift = 6; }
        int n  = lid >> kshift;
        int c4 = (lid & ((1 << kshift) - 1)) << 2;
        float v0 = src[(size_t)(c4 + 0) * N + n];
        float v1 = src[(size_t)(c4 + 1) * N + n];
        float v2 = src[(size_t)(c4 + 2) * N + n];
        float v3 = src[(size_t)(c4 + 3) * N + n];
        ushort4 h, l;
        h.x = f2bf(v0); l.x = f2bf(v0 - bf2f(h.x));
        h.y = f2bf(v1); l.y = f2bf(v1 - bf2f(h.y));
        h.z = f2bf(v2); l.z = f2bf(v2 - bf2f(h.z));
        h.w = f2bf(v3); l.w = f2bf(v3 - bf2f(h.w));
        unsigned short* base = dst + (size_t)n * 2 * K;
        *(ushort4*)&base[c4]     = h;
        *(ushort4*)&base[K + c4] = l;
    }
}

// ---------------------------------------------------------------------------
__device__ __forceinline__ void gld_lds16(const void* g, void* l) {
    __builtin_amdgcn_global_load_lds(
        (const __attribute__((address_space(1))) unsigned int*)g,
        (__attribute__((address_space(3))) unsigned int*)l, 16, 0, 0);
}

// ---------------------------------------------------------------------------
// Dense MFMA GEMM body on [hi|lo] ext operands: C = A.B^T, 3-product split-bf16.
// tile 128x64, 4 waves (2x2), wave = 64x32. Runtime bias/relu/ext flags are
// block-uniform (scalar branches). sh = 12288 ushorts (A 16KB + B 8KB).
// ---------------------------------------------------------------------------
__device__ __forceinline__ void gemm_body(
        const unsigned short* __restrict__ Aext, const unsigned short* __restrict__ Bext,
        const float* __restrict__ bias, void* __restrict__ Cout,
        int M, int N, int K, int rt, int ct, int relu, int ext,
        unsigned short* sh) {
    int t    = threadIdx.x;
    int lane = t & 63;
    int w    = t >> 6;
    int wy   = w >> 1, wx = w & 1;
    int m    = lane & 15;
    int q    = lane >> 4;

    int ra0 = rt * 128 + w * 16 + m;        if (ra0 > M - 1) ra0 = M - 1;
    int ra1 = rt * 128 + (4 + w) * 16 + m;  if (ra1 > M - 1) ra1 = M - 1;
    int rb  = ct * 64 + w * 16 + m;
    const unsigned short* pa0 = Aext + (size_t)ra0 * 2 * K + q * 8;
    const unsigned short* pa1 = Aext + (size_t)ra1 * 2 * K + q * 8;
    const unsigned short* pb  = Bext + (size_t)rb  * 2 * K + q * 8;
    unsigned short* Bs = sh + 8192;

    f32x4 acc[4][2];
#pragma unroll
    for (int i = 0; i < 4; ++i)
#pragma unroll
        for (int j = 0; j < 2; ++j) acc[i][j] = (f32x4){0.f, 0.f, 0.f, 0.f};

    for (int k0 = 0; k0 < K; k0 += 32) {
        gld_lds16(pa0 + k0,     sh + (w * 2 + 0) * 512);
        gld_lds16(pa0 + K + k0, sh + (w * 2 + 1) * 512);
        gld_lds16(pa1 + k0,     sh + ((4 + w) * 2 + 0) * 512);
        gld_lds16(pa1 + K + k0, sh + ((4 + w) * 2 + 1) * 512);
        gld_lds16(pb + k0,      Bs + (w * 2 + 0) * 512);
        gld_lds16(pb + K + k0,  Bs + (w * 2 + 1) * 512);
        __syncthreads();
        short8 ah[4], al[4];
#pragma unroll
        for (int i = 0; i < 4; ++i) {
            ah[i] = *(const short8*)&sh[((wy * 4 + i) * 2 + 0) * 512 + lane * 8];
            al[i] = *(const short8*)&sh[((wy * 4 + i) * 2 + 1) * 512 + lane * 8];
        }
#pragma unroll
        for (int j = 0; j < 2; ++j) {
            short8 bh = *(const short8*)&Bs[((wx * 2 + j) * 2 + 0) * 512 + lane * 8];
            short8 bl = *(const short8*)&Bs[((wx * 2 + j) * 2 + 1) * 512 + lane * 8];
#pragma unroll
            for (int i = 0; i < 4; ++i) {
                acc[i][j] = __builtin_amdgcn_mfma_f32_16x16x32_bf16(ah[i], bh, acc[i][j], 0, 0, 0);
                acc[i][j] = __builtin_amdgcn_mfma_f32_16x16x32_bf16(al[i], bh, acc[i][j], 0, 0, 0);
                acc[i][j] = __builtin_amdgcn_mfma_f32_16x16x32_bf16(ah[i], bl, acc[i][j], 0, 0, 0);
            }
        }
        __syncthreads();
    }

    float b0 = 0.f, b1 = 0.f;
    if (bias) {
        b0 = bias[ct * 64 + wx * 32 + m];
        b1 = bias[ct * 64 + wx * 32 + 16 + m];
    }
#pragma unroll
    for (int i = 0; i < 4; ++i) {
        int rbase = rt * 128 + wy * 64 + i * 16 + q * 4;
#pragma unroll
        for (int j = 0; j < 2; ++j) {
            int col = ct * 64 + wx * 32 + j * 16 + m;
            float bb = j ? b1 : b0;
#pragma unroll
            for (int reg = 0; reg < 4; ++reg) {
                int row = rbase + reg;
                if (row < M) {
                    float v = acc[i][j][reg] + bb;
                    if (relu) v = fmaxf(v, 0.f);
                    if (ext == 0) {
                        ((float*)Cout)[(size_t)row * N + col] = v;
                    } else {
                        unsigned short hi = f2bf(v);
                        unsigned short lo = f2bf(v - bf2f(hi));
                        unsigned short* ob = (unsigned short*)Cout + (size_t)row * 2 * N;
                        ob[col] = hi; ob[N + col] = lo;
                    }
                }
            }
        }
    }
}

// dualA: GCN1 GEMM (ct 0..3, rt 0..78, M=10000, fp32 out) + MLP1 (ct 4..7,
// rt 0..31, M=4096, relu+ext out). Independent — share one launch.
__global__ __launch_bounds__(256, 4) void mfma_gemm_dualA_kernel(
        const unsigned short* __restrict__ A0, const unsigned short* __restrict__ B0,
        void* __restrict__ C0,
        const unsigned short* __restrict__ A1, const unsigned short* __restrict__ B1,
        const float* __restrict__ bias1, void* __restrict__ C1) {
    __shared__ __align__(16) unsigned short sh[12288];
    if ((int)blockIdx.x < 4) {
        gemm_body(A0, B0, nullptr, C0, N_NODES, HID, DIM, blockIdx.y, blockIdx.x, 0, 0, sh);
    } else {
        if ((int)blockIdx.y >= BATCH / 128) return;
        gemm_body(A1, B1, bias1, C1, BATCH, HID, DIM, blockIdx.y, blockIdx.x - 4, 1, 1, sh);
    }
}

// dualB: GCN2 GEMM (ct 0..7, M=pcnt, ext out) + MLP2 (ct 8..15, relu+ext out).
__global__ __launch_bounds__(256, 4) void mfma_gemm_dualB_kernel(
        const unsigned short* __restrict__ A0, const unsigned short* __restrict__ B0,
        const float* __restrict__ bias0, void* __restrict__ C0,
        const int* __restrict__ Mptr0,
        const unsigned short* __restrict__ A1, const unsigned short* __restrict__ B1,
        const float* __restrict__ bias1, void* __restrict__ C1) {
    __shared__ __align__(16) unsigned short sh[12288];
    if ((int)blockIdx.x < 8) {
        gemm_body(A0, B0, bias0, C0, Mptr0[0], DIM, HID, blockIdx.y, blockIdx.x, 0, 1, sh);
    } else {
        gemm_body(A1, B1, bias1, C1, BATCH, DIM, HID, blockIdx.y, blockIdx.x - 8, 1, 1, sh);
    }
}

// ---------------------------------------------------------------------------
// logits = A @ B^T on [hi|lo] ext (K=512, 3-product split-bf16) + fused online
// softmax partials. 256x128 tile, 512 thr = 8 waves (4x2), wave = 64x64.
// 48 KB LDS -> 2 blocks/CU; 512 blocks full residency. In-kernel A-gather via
// pos[label]; fragment-order LDS (conflict-free); XCD swizzle.
// ---------------------------------------------------------------------------
__global__ __launch_bounds__(512, 4) void logits_mfma_kernel(
        const unsigned short* __restrict__ Aext, const unsigned short* __restrict__ Bext,
        const int* __restrict__ label, const int* __restrict__ pos,
        float* __restrict__ pmax, float* __restrict__ psum, float* __restrict__ diagv) {
    __shared__ __align__(16) unsigned short sh[24576];   // 48 KB: A 32KB (16 chunks) + B 16KB (8)
    unsigned short* Bs = sh + 16384;

    int t    = threadIdx.x;
    int lane = t & 63;
    int w    = t >> 6;            // wave 0..7
    int wy   = w >> 1, wx = w & 1;
    // XCD swizzle over 512 blocks = 16 rt x 32 ct; per-XCD region 8rt x 8ct
    int g   = blockIdx.x;
    int xcd = g & 7, s = g >> 3;              // s in 0..63
    int rt  = (xcd & 1) * 8 + (s & 7);        // 0..15 (256-row tiles)
    int ct  = (xcd >> 1) * 8 + (s >> 3);      // 0..31 (128-col tiles)
    int m    = lane & 15;
    int q    = lane >> 4;

    // staging: wave w owns A chunks (w*2, w*2+1) and B chunk w (16 rows each)
    int ar0 = pos[label[rt * 256 + (w * 2 + 0) * 16 + m]];
    int ar1 = pos[label[rt * 256 + (w * 2 + 1) * 16 + m]];
    const unsigned short* ap0 = Aext + (size_t)ar0 * 1024 + q * 8;
    const unsigned short* ap1 = Aext + (size_t)ar1 * 1024 + q * 8;
    const unsigned short* bp  = Bext + (size_t)(ct * 128 + w * 16 + m) * 1024 + q * 8;

    f32x4 acc[4][4];
#pragma unroll
    for (int i = 0; i < 4; ++i)
#pragma unroll
        for (int j = 0; j < 4; ++j) acc[i][j] = (f32x4){0.f, 0.f, 0.f, 0.f};

    for (int k0 = 0; k0 < 512; k0 += 32) {
        gld_lds16(ap0 + k0,       sh + ((w * 2 + 0) * 2 + 0) * 512);
        gld_lds16(ap0 + 512 + k0, sh + ((w * 2 + 0) * 2 + 1) * 512);
        gld_lds16(ap1 + k0,       sh + ((w * 2 + 1) * 2 + 0) * 512);
        gld_lds16(ap1 + 512 + k0, sh + ((w * 2 + 1) * 2 + 1) * 512);
        gld_lds16(bp + k0,        Bs + (w * 2 + 0) * 512);
        gld_lds16(bp + 512 + k0,  Bs + (w * 2 + 1) * 512);
        __syncthreads();                 // drains vmcnt: staging complete
        short8 ah[4], al[4];
#pragma unroll
        for (int i = 0; i < 4; ++i) {
            ah[i] = *(const short8*)&sh[((wy * 4 + i) * 2 + 0) * 512 + lane * 8];
            al[i] = *(const short8*)&sh[((wy * 4 + i) * 2 + 1) * 512 + lane * 8];
        }
#pragma unroll
        for (int j = 0; j < 4; ++j) {
            short8 bh = *(const short8*)&Bs[((wx * 4 + j) * 2 + 0) * 512 + lane * 8];
            short8 bl = *(const short8*)&Bs[((wx * 4 + j) * 2 + 1) * 512 + lane * 8];
#pragma unroll
            for (int i = 0; i < 4; ++i) {
                acc[i][j] = __builtin_amdgcn_mfma_f32_16x16x32_bf16(ah[i], bh, acc[i][j], 0, 0, 0);
                acc[i][j] = __builtin_amdgcn_mfma_f32_16x16x32_bf16(al[i], bh, acc[i][j], 0, 0, 0);
                acc[i][j] = __builtin_amdgcn_mfma_f32_16x16x32_bf16(ah[i], bl, acc[i][j], 0, 0, 0);
            }
        }
        __syncthreads();                 // WAR before next staging
    }

    // C/D layout: col = lane&15, row = q*4 + reg (within each 16x16 tile)
    // diagonal: block touches it iff ct>>1 == rt
    if ((ct >> 1) == rt) {
#pragma unroll
        for (int i = 0; i < 4; ++i)
#pragma unroll
            for (int j = 0; j < 4; ++j)
#pragma unroll
                for (int reg = 0; reg < 4; ++reg) {
                    int row = rt * 256 + wy * 64 + i * 16 + q * 4 + reg;
                    int col = ct * 128 + wx * 64 + j * 16 + m;
                    if (row == col) diagv[row] = acc[i][j][reg];
                }
    }

    // per-row (max, sumexp) over this wave's 64 cols
#pragma unroll
    for (int mt = 0; mt < 4; ++mt) {
#pragma unroll
        for (int reg = 0; reg < 4; ++reg) {
            float v0 = acc[mt][0][reg], v1 = acc[mt][1][reg];
            float v2 = acc[mt][2][reg], v3 = acc[mt][3][reg];
            float mx = fmaxf(fmaxf(v0, v1), fmaxf(v2, v3));
#pragma unroll
            for (int d = 1; d < 16; d <<= 1) mx = fmaxf(mx, __shfl_xor(mx, d, 64));
            float sm = __expf(v0 - mx) + __expf(v1 - mx) + __expf(v2 - mx) + __expf(v3 - mx);
#pragma unroll
            for (int d = 1; d < 16; d <<= 1) sm += __shfl_xor(sm, d, 64);
            if (m == 0) {
                int row = rt * 256 + wy * 64 + mt * 16 + q * 4 + reg;
                pmax[(size_t)row * 64 + ct * 2 + wx] = mx;
                psum[(size_t)row * 64 + ct * 2 + wx] = sm;
            }
        }
    }
}

// combine 64 col-tile partials per row -> per-row loss term; fused final
// reduction via device-scope atomics (last block writes out[0]).
__global__ __launch_bounds__(256) void row_finalize_kernel(const float* __restrict__ pmax,
        const float* __restrict__ psum, const float* __restrict__ diagv,
        const int* __restrict__ label, float* __restrict__ facc, int* __restrict__ fcnt,
        float* __restrict__ out) {
    __shared__ float wsum[4];
    int gid  = blockIdx.x * blockDim.x + threadIdx.x;
    int row  = gid >> 6;
    int lane = threadIdx.x & 63;
    int wv   = threadIdx.x >> 6;
    float term = 0.0f;
    if (row < BATCH) {
        float m = pmax[(size_t)row * 64 + lane];
        float s = psum[(size_t)row * 64 + lane];
        float M = m;
#pragma unroll
        for (int d = 1; d < 64; d <<= 1) M = fmaxf(M, __shfl_xor(M, d, 64));
        s *= __expf(m - M);
#pragma unroll
        for (int d = 1; d < 64; d <<= 1) s += __shfl_xor(s, d, 64);
        float lse = M + __logf(s);
        term = -(float)label[row] * (diagv[row] - lse);
    }
    if (lane == 0) wsum[wv] = (row < BATCH) ? term : 0.0f;
    __syncthreads();
    if (threadIdx.x == 0) {
        float p = wsum[0] + wsum[1] + wsum[2] + wsum[3];
        atomicAdd(facc, p);
        __threadfence();
        int old = atomicAdd(fcnt, 1);
        if (old == (int)gridDim.x - 1) {
            float tot = atomicAdd(facc, 0.0f);   // device-scope coherent read
            // contrastive mean + triplet loss (identically 1.0: d_ap==d_an)
            out[0] = tot / (float)BATCH + 1.0f;
        }
    }
}

// ---------------------------------------------------------------------------
extern "C" void kernel_launch(void* const* d_in, const int* in_sizes, int n_in,
                              void* d_out, int out_size, void* d_ws, size_t ws_size,
                              hipStream_t stream) {
    const float* image   = (const float*)d_in[0];
    const float* x_nodes = (const float*)d_in[1];
    const int*   edge    = (const int*)d_in[2];
    const int*   label   = (const int*)d_in[3];
    const float* W_img1  = (const float*)d_in[4];
    const float* b_img1  = (const float*)d_in[5];
    const float* W_img2  = (const float*)d_in[6];
    const float* b_img2  = (const float*)d_in[7];
    const float* W_g1    = (const float*)d_in[8];
    const float* b_g1    = (const float*)d_in[9];
    const float* W_g2    = (const float*)d_in[10];
    const float* b_g2    = (const float*)d_in[11];
    const int* src = edge;              // edge_index[0]
    const int* dst = edge + N_EDGES;    // edge_index[1]

    // workspace carve-up (256B aligned regions)
    char* ws = (char*)d_ws;
    size_t off = 0;
    auto alloc = [&](size_t bytes) { size_t r = off; off = (off + bytes + 255) & ~(size_t)255; return r; };
    float* dinv     = (float*)(ws + alloc(N_NODES * 4));
    int*   cnt      = (int*)  (ws + alloc(N_NODES * 4));
    int*   offs     = (int*)  (ws + alloc((N_NODES + 1) * 4));
    int*   cursor   = (int*)  (ws + alloc(N_NODES * 4));
    int*   csr_src  = (int*)  (ws + alloc(N_EDGES * 4));
    float* csr_w    = (float*)(ws + alloc(N_EDGES * 4));
    int*   flag     = (int*)  (ws + alloc(N_NODES * 4));
    int*   pos      = (int*)  (ws + alloc(N_NODES * 4));
    int*   nodelist = (int*)  (ws + alloc(BATCH * 4));
    int*   pcnt     = (int*)  (ws + alloc(4));
    int*   bsum     = (int*)  (ws + alloc(64 * 4));
    float* facc     = (float*)(ws + alloc(4));
    int*   fcnt     = (int*)  (ws + alloc(4));
    float* xw1      = (float*)(ws + alloc((size_t)N_NODES * HID * 4));
    float* h        = (float*)(ws + alloc((size_t)N_NODES * HID * 4));
    unsigned short* g2inext = (unsigned short*)(ws + alloc((size_t)BATCH * 2 * HID * 2));
    unsigned short* g2ext   = (unsigned short*)(ws + alloc((size_t)BATCH * 2 * DIM * 2));
    unsigned short* himgext = (unsigned short*)(ws + alloc((size_t)BATCH * 2 * HID * 2));
    unsigned short* extbuf  = (unsigned short*)(ws + alloc((size_t)N_NODES * 2 * DIM * 2));
    unsigned short* imgext  = (unsigned short*)(ws + alloc((size_t)BATCH * 2 * DIM * 2));
    unsigned short* wext1   = (unsigned short*)(ws + alloc((size_t)HID * 2 * DIM * 2));
    unsigned short* wext2   = (unsigned short*)(ws + alloc((size_t)DIM * 2 * HID * 2));
    unsigned short* wext3   = (unsigned short*)(ws + alloc((size_t)HID * 2 * DIM * 2));
    unsigned short* wext4   = (unsigned short*)(ws + alloc((size_t)DIM * 2 * HID * 2));
    unsigned short* Bext    = (unsigned short*)(ws + alloc((size_t)BATCH * 2 * DIM * 2));
    float* pmax  = (float*)(ws + alloc((size_t)BATCH * 64 * 4));
    float* psum  = (float*)(ws + alloc((size_t)BATCH * 64 * 4));
    float* diagv = (float*)(ws + alloc(BATCH * 4));

    const int SCAN_BLOCKS = (N_NODES + 255) / 256;   // 40

    // graph build: CSR by dst (storing src+weight) + dinv + label compaction
    zero_init_kernel<<<SCAN_BLOCKS, 256, 0, stream>>>(cnt, cursor, flag, pcnt, facc, fcnt);
    count_mark_kernel<<<(N_EDGES + 255) / 256, 256, 0, stream>>>(dst, label, cnt, flag);
    scanA_kernel<<<SCAN_BLOCKS, 256, 0, stream>>>(cnt, offs, bsum, dinv);
    scanC_kernel<<<SCAN_BLOCKS, 256, 0, stream>>>(offs, bsum);
    fill_compact_kernel<<<(N_EDGES + 255) / 256, 256, 0, stream>>>(
        src, dst, offs, dinv, cursor, csr_src, csr_w, flag, pcnt, nodelist, pos);

    // all operand builds (x_nodes + image row-ext, 4 weight col-ext) in one launch
    build_all_kernel<<<((N_NODES + BATCH) * 128 + 4 * 32768) / 256, 256, 0, stream>>>(
        x_nodes, image, W_g1, W_img1, W_g2, W_img2,
        extbuf, imgext, wext1, wext3, wext2, wext4);

    // dualA: GCN1 GEMM (xw1 = x_nodes @ W_g1) + MLP1 (himgext) — independent
    mfma_gemm_dualA_kernel<<<dim3(8, (N_NODES + 127) / 128), 256, 0, stream>>>(
        extbuf, wext1, xw1, imgext, wext3, b_img1, himgext);

    // GCN layer 1 aggregation: h = relu(A-hat xw1 + b1)
    agg256_kernel<1, 1, 0, 0><<<(N_NODES + 3) / 4, 256, 0, stream>>>(
        xw1, dinv, csr_src, csr_w, offs, b_g1, h, nullptr, nullptr);

    // GCN layer 2 aggregation (compact label rows)
    agg256_kernel<0, 0, 1, 1><<<BATCH / 4, 256, 0, stream>>>(
        h, dinv, csr_src, csr_w, offs, nullptr, g2inext, nodelist, pcnt);

    // dualB: GCN2 GEMM (g2ext, M=pcnt) + MLP2 (Bext) — independent at this point
    mfma_gemm_dualB_kernel<<<dim3(16, BATCH / 128), 256, 0, stream>>>(
        g2inext, wext2, b_g2, g2ext, pcnt, himgext, wext4, b_img2, Bext);

    // fused logits (split-bf16 MFMA, 256x128 tile) + online softmax partials
    logits_mfma_kernel<<<512, 512, 0, stream>>>(g2ext, Bext, label, pos,
                                                pmax, psum, diagv);
    // per-row LSE + fused mean + triplet constant
    row_finalize_kernel<<<(BATCH * 64) / 256, 256, 0, stream>>>(
        pmax, psum, diagv, label, facc, fcnt, (float*)d_out);
}